// Round 5
// baseline (1706.363 us; speedup 1.0000x reference)
//
#include <hip/hip_runtime.h>
#include <hip/hip_fp16.h>

// GCN: h1 = relu(gcn(x,W1,b1)); h2 = relu(gcn(h1,W2,b2)); out = h2.reshape(B,896)@Wfc + bfc
// Factored: g1 = dinv*(x@W1); h1 = relu(dinv*agg(g1)+b1); u1 = dinv*h1;
//           a2 = dinv*agg(u1);  h2 = relu(a2@W2+b2)  [agg commutes with @W2]
//           out[g] = sum_t sum_j h2[g*14+t,j]*Wfc[t*64+j] + bfc
// CSR built via dst>>8 buckets: hist -> scan -> packed partition -> per-bucket LDS build.
// Features fp16, two N*64 buffers. Layer2 matmul+FC fused on MFMA.

typedef _Float16 half8 __attribute__((ext_vector_type(8)));
typedef float float4v __attribute__((ext_vector_type(4)));

__global__ __launch_bounds__(256) void fallback_kernel(float* __restrict__ out, int n, float v)
{
  int i = blockIdx.x * 256 + threadIdx.x;
  if (i < n) out[i] = v;
}

// detect edges dtype: int64 values < 2^31 -> every odd int32 word is 0
__global__ __launch_bounds__(64) void probe_kernel(const int* __restrict__ edges, int* __restrict__ flag)
{
  if (threadIdx.x == 0) {
    int orv = edges[1] | edges[3] | edges[5] | edges[7] | edges[9] | edges[11] | edges[13] | edges[15];
    flag[0] = (orv == 0) ? 1 : 0;  // 1 => int64 layout (shift word index by 1)
  }
}

__global__ __launch_bounds__(256) void zero_i32_kernel(int* __restrict__ p, int n)
{
  int i = blockIdx.x * 256 + threadIdx.x;
  if (i < n) p[i] = 0;
}

// A: bucket histogram over dst>>8
__global__ __launch_bounds__(256) void bucket_hist_kernel(
    const int* __restrict__ edges, int E, int N, const int* __restrict__ flag,
    int* __restrict__ bhist)
{
  int e = blockIdx.x * 256 + threadIdx.x;
  if (e >= E) return;
  int sh = flag[0];
  int d = edges[(E + e) << sh];
  if ((unsigned)d < (unsigned)N) atomicAdd(&bhist[d >> 8], 1);
}

// B: exclusive scan of bucket counts (NBK <= 3072), writes bstart, bcursor, rowptr[N], bstart[NBK]
__global__ __launch_bounds__(1024) void scan_buckets_kernel(
    const int* __restrict__ bhist, int nbk,
    int* __restrict__ bstart, int* __restrict__ bcursor,
    int* __restrict__ rowptr, int N, int E)
{
  __shared__ int sm[1024];
  int t = threadIdx.x;
  int base = t * 3;
  int a0 = (base + 0 < nbk) ? bhist[base + 0] : 0;
  int a1 = (base + 1 < nbk) ? bhist[base + 1] : 0;
  int a2 = (base + 2 < nbk) ? bhist[base + 2] : 0;
  int s = a0 + a1 + a2;
  sm[t] = s;
  __syncthreads();
  for (int off = 1; off < 1024; off <<= 1) {
    int x = 0;
    if (t >= off) x = sm[t - off];
    __syncthreads();
    if (t >= off) sm[t] += x;
    __syncthreads();
  }
  int excl = sm[t] - s;
  if (base + 0 <= nbk) { int v = excl;            bstart[base + 0] = v; if (base + 0 < nbk) bcursor[base + 0] = v; }
  if (base + 1 <= nbk) { int v = excl + a0;       bstart[base + 1] = v; if (base + 1 < nbk) bcursor[base + 1] = v; }
  if (base + 2 <= nbk) { int v = excl + a0 + a1;  bstart[base + 2] = v; if (base + 2 < nbk) bcursor[base + 2] = v; }
  if (t == 0) { bstart[nbk] = E; rowptr[N] = E; }
}

// C: partition edges into buckets; packed word = src | (dst&255)<<20  (src < 2^20)
__global__ __launch_bounds__(256) void partition_kernel(
    const int* __restrict__ edges, int E, int N, const int* __restrict__ flag,
    int* __restrict__ bcursor, int* __restrict__ pair)
{
  int e = blockIdx.x * 256 + threadIdx.x;
  if (e >= E) return;
  int sh = flag[0];
  int s = edges[e << sh];
  int d = edges[(E + e) << sh];
  if ((unsigned)s >= (unsigned)N || (unsigned)d >= (unsigned)N) return;
  int b = d >> 8;
  int pos = atomicAdd(&bcursor[b], 1);
  pair[pos] = s | ((d & 255) << 20);
}

// D: per-bucket CSR build: LDS hist -> LDS scan -> rowptr/dinv -> place edges (LDS cursors)
__global__ __launch_bounds__(256) void build_kernel(
    const int* __restrict__ pair, const int* __restrict__ bstart,
    int* __restrict__ rowptr, float* __restrict__ dinv, int* __restrict__ col, int N)
{
  __shared__ int hist[256];
  __shared__ int sc[256];
  __shared__ int cur[256];
  int b = blockIdx.x;
  int t = threadIdx.x;
  int pbeg = bstart[b], pend = bstart[b + 1];
  hist[t] = 0;
  __syncthreads();
  for (int p = pbeg + t; p < pend; p += 256) {
    int v = pair[p];
    atomicAdd(&hist[(v >> 20) & 255], 1);
  }
  __syncthreads();
  int val = hist[t];
  sc[t] = val;
  __syncthreads();
  for (int off = 1; off < 256; off <<= 1) {
    int x = 0;
    if (t >= off) x = sc[t - off];
    __syncthreads();
    if (t >= off) sc[t] += x;
    __syncthreads();
  }
  int excl = sc[t] - val;
  int row = (b << 8) + t;
  int rp = pbeg + excl;
  cur[t] = rp;
  if (row < N) {
    rowptr[row] = rp;
    dinv[row] = rsqrtf((float)(val + 1));  // deg = dst-count + 1 (self loop)
  }
  __syncthreads();
  for (int p = pbeg + t; p < pend; p += 256) {
    int v = pair[p];
    int pos = atomicAdd(&cur[(v >> 20) & 255], 1);
    col[pos] = v & 0xFFFFF;
  }
}

// g1[n,j] = dinv[n] * sum_k x[n,k]*W1[k,j]   (K=32, wave per node, lane=j, grid-stride)
__global__ __launch_bounds__(256) void mm1_kernel(
    const float* __restrict__ X, const float* __restrict__ W1,
    const float* __restrict__ dinv, __half* __restrict__ G, int n)
{
  int lane = threadIdx.x & 63;
  float Wr[32];
#pragma unroll
  for (int k = 0; k < 32; k++) Wr[k] = W1[k * 64 + lane];
  int wave = (blockIdx.x * 256 + threadIdx.x) >> 6;
  int nw = (gridDim.x * 256) >> 6;
  for (int node = wave; node < n; node += nw) {
    int un = __builtin_amdgcn_readfirstlane(node);
    float xv = X[(size_t)un * 32 + (lane & 31)];  // lanes 0..31 hold the row
    float acc = 0.f;
#pragma unroll
    for (int k = 0; k < 32; k++) acc += __shfl(xv, k) * Wr[k];
    G[(size_t)un * 64 + lane] = __float2half(dinv[un] * acc);
  }
}

// u1[n,:] = dinv[n] * relu(dinv[n]*(sum_{e in row n} g1[col[e],:] + g1[n,:]) + b1)
__global__ __launch_bounds__(256) void agg1_kernel(
    const __half* __restrict__ G, const int* __restrict__ rowptr,
    const int* __restrict__ col, const float* __restrict__ dinv,
    const float* __restrict__ bias, __half* __restrict__ U, int n)
{
  int lane = threadIdx.x & 63;
  int wave = (blockIdx.x * 256 + threadIdx.x) >> 6;
  if (wave >= n) return;
  int un = __builtin_amdgcn_readfirstlane(wave);
  float di = dinv[un];
  float acc = __half2float(G[(size_t)un * 64 + lane]);
  int e = rowptr[un], end = rowptr[un + 1];
  for (; e + 8 <= end; e += 8) {
    float v0 = __half2float(G[(size_t)col[e + 0] * 64 + lane]);
    float v1 = __half2float(G[(size_t)col[e + 1] * 64 + lane]);
    float v2 = __half2float(G[(size_t)col[e + 2] * 64 + lane]);
    float v3 = __half2float(G[(size_t)col[e + 3] * 64 + lane]);
    float v4 = __half2float(G[(size_t)col[e + 4] * 64 + lane]);
    float v5 = __half2float(G[(size_t)col[e + 5] * 64 + lane]);
    float v6 = __half2float(G[(size_t)col[e + 6] * 64 + lane]);
    float v7 = __half2float(G[(size_t)col[e + 7] * 64 + lane]);
    acc += ((v0 + v1) + (v2 + v3)) + ((v4 + v5) + (v6 + v7));
  }
  for (; e < end; e++) acc += __half2float(G[(size_t)col[e] * 64 + lane]);
  float h = di * acc + bias[lane];
  h = h > 0.f ? h : 0.f;
  U[(size_t)un * 64 + lane] = __float2half(di * h);
}

// a2[n,:] = dinv[n] * (sum_{e in row n} u1[col[e],:] + u1[n,:])
__global__ __launch_bounds__(256) void agg2_kernel(
    const __half* __restrict__ U, const int* __restrict__ rowptr,
    const int* __restrict__ col, const float* __restrict__ dinv,
    __half* __restrict__ A2, int n)
{
  int lane = threadIdx.x & 63;
  int wave = (blockIdx.x * 256 + threadIdx.x) >> 6;
  if (wave >= n) return;
  int un = __builtin_amdgcn_readfirstlane(wave);
  float acc = __half2float(U[(size_t)un * 64 + lane]);
  int e = rowptr[un], end = rowptr[un + 1];
  for (; e + 8 <= end; e += 8) {
    float v0 = __half2float(U[(size_t)col[e + 0] * 64 + lane]);
    float v1 = __half2float(U[(size_t)col[e + 1] * 64 + lane]);
    float v2 = __half2float(U[(size_t)col[e + 2] * 64 + lane]);
    float v3 = __half2float(U[(size_t)col[e + 3] * 64 + lane]);
    float v4 = __half2float(U[(size_t)col[e + 4] * 64 + lane]);
    float v5 = __half2float(U[(size_t)col[e + 5] * 64 + lane]);
    float v6 = __half2float(U[(size_t)col[e + 6] * 64 + lane]);
    float v7 = __half2float(U[(size_t)col[e + 7] * 64 + lane]);
    acc += ((v0 + v1) + (v2 + v3)) + ((v4 + v5) + (v6 + v7));
  }
  for (; e < end; e++) acc += __half2float(U[(size_t)col[e] * 64 + lane]);
  A2[(size_t)un * 64 + lane] = __float2half(dinv[un] * acc);
}

__global__ __launch_bounds__(256) void out_init_kernel(
    float* __restrict__ out, const float* __restrict__ bfc, int n)
{
  int i = blockIdx.x * 256 + threadIdx.x;
  if (i < n) out[i] = bfc[0];
}

// MFMA fused layer2-matmul + relu + FC (validated R4):
// per wave: 16 nodes; D[16][64] = A2tile @ W2 via 8x mfma_f32_16x16x32_f16;
// h2 = relu(D + b2); out[node/14] += sum_j h2[node][j]*Wfc[(node%14)*64+j]
__global__ __launch_bounds__(256) void mfma_final_kernel(
    const __half* __restrict__ A2, const float* __restrict__ W2,
    const float* __restrict__ b2, const float* __restrict__ Wfc,
    float* __restrict__ out, int ntiles)
{
  int lane = threadIdx.x & 63;
  int n16 = lane & 15;
  int quad = lane >> 4;

  half8 bf[4][2];
#pragma unroll
  for (int jb = 0; jb < 4; jb++)
#pragma unroll
    for (int kf = 0; kf < 2; kf++)
#pragma unroll
      for (int i = 0; i < 8; i++)
        bf[jb][kf][i] = (_Float16)W2[(kf * 32 + quad * 8 + i) * 64 + jb * 16 + n16];
  float b2j[4];
#pragma unroll
  for (int jb = 0; jb < 4; jb++) b2j[jb] = b2[jb * 16 + n16];

  const _Float16* A2h = (const _Float16*)A2;
  int wave = (blockIdx.x * 256 + threadIdx.x) >> 6;
  int nw = (gridDim.x * 256) >> 6;
  for (int tile = wave; tile < ntiles; tile += nw) {
    int ut = __builtin_amdgcn_readfirstlane(tile);
    int base = ut * 16;
    const _Float16* arow = A2h + (size_t)(base + n16) * 64 + quad * 8;
    half8 a0 = *(const half8*)(arow);
    half8 a1 = *(const half8*)(arow + 32);

    int g_r[4], t_r[4];
#pragma unroll
    for (int r = 0; r < 4; r++) {
      int node = base + quad * 4 + r;
      g_r[r] = node / 14;
      t_r[r] = node - g_r[r] * 14;
    }
    float pr[4] = {0.f, 0.f, 0.f, 0.f};
#pragma unroll
    for (int jb = 0; jb < 4; jb++) {
      float4v acc = {0.f, 0.f, 0.f, 0.f};
      acc = __builtin_amdgcn_mfma_f32_16x16x32_f16(a0, bf[jb][0], acc, 0, 0, 0);
      acc = __builtin_amdgcn_mfma_f32_16x16x32_f16(a1, bf[jb][1], acc, 0, 0, 0);
      int j = jb * 16 + n16;
#pragma unroll
      for (int r = 0; r < 4; r++) {
        float h = acc[r] + b2j[jb];
        h = h > 0.f ? h : 0.f;
        pr[r] += h * Wfc[t_r[r] * 64 + j];
      }
    }
#pragma unroll
    for (int r = 0; r < 4; r++) {
#pragma unroll
      for (int off = 1; off < 16; off <<= 1) pr[r] += __shfl_xor(pr[r], off);
    }
    if (n16 == 0) {
#pragma unroll
      for (int r = 0; r < 4; r++) atomicAdd(&out[g_r[r]], pr[r]);
    }
  }
}

extern "C" void kernel_launch(void* const* d_in, const int* in_sizes, int n_in,
                              void* d_out, int out_size, void* d_ws, size_t ws_size,
                              hipStream_t stream)
{
  const float* x = (const float*)d_in[0];
  const int* edges = (const int*)d_in[1];
  const float* W1 = (const float*)d_in[2];
  const float* b1 = (const float*)d_in[3];
  const float* W2 = (const float*)d_in[4];
  const float* b2 = (const float*)d_in[5];
  const float* Wfc = (const float*)d_in[6];
  const float* bfc = (const float*)d_in[7];
  float* out = (float*)d_out;
  (void)n_in;

  const int N = in_sizes[0] / 32;  // 700000
  const int E = in_sizes[1] / 2;   // 4000000
  const int B = out_size;          // 50000
  const int NBK = (N + 255) >> 8;  // 2735 buckets (dst>>8)

  char* ws = (char*)d_ws;
  size_t off = 0;
  auto alloc = [&](size_t bytes) -> void* {
    void* p = ws + off;
    off += (bytes + 255) & ~(size_t)255;
    return p;
  };
  int* flag = (int*)alloc(256);
  int* bhist = (int*)alloc((size_t)NBK * 4);
  int* bstart = (int*)alloc(((size_t)NBK + 1) * 4);
  int* bcursor = (int*)alloc((size_t)NBK * 4);
  int* col = (int*)alloc((size_t)E * 4);
  int* rowptr = (int*)alloc(((size_t)N + 1) * 4);
  float* dinv = (float*)alloc((size_t)N * 4);
  __half* F1 = (__half*)alloc(((size_t)N + 16) * 64 * 2);  // g1, later a2; first 16MB aliased as pairbuf
  __half* F2 = (__half*)alloc(((size_t)N + 16) * 64 * 2);  // u1
  int* pair = (int*)F1;  // pairbuf (E*4 bytes) dead before mm1 writes F1

  if (off > ws_size) {
    float v = -(float)(double)(ws_size >> 20);
    fallback_kernel<<<(B + 255) / 256, 256, 0, stream>>>(out, B, v);
    return;
  }

  probe_kernel<<<1, 64, 0, stream>>>(edges, flag);
  zero_i32_kernel<<<(NBK + 255) / 256, 256, 0, stream>>>(bhist, NBK);
  bucket_hist_kernel<<<(E + 255) / 256, 256, 0, stream>>>(edges, E, N, flag, bhist);
  scan_buckets_kernel<<<1, 1024, 0, stream>>>(bhist, NBK, bstart, bcursor, rowptr, N, E);
  partition_kernel<<<(E + 255) / 256, 256, 0, stream>>>(edges, E, N, flag, bcursor, pair);
  build_kernel<<<NBK, 256, 0, stream>>>(pair, bstart, rowptr, dinv, col, N);

  int aggBlocks = (N * 64 + 255) / 256;  // one wave per node
  mm1_kernel<<<8192, 256, 0, stream>>>(x, W1, dinv, F1, N);
  agg1_kernel<<<aggBlocks, 256, 0, stream>>>(F1, rowptr, col, dinv, b1, F2, N);
  agg2_kernel<<<aggBlocks, 256, 0, stream>>>(F2, rowptr, col, dinv, F1, N);
  out_init_kernel<<<(B + 255) / 256, 256, 0, stream>>>(out, bfc, B);
  int ntiles = (N + 15) / 16;  // 43750
  mfma_final_kernel<<<2048, 256, 0, stream>>>(F1, W2, b2, Wfc, out, ntiles);
}

// Round 6
// 1324.086 us; speedup vs baseline: 1.2887x; 1.2887x over previous
//
#include <hip/hip_runtime.h>
#include <hip/hip_fp16.h>

// GCN: h1 = relu(gcn(x,W1,b1)); h2 = relu(gcn(h1,W2,b2)); out = h2.reshape(B,896)@Wfc + bfc
// Factored: g1 = dinv*(x@W1); h1 = relu(dinv*agg(g1)+b1); u1 = dinv*h1;
//           a2 = dinv*agg(u1);  h2 = relu(a2@W2+b2)  [agg commutes with @W2]
//           out[g] = sum_t sum_j h2[g*14+t,j]*Wfc[t*64+j] + bfc
// CSR via dst>>8 buckets with XCD-sliced (blockIdx&7) cursors so each pair-buffer
// cache line has a single writer XCD (per-XCD L2s are non-coherent; shared frontier
// lines caused 12x write amplification in R5). Features fp16. Layer2+FC on MFMA.

typedef _Float16 half8 __attribute__((ext_vector_type(8)));
typedef float float4v __attribute__((ext_vector_type(4)));

__global__ __launch_bounds__(256) void fallback_kernel(float* __restrict__ out, int n, float v)
{
  int i = blockIdx.x * 256 + threadIdx.x;
  if (i < n) out[i] = v;
}

// detect edges dtype: int64 values < 2^31 -> every odd int32 word is 0
__global__ __launch_bounds__(64) void probe_kernel(const int* __restrict__ edges, int* __restrict__ flag)
{
  if (threadIdx.x == 0) {
    int orv = edges[1] | edges[3] | edges[5] | edges[7] | edges[9] | edges[11] | edges[13] | edges[15];
    flag[0] = (orv == 0) ? 1 : 0;  // 1 => int64 layout (shift word index by 1)
  }
}

__global__ __launch_bounds__(256) void zero_i32_kernel(int* __restrict__ p, int n)
{
  int i = blockIdx.x * 256 + threadIdx.x;
  if (i < n) p[i] = 0;
}

// A: histogram over (dst>>8, blockIdx&7)
__global__ __launch_bounds__(256) void bucket_hist_kernel(
    const int* __restrict__ edges, int E, int N, const int* __restrict__ flag,
    int* __restrict__ bhist8)
{
  int e = blockIdx.x * 256 + threadIdx.x;
  if (e >= E) return;
  int g = blockIdx.x & 7;
  int sh = flag[0];
  int d = edges[(E + e) << sh];
  if ((unsigned)d < (unsigned)N) atomicAdd(&bhist8[((d >> 8) << 3) + g], 1);
}

// B: exclusive scan over m = NBK*8 entries (single block, 24 per thread)
__global__ __launch_bounds__(1024) void scan_buckets8_kernel(
    const int* __restrict__ bhist8, int m,
    int* __restrict__ bstart8, int* __restrict__ bcursor8,
    int* __restrict__ rowptr, int N, int E)
{
  __shared__ int sm[1024];
  const int PER = 24;
  int t = threadIdx.x;
  int base = t * PER;
  int vals[PER];
  int s = 0;
#pragma unroll
  for (int i = 0; i < PER; i++) {
    int idx = base + i;
    int v = (idx < m) ? bhist8[idx] : 0;
    vals[i] = v;
    s += v;
  }
  sm[t] = s;
  __syncthreads();
  for (int off = 1; off < 1024; off <<= 1) {
    int x = 0;
    if (t >= off) x = sm[t - off];
    __syncthreads();
    if (t >= off) sm[t] += x;
    __syncthreads();
  }
  int run = sm[t] - s;  // exclusive prefix of this thread's first element
#pragma unroll
  for (int i = 0; i < PER; i++) {
    int idx = base + i;
    if (idx < m) { bstart8[idx] = run; bcursor8[idx] = run; }
    run += vals[i];
  }
  if (t == 0) { bstart8[m] = E; rowptr[N] = E; }
}

// C: partition edges into (bucket, group) slices; packed word = src | (dst&255)<<20
__global__ __launch_bounds__(256) void partition_kernel(
    const int* __restrict__ edges, int E, int N, const int* __restrict__ flag,
    int* __restrict__ bcursor8, int* __restrict__ pair)
{
  int e = blockIdx.x * 256 + threadIdx.x;
  if (e >= E) return;
  int g = blockIdx.x & 7;
  int sh = flag[0];
  int s = edges[e << sh];
  int d = edges[(E + e) << sh];
  if ((unsigned)s >= (unsigned)N || (unsigned)d >= (unsigned)N) return;
  int pos = atomicAdd(&bcursor8[((d >> 8) << 3) + g], 1);
  pair[pos] = s | ((d & 255) << 20);
}

// D: per-bucket CSR build: LDS hist -> LDS scan -> rowptr/dinv -> place edges (LDS cursors)
__global__ __launch_bounds__(256) void build_kernel(
    const int* __restrict__ pair, const int* __restrict__ bstart8,
    int* __restrict__ rowptr, float* __restrict__ dinv, int* __restrict__ col, int N)
{
  __shared__ int hist[256];
  __shared__ int sc[256];
  __shared__ int cur[256];
  int b = blockIdx.x;
  int t = threadIdx.x;
  int pbeg = bstart8[b << 3], pend = bstart8[(b + 1) << 3];
  hist[t] = 0;
  __syncthreads();
  for (int p = pbeg + t; p < pend; p += 256) {
    int v = pair[p];
    atomicAdd(&hist[(v >> 20) & 255], 1);
  }
  __syncthreads();
  int val = hist[t];
  sc[t] = val;
  __syncthreads();
  for (int off = 1; off < 256; off <<= 1) {
    int x = 0;
    if (t >= off) x = sc[t - off];
    __syncthreads();
    if (t >= off) sc[t] += x;
    __syncthreads();
  }
  int excl = sc[t] - val;
  int row = (b << 8) + t;
  int rp = pbeg + excl;
  cur[t] = rp;
  if (row < N) {
    rowptr[row] = rp;
    dinv[row] = rsqrtf((float)(val + 1));  // deg = dst-count + 1 (self loop)
  }
  __syncthreads();
  for (int p = pbeg + t; p < pend; p += 256) {
    int v = pair[p];
    int pos = atomicAdd(&cur[(v >> 20) & 255], 1);
    col[pos] = v & 0xFFFFF;
  }
}

// g1[n,j] = dinv[n] * sum_k x[n,k]*W1[k,j]   (K=32, wave per node, lane=j, grid-stride)
__global__ __launch_bounds__(256) void mm1_kernel(
    const float* __restrict__ X, const float* __restrict__ W1,
    const float* __restrict__ dinv, __half* __restrict__ G, int n)
{
  int lane = threadIdx.x & 63;
  float Wr[32];
#pragma unroll
  for (int k = 0; k < 32; k++) Wr[k] = W1[k * 64 + lane];
  int wave = (blockIdx.x * 256 + threadIdx.x) >> 6;
  int nw = (gridDim.x * 256) >> 6;
  for (int node = wave; node < n; node += nw) {
    int un = __builtin_amdgcn_readfirstlane(node);
    float xv = X[(size_t)un * 32 + (lane & 31)];  // lanes 0..31 hold the row
    float acc = 0.f;
#pragma unroll
    for (int k = 0; k < 32; k++) acc += __shfl(xv, k) * Wr[k];
    G[(size_t)un * 64 + lane] = __float2half(dinv[un] * acc);
  }
}

// u1[n,:] = dinv[n] * relu(dinv[n]*(sum_{e in row n} g1[col[e],:] + g1[n,:]) + b1)
__global__ __launch_bounds__(256) void agg1_kernel(
    const __half* __restrict__ G, const int* __restrict__ rowptr,
    const int* __restrict__ col, const float* __restrict__ dinv,
    const float* __restrict__ bias, __half* __restrict__ U, int n)
{
  int lane = threadIdx.x & 63;
  int wave = (blockIdx.x * 256 + threadIdx.x) >> 6;
  if (wave >= n) return;
  int un = __builtin_amdgcn_readfirstlane(wave);
  float di = dinv[un];
  float acc = __half2float(G[(size_t)un * 64 + lane]);
  int e = rowptr[un], end = rowptr[un + 1];
  for (; e + 8 <= end; e += 8) {
    float v0 = __half2float(G[(size_t)col[e + 0] * 64 + lane]);
    float v1 = __half2float(G[(size_t)col[e + 1] * 64 + lane]);
    float v2 = __half2float(G[(size_t)col[e + 2] * 64 + lane]);
    float v3 = __half2float(G[(size_t)col[e + 3] * 64 + lane]);
    float v4 = __half2float(G[(size_t)col[e + 4] * 64 + lane]);
    float v5 = __half2float(G[(size_t)col[e + 5] * 64 + lane]);
    float v6 = __half2float(G[(size_t)col[e + 6] * 64 + lane]);
    float v7 = __half2float(G[(size_t)col[e + 7] * 64 + lane]);
    acc += ((v0 + v1) + (v2 + v3)) + ((v4 + v5) + (v6 + v7));
  }
  for (; e < end; e++) acc += __half2float(G[(size_t)col[e] * 64 + lane]);
  float h = di * acc + bias[lane];
  h = h > 0.f ? h : 0.f;
  U[(size_t)un * 64 + lane] = __float2half(di * h);
}

// a2[n,:] = dinv[n] * (sum_{e in row n} u1[col[e],:] + u1[n,:])
__global__ __launch_bounds__(256) void agg2_kernel(
    const __half* __restrict__ U, const int* __restrict__ rowptr,
    const int* __restrict__ col, const float* __restrict__ dinv,
    __half* __restrict__ A2, int n)
{
  int lane = threadIdx.x & 63;
  int wave = (blockIdx.x * 256 + threadIdx.x) >> 6;
  if (wave >= n) return;
  int un = __builtin_amdgcn_readfirstlane(wave);
  float acc = __half2float(U[(size_t)un * 64 + lane]);
  int e = rowptr[un], end = rowptr[un + 1];
  for (; e + 8 <= end; e += 8) {
    float v0 = __half2float(U[(size_t)col[e + 0] * 64 + lane]);
    float v1 = __half2float(U[(size_t)col[e + 1] * 64 + lane]);
    float v2 = __half2float(U[(size_t)col[e + 2] * 64 + lane]);
    float v3 = __half2float(U[(size_t)col[e + 3] * 64 + lane]);
    float v4 = __half2float(U[(size_t)col[e + 4] * 64 + lane]);
    float v5 = __half2float(U[(size_t)col[e + 5] * 64 + lane]);
    float v6 = __half2float(U[(size_t)col[e + 6] * 64 + lane]);
    float v7 = __half2float(U[(size_t)col[e + 7] * 64 + lane]);
    acc += ((v0 + v1) + (v2 + v3)) + ((v4 + v5) + (v6 + v7));
  }
  for (; e < end; e++) acc += __half2float(U[(size_t)col[e] * 64 + lane]);
  A2[(size_t)un * 64 + lane] = __float2half(dinv[un] * acc);
}

__global__ __launch_bounds__(256) void out_init_kernel(
    float* __restrict__ out, const float* __restrict__ bfc, int n)
{
  int i = blockIdx.x * 256 + threadIdx.x;
  if (i < n) out[i] = bfc[0];
}

// MFMA fused layer2-matmul + relu + FC (validated R4):
// per wave: 16 nodes; D[16][64] = A2tile @ W2 via 8x mfma_f32_16x16x32_f16;
// h2 = relu(D + b2); out[node/14] += sum_j h2[node][j]*Wfc[(node%14)*64+j]
__global__ __launch_bounds__(256) void mfma_final_kernel(
    const __half* __restrict__ A2, const float* __restrict__ W2,
    const float* __restrict__ b2, const float* __restrict__ Wfc,
    float* __restrict__ out, int ntiles)
{
  int lane = threadIdx.x & 63;
  int n16 = lane & 15;
  int quad = lane >> 4;

  half8 bf[4][2];
#pragma unroll
  for (int jb = 0; jb < 4; jb++)
#pragma unroll
    for (int kf = 0; kf < 2; kf++)
#pragma unroll
      for (int i = 0; i < 8; i++)
        bf[jb][kf][i] = (_Float16)W2[(kf * 32 + quad * 8 + i) * 64 + jb * 16 + n16];
  float b2j[4];
#pragma unroll
  for (int jb = 0; jb < 4; jb++) b2j[jb] = b2[jb * 16 + n16];

  const _Float16* A2h = (const _Float16*)A2;
  int wave = (blockIdx.x * 256 + threadIdx.x) >> 6;
  int nw = (gridDim.x * 256) >> 6;
  for (int tile = wave; tile < ntiles; tile += nw) {
    int ut = __builtin_amdgcn_readfirstlane(tile);
    int base = ut * 16;
    const _Float16* arow = A2h + (size_t)(base + n16) * 64 + quad * 8;
    half8 a0 = *(const half8*)(arow);
    half8 a1 = *(const half8*)(arow + 32);

    int g_r[4], t_r[4];
#pragma unroll
    for (int r = 0; r < 4; r++) {
      int node = base + quad * 4 + r;
      g_r[r] = node / 14;
      t_r[r] = node - g_r[r] * 14;
    }
    float pr[4] = {0.f, 0.f, 0.f, 0.f};
#pragma unroll
    for (int jb = 0; jb < 4; jb++) {
      float4v acc = {0.f, 0.f, 0.f, 0.f};
      acc = __builtin_amdgcn_mfma_f32_16x16x32_f16(a0, bf[jb][0], acc, 0, 0, 0);
      acc = __builtin_amdgcn_mfma_f32_16x16x32_f16(a1, bf[jb][1], acc, 0, 0, 0);
      int j = jb * 16 + n16;
#pragma unroll
      for (int r = 0; r < 4; r++) {
        float h = acc[r] + b2j[jb];
        h = h > 0.f ? h : 0.f;
        pr[r] += h * Wfc[t_r[r] * 64 + j];
      }
    }
#pragma unroll
    for (int r = 0; r < 4; r++) {
#pragma unroll
      for (int off = 1; off < 16; off <<= 1) pr[r] += __shfl_xor(pr[r], off);
    }
    if (n16 == 0) {
#pragma unroll
      for (int r = 0; r < 4; r++) atomicAdd(&out[g_r[r]], pr[r]);
    }
  }
}

extern "C" void kernel_launch(void* const* d_in, const int* in_sizes, int n_in,
                              void* d_out, int out_size, void* d_ws, size_t ws_size,
                              hipStream_t stream)
{
  const float* x = (const float*)d_in[0];
  const int* edges = (const int*)d_in[1];
  const float* W1 = (const float*)d_in[2];
  const float* b1 = (const float*)d_in[3];
  const float* W2 = (const float*)d_in[4];
  const float* b2 = (const float*)d_in[5];
  const float* Wfc = (const float*)d_in[6];
  const float* bfc = (const float*)d_in[7];
  float* out = (float*)d_out;
  (void)n_in;

  const int N = in_sizes[0] / 32;  // 700000
  const int E = in_sizes[1] / 2;   // 4000000
  const int B = out_size;          // 50000
  const int NBK = (N + 255) >> 8;  // 2735 buckets (dst>>8)
  const int NBK8 = NBK * 8;        // 21880 (bucket, xcd-group) slices

  char* ws = (char*)d_ws;
  size_t off = 0;
  auto alloc = [&](size_t bytes) -> void* {
    void* p = ws + off;
    off += (bytes + 255) & ~(size_t)255;
    return p;
  };
  int* flag = (int*)alloc(256);
  int* bhist8 = (int*)alloc((size_t)NBK8 * 4);
  int* bstart8 = (int*)alloc(((size_t)NBK8 + 1) * 4);
  int* bcursor8 = (int*)alloc((size_t)NBK8 * 4);
  int* col = (int*)alloc((size_t)E * 4);
  int* rowptr = (int*)alloc(((size_t)N + 1) * 4);
  float* dinv = (float*)alloc((size_t)N * 4);
  __half* F1 = (__half*)alloc(((size_t)N + 16) * 64 * 2);  // g1, later a2; head aliased as pairbuf
  __half* F2 = (__half*)alloc(((size_t)N + 16) * 64 * 2);  // u1
  int* pair = (int*)F1;  // pairbuf (E*4 = 16MB) dead before mm1 writes F1

  if (off > ws_size) {
    float v = -(float)(double)(ws_size >> 20);
    fallback_kernel<<<(B + 255) / 256, 256, 0, stream>>>(out, B, v);
    return;
  }

  probe_kernel<<<1, 64, 0, stream>>>(edges, flag);
  zero_i32_kernel<<<(NBK8 + 255) / 256, 256, 0, stream>>>(bhist8, NBK8);
  bucket_hist_kernel<<<(E + 255) / 256, 256, 0, stream>>>(edges, E, N, flag, bhist8);
  scan_buckets8_kernel<<<1, 1024, 0, stream>>>(bhist8, NBK8, bstart8, bcursor8, rowptr, N, E);
  partition_kernel<<<(E + 255) / 256, 256, 0, stream>>>(edges, E, N, flag, bcursor8, pair);
  build_kernel<<<NBK, 256, 0, stream>>>(pair, bstart8, rowptr, dinv, col, N);

  int aggBlocks = (N * 64 + 255) / 256;  // one wave per node
  mm1_kernel<<<8192, 256, 0, stream>>>(x, W1, dinv, F1, N);
  agg1_kernel<<<aggBlocks, 256, 0, stream>>>(F1, rowptr, col, dinv, b1, F2, N);
  agg2_kernel<<<aggBlocks, 256, 0, stream>>>(F2, rowptr, col, dinv, F1, N);
  out_init_kernel<<<(B + 255) / 256, 256, 0, stream>>>(out, bfc, B);
  int ntiles = (N + 15) / 16;  // 43750
  mfma_final_kernel<<<2048, 256, 0, stream>>>(F1, W2, b2, Wfc, out, ntiles);
}

// Round 7
// 1141.633 us; speedup vs baseline: 1.4947x; 1.1598x over previous
//
#include <hip/hip_runtime.h>
#include <hip/hip_fp16.h>

// GCN: h1 = relu(gcn(x,W1,b1)); h2 = relu(gcn(h1,W2,b2)); out = h2.reshape(B,896)@Wfc + bfc
// Factored: g1 = dinv*(x@W1); h1 = relu(dinv*agg(g1)+b1); u1 = dinv*h1;
//           a2 = dinv*agg(u1);  h2 = relu(a2@W2+b2)  [agg commutes with @W2]
// CSR via dst>>8 buckets with XCD-sliced (blockIdx&7) cursors (single-writer-XCD lines).
// mm1 and layer2+FC both on MFMA (fp16 16x16x32). Features fp16.

typedef _Float16 half8 __attribute__((ext_vector_type(8)));
typedef float float4v __attribute__((ext_vector_type(4)));

__global__ __launch_bounds__(256) void fallback_kernel(float* __restrict__ out, int n, float v)
{
  int i = blockIdx.x * 256 + threadIdx.x;
  if (i < n) out[i] = v;
}

// detect edges dtype: int64 values < 2^31 -> every odd int32 word is 0
__global__ __launch_bounds__(64) void probe_kernel(const int* __restrict__ edges, int* __restrict__ flag)
{
  if (threadIdx.x == 0) {
    int orv = edges[1] | edges[3] | edges[5] | edges[7] | edges[9] | edges[11] | edges[13] | edges[15];
    flag[0] = (orv == 0) ? 1 : 0;  // 1 => int64 layout (shift word index by 1)
  }
}

__global__ __launch_bounds__(256) void zero_i32_kernel(int* __restrict__ p, int n)
{
  int i = blockIdx.x * 256 + threadIdx.x;
  if (i < n) p[i] = 0;
}

// A: histogram over (dst>>8, blockIdx&7)
__global__ __launch_bounds__(256) void bucket_hist_kernel(
    const int* __restrict__ edges, int E, int N, const int* __restrict__ flag,
    int* __restrict__ bhist8)
{
  int e = blockIdx.x * 256 + threadIdx.x;
  if (e >= E) return;
  int g = blockIdx.x & 7;
  int sh = flag[0];
  int d = edges[(E + e) << sh];
  if ((unsigned)d < (unsigned)N) atomicAdd(&bhist8[((d >> 8) << 3) + g], 1);
}

// B: exclusive scan over m = NBK*8 entries (single block, 24 per thread)
__global__ __launch_bounds__(1024) void scan_buckets8_kernel(
    const int* __restrict__ bhist8, int m,
    int* __restrict__ bstart8, int* __restrict__ bcursor8,
    int* __restrict__ rowptr, int N, int E)
{
  __shared__ int sm[1024];
  const int PER = 24;
  int t = threadIdx.x;
  int base = t * PER;
  int vals[PER];
  int s = 0;
#pragma unroll
  for (int i = 0; i < PER; i++) {
    int idx = base + i;
    int v = (idx < m) ? bhist8[idx] : 0;
    vals[i] = v;
    s += v;
  }
  sm[t] = s;
  __syncthreads();
  for (int off = 1; off < 1024; off <<= 1) {
    int x = 0;
    if (t >= off) x = sm[t - off];
    __syncthreads();
    if (t >= off) sm[t] += x;
    __syncthreads();
  }
  int run = sm[t] - s;
#pragma unroll
  for (int i = 0; i < PER; i++) {
    int idx = base + i;
    if (idx < m) { bstart8[idx] = run; bcursor8[idx] = run; }
    run += vals[i];
  }
  if (t == 0) { bstart8[m] = E; rowptr[N] = E; }
}

// C: partition edges into (bucket, group) slices; packed word = src | (dst&255)<<20
__global__ __launch_bounds__(256) void partition_kernel(
    const int* __restrict__ edges, int E, int N, const int* __restrict__ flag,
    int* __restrict__ bcursor8, int* __restrict__ pair)
{
  int e = blockIdx.x * 256 + threadIdx.x;
  if (e >= E) return;
  int g = blockIdx.x & 7;
  int sh = flag[0];
  int s = edges[e << sh];
  int d = edges[(E + e) << sh];
  if ((unsigned)s >= (unsigned)N || (unsigned)d >= (unsigned)N) return;
  int pos = atomicAdd(&bcursor8[((d >> 8) << 3) + g], 1);
  pair[pos] = s | ((d & 255) << 20);
}

// D: per-bucket CSR build: LDS hist -> LDS scan -> rowptr/dinv -> place edges (LDS cursors)
__global__ __launch_bounds__(256) void build_kernel(
    const int* __restrict__ pair, const int* __restrict__ bstart8,
    int* __restrict__ rowptr, float* __restrict__ dinv, int* __restrict__ col, int N)
{
  __shared__ int hist[256];
  __shared__ int sc[256];
  __shared__ int cur[256];
  int b = blockIdx.x;
  int t = threadIdx.x;
  int pbeg = bstart8[b << 3], pend = bstart8[(b + 1) << 3];
  hist[t] = 0;
  __syncthreads();
  for (int p = pbeg + t; p < pend; p += 256) {
    int v = pair[p];
    atomicAdd(&hist[(v >> 20) & 255], 1);
  }
  __syncthreads();
  int val = hist[t];
  sc[t] = val;
  __syncthreads();
  for (int off = 1; off < 256; off <<= 1) {
    int x = 0;
    if (t >= off) x = sc[t - off];
    __syncthreads();
    if (t >= off) sc[t] += x;
    __syncthreads();
  }
  int excl = sc[t] - val;
  int row = (b << 8) + t;
  int rp = pbeg + excl;
  cur[t] = rp;
  if (row < N) {
    rowptr[row] = rp;
    dinv[row] = rsqrtf((float)(val + 1));  // deg = dst-count + 1 (self loop)
  }
  __syncthreads();
  for (int p = pbeg + t; p < pend; p += 256) {
    int v = pair[p];
    int pos = atomicAdd(&cur[(v >> 20) & 255], 1);
    col[pos] = v & 0xFFFFF;
  }
}

// MFMA mm1: per wave, 16 nodes; D[16][64] = x-tile(fp16) @ W1; G = dinv*D (fp16).
// A-frag: lane holds A[m=lane&15][k=quad*8+i]; B-frag: B[k=quad*8+i][n=lane&15]
// C/D:    lane holds D[row=quad*4+r][col=lane&15]
__global__ __launch_bounds__(256) void mfma_mm1_kernel(
    const float* __restrict__ X, const float* __restrict__ W1,
    const float* __restrict__ dinv, __half* __restrict__ G, int n, int ntiles)
{
  int lane = threadIdx.x & 63;
  int n16 = lane & 15;
  int quad = lane >> 4;

  half8 bf[4];
#pragma unroll
  for (int jb = 0; jb < 4; jb++)
#pragma unroll
    for (int i = 0; i < 8; i++)
      bf[jb][i] = (_Float16)W1[(quad * 8 + i) * 64 + jb * 16 + n16];

  _Float16* Gh = (_Float16*)G;
  int wave = (blockIdx.x * 256 + threadIdx.x) >> 6;
  int nw = (gridDim.x * 256) >> 6;
  for (int tile = wave; tile < ntiles; tile += nw) {
    int ut = __builtin_amdgcn_readfirstlane(tile);
    int base = ut * 16;
    int node = base + n16;
    if (node >= n) node = n - 1;
    const float* xr = X + (size_t)node * 32 + quad * 8;
    half8 a;
#pragma unroll
    for (int i = 0; i < 8; i++) a[i] = (_Float16)xr[i];

    float4v acc[4];
#pragma unroll
    for (int jb = 0; jb < 4; jb++) {
      float4v z = {0.f, 0.f, 0.f, 0.f};
      acc[jb] = __builtin_amdgcn_mfma_f32_16x16x32_f16(a, bf[jb], z, 0, 0, 0);
    }
#pragma unroll
    for (int r = 0; r < 4; r++) {
      int node2 = base + quad * 4 + r;
      if (node2 < n) {
        float dv = dinv[node2];
#pragma unroll
        for (int jb = 0; jb < 4; jb++)
          Gh[(size_t)node2 * 64 + jb * 16 + n16] = (_Float16)(dv * acc[jb][r]);
      }
    }
  }
}

// u1[n,:] = dinv[n] * relu(dinv[n]*(sum_{e in row n} g1[col[e],:] + g1[n,:]) + b1)
__global__ __launch_bounds__(256) void agg1_kernel(
    const __half* __restrict__ G, const int* __restrict__ rowptr,
    const int* __restrict__ col, const float* __restrict__ dinv,
    const float* __restrict__ bias, __half* __restrict__ U, int n)
{
  int lane = threadIdx.x & 63;
  int wave = (blockIdx.x * 256 + threadIdx.x) >> 6;
  if (wave >= n) return;
  int un = __builtin_amdgcn_readfirstlane(wave);
  float di = dinv[un];
  float acc = __half2float(G[(size_t)un * 64 + lane]);
  int e = rowptr[un], end = rowptr[un + 1];
  for (; e + 8 <= end; e += 8) {
    float v0 = __half2float(G[(size_t)col[e + 0] * 64 + lane]);
    float v1 = __half2float(G[(size_t)col[e + 1] * 64 + lane]);
    float v2 = __half2float(G[(size_t)col[e + 2] * 64 + lane]);
    float v3 = __half2float(G[(size_t)col[e + 3] * 64 + lane]);
    float v4 = __half2float(G[(size_t)col[e + 4] * 64 + lane]);
    float v5 = __half2float(G[(size_t)col[e + 5] * 64 + lane]);
    float v6 = __half2float(G[(size_t)col[e + 6] * 64 + lane]);
    float v7 = __half2float(G[(size_t)col[e + 7] * 64 + lane]);
    acc += ((v0 + v1) + (v2 + v3)) + ((v4 + v5) + (v6 + v7));
  }
  for (; e < end; e++) acc += __half2float(G[(size_t)col[e] * 64 + lane]);
  float h = di * acc + bias[lane];
  h = h > 0.f ? h : 0.f;
  U[(size_t)un * 64 + lane] = __float2half(di * h);
}

// a2[n,:] = dinv[n] * (sum_{e in row n} u1[col[e],:] + u1[n,:])
__global__ __launch_bounds__(256) void agg2_kernel(
    const __half* __restrict__ U, const int* __restrict__ rowptr,
    const int* __restrict__ col, const float* __restrict__ dinv,
    __half* __restrict__ A2, int n)
{
  int lane = threadIdx.x & 63;
  int wave = (blockIdx.x * 256 + threadIdx.x) >> 6;
  if (wave >= n) return;
  int un = __builtin_amdgcn_readfirstlane(wave);
  float acc = __half2float(U[(size_t)un * 64 + lane]);
  int e = rowptr[un], end = rowptr[un + 1];
  for (; e + 8 <= end; e += 8) {
    float v0 = __half2float(U[(size_t)col[e + 0] * 64 + lane]);
    float v1 = __half2float(U[(size_t)col[e + 1] * 64 + lane]);
    float v2 = __half2float(U[(size_t)col[e + 2] * 64 + lane]);
    float v3 = __half2float(U[(size_t)col[e + 3] * 64 + lane]);
    float v4 = __half2float(U[(size_t)col[e + 4] * 64 + lane]);
    float v5 = __half2float(U[(size_t)col[e + 5] * 64 + lane]);
    float v6 = __half2float(U[(size_t)col[e + 6] * 64 + lane]);
    float v7 = __half2float(U[(size_t)col[e + 7] * 64 + lane]);
    acc += ((v0 + v1) + (v2 + v3)) + ((v4 + v5) + (v6 + v7));
  }
  for (; e < end; e++) acc += __half2float(U[(size_t)col[e] * 64 + lane]);
  A2[(size_t)un * 64 + lane] = __float2half(dinv[un] * acc);
}

__global__ __launch_bounds__(256) void out_init_kernel(
    float* __restrict__ out, const float* __restrict__ bfc, int n)
{
  int i = blockIdx.x * 256 + threadIdx.x;
  if (i < n) out[i] = bfc[0];
}

// MFMA fused layer2-matmul + relu + FC (validated R4)
__global__ __launch_bounds__(256) void mfma_final_kernel(
    const __half* __restrict__ A2, const float* __restrict__ W2,
    const float* __restrict__ b2, const float* __restrict__ Wfc,
    float* __restrict__ out, int ntiles)
{
  int lane = threadIdx.x & 63;
  int n16 = lane & 15;
  int quad = lane >> 4;

  half8 bf[4][2];
#pragma unroll
  for (int jb = 0; jb < 4; jb++)
#pragma unroll
    for (int kf = 0; kf < 2; kf++)
#pragma unroll
      for (int i = 0; i < 8; i++)
        bf[jb][kf][i] = (_Float16)W2[(kf * 32 + quad * 8 + i) * 64 + jb * 16 + n16];
  float b2j[4];
#pragma unroll
  for (int jb = 0; jb < 4; jb++) b2j[jb] = b2[jb * 16 + n16];

  const _Float16* A2h = (const _Float16*)A2;
  int wave = (blockIdx.x * 256 + threadIdx.x) >> 6;
  int nw = (gridDim.x * 256) >> 6;
  for (int tile = wave; tile < ntiles; tile += nw) {
    int ut = __builtin_amdgcn_readfirstlane(tile);
    int base = ut * 16;
    const _Float16* arow = A2h + (size_t)(base + n16) * 64 + quad * 8;
    half8 a0 = *(const half8*)(arow);
    half8 a1 = *(const half8*)(arow + 32);

    int g_r[4], t_r[4];
#pragma unroll
    for (int r = 0; r < 4; r++) {
      int node = base + quad * 4 + r;
      g_r[r] = node / 14;
      t_r[r] = node - g_r[r] * 14;
    }
    float pr[4] = {0.f, 0.f, 0.f, 0.f};
#pragma unroll
    for (int jb = 0; jb < 4; jb++) {
      float4v acc = {0.f, 0.f, 0.f, 0.f};
      acc = __builtin_amdgcn_mfma_f32_16x16x32_f16(a0, bf[jb][0], acc, 0, 0, 0);
      acc = __builtin_amdgcn_mfma_f32_16x16x32_f16(a1, bf[jb][1], acc, 0, 0, 0);
      int j = jb * 16 + n16;
#pragma unroll
      for (int r = 0; r < 4; r++) {
        float h = acc[r] + b2j[jb];
        h = h > 0.f ? h : 0.f;
        pr[r] += h * Wfc[t_r[r] * 64 + j];
      }
    }
#pragma unroll
    for (int r = 0; r < 4; r++) {
#pragma unroll
      for (int off = 1; off < 16; off <<= 1) pr[r] += __shfl_xor(pr[r], off);
    }
    if (n16 == 0) {
#pragma unroll
      for (int r = 0; r < 4; r++) atomicAdd(&out[g_r[r]], pr[r]);
    }
  }
}

extern "C" void kernel_launch(void* const* d_in, const int* in_sizes, int n_in,
                              void* d_out, int out_size, void* d_ws, size_t ws_size,
                              hipStream_t stream)
{
  const float* x = (const float*)d_in[0];
  const int* edges = (const int*)d_in[1];
  const float* W1 = (const float*)d_in[2];
  const float* b1 = (const float*)d_in[3];
  const float* W2 = (const float*)d_in[4];
  const float* b2 = (const float*)d_in[5];
  const float* Wfc = (const float*)d_in[6];
  const float* bfc = (const float*)d_in[7];
  float* out = (float*)d_out;
  (void)n_in;

  const int N = in_sizes[0] / 32;  // 700000
  const int E = in_sizes[1] / 2;   // 4000000
  const int B = out_size;          // 50000
  const int NBK = (N + 255) >> 8;  // 2735 buckets (dst>>8)
  const int NBK8 = NBK * 8;        // 21880 (bucket, xcd-group) slices

  char* ws = (char*)d_ws;
  size_t off = 0;
  auto alloc = [&](size_t bytes) -> void* {
    void* p = ws + off;
    off += (bytes + 255) & ~(size_t)255;
    return p;
  };
  int* flag = (int*)alloc(256);
  int* bhist8 = (int*)alloc((size_t)NBK8 * 4);
  int* bstart8 = (int*)alloc(((size_t)NBK8 + 1) * 4);
  int* bcursor8 = (int*)alloc((size_t)NBK8 * 4);
  int* col = (int*)alloc((size_t)E * 4);
  int* rowptr = (int*)alloc(((size_t)N + 1) * 4);
  float* dinv = (float*)alloc((size_t)N * 4);
  __half* F1 = (__half*)alloc(((size_t)N + 16) * 64 * 2);  // g1, later a2; head aliased as pairbuf
  __half* F2 = (__half*)alloc(((size_t)N + 16) * 64 * 2);  // u1
  int* pair = (int*)F1;  // pairbuf (E*4 = 16MB) dead before mm1 writes F1

  if (off > ws_size) {
    float v = -(float)(double)(ws_size >> 20);
    fallback_kernel<<<(B + 255) / 256, 256, 0, stream>>>(out, B, v);
    return;
  }

  probe_kernel<<<1, 64, 0, stream>>>(edges, flag);
  zero_i32_kernel<<<(NBK8 + 255) / 256, 256, 0, stream>>>(bhist8, NBK8);
  bucket_hist_kernel<<<(E + 255) / 256, 256, 0, stream>>>(edges, E, N, flag, bhist8);
  scan_buckets8_kernel<<<1, 1024, 0, stream>>>(bhist8, NBK8, bstart8, bcursor8, rowptr, N, E);
  partition_kernel<<<(E + 255) / 256, 256, 0, stream>>>(edges, E, N, flag, bcursor8, pair);
  build_kernel<<<NBK, 256, 0, stream>>>(pair, bstart8, rowptr, dinv, col, N);

  int ntiles = (N + 15) / 16;  // 43750
  int aggBlocks = (N * 64 + 255) / 256;  // one wave per node
  mfma_mm1_kernel<<<4096, 256, 0, stream>>>(x, W1, dinv, F1, N, ntiles);
  agg1_kernel<<<aggBlocks, 256, 0, stream>>>(F1, rowptr, col, dinv, b1, F2, N);
  agg2_kernel<<<aggBlocks, 256, 0, stream>>>(F2, rowptr, col, dinv, F1, N);
  out_init_kernel<<<(B + 255) / 256, 256, 0, stream>>>(out, bfc, B);
  mfma_final_kernel<<<2048, 256, 0, stream>>>(F1, W2, b2, Wfc, out, ntiles);
}

// Round 8
// 1056.177 us; speedup vs baseline: 1.6156x; 1.0809x over previous
//
#include <hip/hip_runtime.h>
#include <hip/hip_fp16.h>

// GCN: h1 = relu(gcn(x,W1,b1)); h2 = relu(gcn(h1,W2,b2)); out = h2.reshape(B,896)@Wfc + bfc
// Factored: g1 = dinv*(x@W1); h1 = relu(dinv*agg(g1)+b1); u1 = dinv*h1;
//           a2 = dinv*agg(u1);  h2 = relu(a2@W2+b2)  [agg commutes with @W2]
// CSR via dst>>8 buckets with XCD-sliced (blockIdx&7) cursors (single-writer-XCD lines).
// mm1 and layer2+FC on MFMA. Aggs use predicated 8-wide gather batches so every
// row keeps 8 loads in flight (avg deg 5.7 made the old remainder loop serial).

typedef _Float16 half8 __attribute__((ext_vector_type(8)));
typedef float float4v __attribute__((ext_vector_type(4)));

__global__ __launch_bounds__(256) void fallback_kernel(float* __restrict__ out, int n, float v)
{
  int i = blockIdx.x * 256 + threadIdx.x;
  if (i < n) out[i] = v;
}

// detect edges dtype: int64 values < 2^31 -> every odd int32 word is 0
__global__ __launch_bounds__(64) void probe_kernel(const int* __restrict__ edges, int* __restrict__ flag)
{
  if (threadIdx.x == 0) {
    int orv = edges[1] | edges[3] | edges[5] | edges[7] | edges[9] | edges[11] | edges[13] | edges[15];
    flag[0] = (orv == 0) ? 1 : 0;  // 1 => int64 layout (shift word index by 1)
  }
}

__global__ __launch_bounds__(256) void zero_i32_kernel(int* __restrict__ p, int n)
{
  int i = blockIdx.x * 256 + threadIdx.x;
  if (i < n) p[i] = 0;
}

// A: histogram over (dst>>8, blockIdx&7)
__global__ __launch_bounds__(256) void bucket_hist_kernel(
    const int* __restrict__ edges, int E, int N, const int* __restrict__ flag,
    int* __restrict__ bhist8)
{
  int e = blockIdx.x * 256 + threadIdx.x;
  if (e >= E) return;
  int g = blockIdx.x & 7;
  int sh = flag[0];
  int d = edges[(E + e) << sh];
  if ((unsigned)d < (unsigned)N) atomicAdd(&bhist8[((d >> 8) << 3) + g], 1);
}

// B: exclusive scan over m = NBK*8 entries (single block, 24 per thread)
__global__ __launch_bounds__(1024) void scan_buckets8_kernel(
    const int* __restrict__ bhist8, int m,
    int* __restrict__ bstart8, int* __restrict__ bcursor8,
    int* __restrict__ rowptr, int N, int E)
{
  __shared__ int sm[1024];
  const int PER = 24;
  int t = threadIdx.x;
  int base = t * PER;
  int vals[PER];
  int s = 0;
#pragma unroll
  for (int i = 0; i < PER; i++) {
    int idx = base + i;
    int v = (idx < m) ? bhist8[idx] : 0;
    vals[i] = v;
    s += v;
  }
  sm[t] = s;
  __syncthreads();
  for (int off = 1; off < 1024; off <<= 1) {
    int x = 0;
    if (t >= off) x = sm[t - off];
    __syncthreads();
    if (t >= off) sm[t] += x;
    __syncthreads();
  }
  int run = sm[t] - s;
#pragma unroll
  for (int i = 0; i < PER; i++) {
    int idx = base + i;
    if (idx < m) { bstart8[idx] = run; bcursor8[idx] = run; }
    run += vals[i];
  }
  if (t == 0) { bstart8[m] = E; rowptr[N] = E; }
}

// C: partition edges into (bucket, group) slices; packed word = src | (dst&255)<<20
__global__ __launch_bounds__(256) void partition_kernel(
    const int* __restrict__ edges, int E, int N, const int* __restrict__ flag,
    int* __restrict__ bcursor8, int* __restrict__ pair)
{
  int e = blockIdx.x * 256 + threadIdx.x;
  if (e >= E) return;
  int g = blockIdx.x & 7;
  int sh = flag[0];
  int s = edges[e << sh];
  int d = edges[(E + e) << sh];
  if ((unsigned)s >= (unsigned)N || (unsigned)d >= (unsigned)N) return;
  int pos = atomicAdd(&bcursor8[((d >> 8) << 3) + g], 1);
  pair[pos] = s | ((d & 255) << 20);
}

// D: per-bucket CSR build: LDS hist -> LDS scan -> rowptr/dinv -> place edges (LDS cursors)
__global__ __launch_bounds__(256) void build_kernel(
    const int* __restrict__ pair, const int* __restrict__ bstart8,
    int* __restrict__ rowptr, float* __restrict__ dinv, int* __restrict__ col, int N)
{
  __shared__ int hist[256];
  __shared__ int sc[256];
  __shared__ int cur[256];
  int b = blockIdx.x;
  int t = threadIdx.x;
  int pbeg = bstart8[b << 3], pend = bstart8[(b + 1) << 3];
  hist[t] = 0;
  __syncthreads();
  for (int p = pbeg + t; p < pend; p += 256) {
    int v = pair[p];
    atomicAdd(&hist[(v >> 20) & 255], 1);
  }
  __syncthreads();
  int val = hist[t];
  sc[t] = val;
  __syncthreads();
  for (int off = 1; off < 256; off <<= 1) {
    int x = 0;
    if (t >= off) x = sc[t - off];
    __syncthreads();
    if (t >= off) sc[t] += x;
    __syncthreads();
  }
  int excl = sc[t] - val;
  int row = (b << 8) + t;
  int rp = pbeg + excl;
  cur[t] = rp;
  if (row < N) {
    rowptr[row] = rp;
    dinv[row] = rsqrtf((float)(val + 1));  // deg = dst-count + 1 (self loop)
  }
  __syncthreads();
  for (int p = pbeg + t; p < pend; p += 256) {
    int v = pair[p];
    int pos = atomicAdd(&cur[(v >> 20) & 255], 1);
    col[pos] = v & 0xFFFFF;
  }
}

// MFMA mm1: per wave, 16 nodes; D[16][64] = x-tile(fp16) @ W1; G = dinv*D (fp16).
__global__ __launch_bounds__(256) void mfma_mm1_kernel(
    const float* __restrict__ X, const float* __restrict__ W1,
    const float* __restrict__ dinv, __half* __restrict__ G, int n, int ntiles)
{
  int lane = threadIdx.x & 63;
  int n16 = lane & 15;
  int quad = lane >> 4;

  half8 bf[4];
#pragma unroll
  for (int jb = 0; jb < 4; jb++)
#pragma unroll
    for (int i = 0; i < 8; i++)
      bf[jb][i] = (_Float16)W1[(quad * 8 + i) * 64 + jb * 16 + n16];

  _Float16* Gh = (_Float16*)G;
  int wave = (blockIdx.x * 256 + threadIdx.x) >> 6;
  int nw = (gridDim.x * 256) >> 6;
  for (int tile = wave; tile < ntiles; tile += nw) {
    int ut = __builtin_amdgcn_readfirstlane(tile);
    int base = ut * 16;
    int node = base + n16;
    if (node >= n) node = n - 1;
    const float* xr = X + (size_t)node * 32 + quad * 8;
    half8 a;
#pragma unroll
    for (int i = 0; i < 8; i++) a[i] = (_Float16)xr[i];

    float4v acc[4];
#pragma unroll
    for (int jb = 0; jb < 4; jb++) {
      float4v z = {0.f, 0.f, 0.f, 0.f};
      acc[jb] = __builtin_amdgcn_mfma_f32_16x16x32_f16(a, bf[jb], z, 0, 0, 0);
    }
#pragma unroll
    for (int r = 0; r < 4; r++) {
      int node2 = base + quad * 4 + r;
      if (node2 < n) {
        float dv = dinv[node2];
#pragma unroll
        for (int jb = 0; jb < 4; jb++)
          Gh[(size_t)node2 * 64 + jb * 16 + n16] = (_Float16)(dv * acc[jb][r]);
      }
    }
  }
}

// u1[n,:] = dinv[n] * relu(dinv[n]*(sum_{e in row n} g1[col[e],:] + g1[n,:]) + b1)
// Predicated 8-wide batches: always 8 independent gathers in flight per wave.
__global__ __launch_bounds__(256) void agg1_kernel(
    const __half* __restrict__ G, const int* __restrict__ rowptr,
    const int* __restrict__ col, const float* __restrict__ dinv,
    const float* __restrict__ bias, __half* __restrict__ U, int n)
{
  int lane = threadIdx.x & 63;
  int wave = (blockIdx.x * 256 + threadIdx.x) >> 6;
  if (wave >= n) return;
  int un = __builtin_amdgcn_readfirstlane(wave);
  float di = dinv[un];
  float acc = __half2float(G[(size_t)un * 64 + lane]);
  int beg = rowptr[un], end = rowptr[un + 1];
  for (int e = beg; e < end; e += 8) {
#pragma unroll
    for (int k = 0; k < 8; k++) {
      int idx = e + k;
      int c = col[idx < end ? idx : end - 1];
      float v = __half2float(G[(size_t)c * 64 + lane]);
      acc += (idx < end) ? v : 0.f;
    }
  }
  float h = di * acc + bias[lane];
  h = h > 0.f ? h : 0.f;
  U[(size_t)un * 64 + lane] = __float2half(di * h);
}

// a2[n,:] = dinv[n] * (sum_{e in row n} u1[col[e],:] + u1[n,:])
__global__ __launch_bounds__(256) void agg2_kernel(
    const __half* __restrict__ U, const int* __restrict__ rowptr,
    const int* __restrict__ col, const float* __restrict__ dinv,
    __half* __restrict__ A2, int n)
{
  int lane = threadIdx.x & 63;
  int wave = (blockIdx.x * 256 + threadIdx.x) >> 6;
  if (wave >= n) return;
  int un = __builtin_amdgcn_readfirstlane(wave);
  float acc = __half2float(U[(size_t)un * 64 + lane]);
  int beg = rowptr[un], end = rowptr[un + 1];
  for (int e = beg; e < end; e += 8) {
#pragma unroll
    for (int k = 0; k < 8; k++) {
      int idx = e + k;
      int c = col[idx < end ? idx : end - 1];
      float v = __half2float(U[(size_t)c * 64 + lane]);
      acc += (idx < end) ? v : 0.f;
    }
  }
  A2[(size_t)un * 64 + lane] = __float2half(dinv[un] * acc);
}

__global__ __launch_bounds__(256) void out_init_kernel(
    float* __restrict__ out, const float* __restrict__ bfc, int n)
{
  int i = blockIdx.x * 256 + threadIdx.x;
  if (i < n) out[i] = bfc[0];
}

// MFMA fused layer2-matmul + relu + FC (validated R4)
__global__ __launch_bounds__(256) void mfma_final_kernel(
    const __half* __restrict__ A2, const float* __restrict__ W2,
    const float* __restrict__ b2, const float* __restrict__ Wfc,
    float* __restrict__ out, int ntiles)
{
  int lane = threadIdx.x & 63;
  int n16 = lane & 15;
  int quad = lane >> 4;

  half8 bf[4][2];
#pragma unroll
  for (int jb = 0; jb < 4; jb++)
#pragma unroll
    for (int kf = 0; kf < 2; kf++)
#pragma unroll
      for (int i = 0; i < 8; i++)
        bf[jb][kf][i] = (_Float16)W2[(kf * 32 + quad * 8 + i) * 64 + jb * 16 + n16];
  float b2j[4];
#pragma unroll
  for (int jb = 0; jb < 4; jb++) b2j[jb] = b2[jb * 16 + n16];

  const _Float16* A2h = (const _Float16*)A2;
  int wave = (blockIdx.x * 256 + threadIdx.x) >> 6;
  int nw = (gridDim.x * 256) >> 6;
  for (int tile = wave; tile < ntiles; tile += nw) {
    int ut = __builtin_amdgcn_readfirstlane(tile);
    int base = ut * 16;
    const _Float16* arow = A2h + (size_t)(base + n16) * 64 + quad * 8;
    half8 a0 = *(const half8*)(arow);
    half8 a1 = *(const half8*)(arow + 32);

    int g_r[4], t_r[4];
#pragma unroll
    for (int r = 0; r < 4; r++) {
      int node = base + quad * 4 + r;
      g_r[r] = node / 14;
      t_r[r] = node - g_r[r] * 14;
    }
    float pr[4] = {0.f, 0.f, 0.f, 0.f};
#pragma unroll
    for (int jb = 0; jb < 4; jb++) {
      float4v acc = {0.f, 0.f, 0.f, 0.f};
      acc = __builtin_amdgcn_mfma_f32_16x16x32_f16(a0, bf[jb][0], acc, 0, 0, 0);
      acc = __builtin_amdgcn_mfma_f32_16x16x32_f16(a1, bf[jb][1], acc, 0, 0, 0);
      int j = jb * 16 + n16;
#pragma unroll
      for (int r = 0; r < 4; r++) {
        float h = acc[r] + b2j[jb];
        h = h > 0.f ? h : 0.f;
        pr[r] += h * Wfc[t_r[r] * 64 + j];
      }
    }
#pragma unroll
    for (int r = 0; r < 4; r++) {
#pragma unroll
      for (int off = 1; off < 16; off <<= 1) pr[r] += __shfl_xor(pr[r], off);
    }
    if (n16 == 0) {
#pragma unroll
      for (int r = 0; r < 4; r++) atomicAdd(&out[g_r[r]], pr[r]);
    }
  }
}

extern "C" void kernel_launch(void* const* d_in, const int* in_sizes, int n_in,
                              void* d_out, int out_size, void* d_ws, size_t ws_size,
                              hipStream_t stream)
{
  const float* x = (const float*)d_in[0];
  const int* edges = (const int*)d_in[1];
  const float* W1 = (const float*)d_in[2];
  const float* b1 = (const float*)d_in[3];
  const float* W2 = (const float*)d_in[4];
  const float* b2 = (const float*)d_in[5];
  const float* Wfc = (const float*)d_in[6];
  const float* bfc = (const float*)d_in[7];
  float* out = (float*)d_out;
  (void)n_in;

  const int N = in_sizes[0] / 32;  // 700000
  const int E = in_sizes[1] / 2;   // 4000000
  const int B = out_size;          // 50000
  const int NBK = (N + 255) >> 8;  // 2735 buckets (dst>>8)
  const int NBK8 = NBK * 8;        // 21880 (bucket, xcd-group) slices

  char* ws = (char*)d_ws;
  size_t off = 0;
  auto alloc = [&](size_t bytes) -> void* {
    void* p = ws + off;
    off += (bytes + 255) & ~(size_t)255;
    return p;
  };
  int* flag = (int*)alloc(256);
  int* bhist8 = (int*)alloc((size_t)NBK8 * 4);
  int* bstart8 = (int*)alloc(((size_t)NBK8 + 1) * 4);
  int* bcursor8 = (int*)alloc((size_t)NBK8 * 4);
  int* col = (int*)alloc((size_t)E * 4);
  int* rowptr = (int*)alloc(((size_t)N + 1) * 4);
  float* dinv = (float*)alloc((size_t)N * 4);
  __half* F1 = (__half*)alloc(((size_t)N + 16) * 64 * 2);  // g1, later a2; head aliased as pairbuf
  __half* F2 = (__half*)alloc(((size_t)N + 16) * 64 * 2);  // u1
  int* pair = (int*)F1;  // pairbuf (E*4 = 16MB) dead before mm1 writes F1

  if (off > ws_size) {
    float v = -(float)(double)(ws_size >> 20);
    fallback_kernel<<<(B + 255) / 256, 256, 0, stream>>>(out, B, v);
    return;
  }

  probe_kernel<<<1, 64, 0, stream>>>(edges, flag);
  zero_i32_kernel<<<(NBK8 + 255) / 256, 256, 0, stream>>>(bhist8, NBK8);
  bucket_hist_kernel<<<(E + 255) / 256, 256, 0, stream>>>(edges, E, N, flag, bhist8);
  scan_buckets8_kernel<<<1, 1024, 0, stream>>>(bhist8, NBK8, bstart8, bcursor8, rowptr, N, E);
  partition_kernel<<<(E + 255) / 256, 256, 0, stream>>>(edges, E, N, flag, bcursor8, pair);
  build_kernel<<<NBK, 256, 0, stream>>>(pair, bstart8, rowptr, dinv, col, N);

  int ntiles = (N + 15) / 16;  // 43750
  int aggBlocks = (N * 64 + 255) / 256;  // one wave per node
  mfma_mm1_kernel<<<4096, 256, 0, stream>>>(x, W1, dinv, F1, N, ntiles);
  agg1_kernel<<<aggBlocks, 256, 0, stream>>>(F1, rowptr, col, dinv, b1, F2, N);
  agg2_kernel<<<aggBlocks, 256, 0, stream>>>(F2, rowptr, col, dinv, F1, N);
  out_init_kernel<<<(B + 255) / 256, 256, 0, stream>>>(out, bfc, B);
  mfma_final_kernel<<<2048, 256, 0, stream>>>(F1, W2, b2, Wfc, out, ntiles);
}

// Round 9
// 991.163 us; speedup vs baseline: 1.7216x; 1.0656x over previous
//
#include <hip/hip_runtime.h>
#include <hip/hip_fp16.h>

// GCN: h1 = relu(gcn(x,W1,b1)); h2 = relu(gcn(h1,W2,b2)); out = h2.reshape(B,896)@Wfc + bfc
// Factored: g1 = dinv*(x@W1); h1 = relu(dinv*agg(g1)+b1); u1 = dinv*h1;
//           a2 = dinv*agg(u1);  h2 = relu(a2@W2+b2)  [agg commutes with @W2]
// CSR via dst>>8 buckets with XCD-sliced (blockIdx&7) cursors (single-writer-XCD lines).
// mm1 and layer2+FC on MFMA. Aggs: edge-parallel gathers — lane = (edge-group, feat-quad),
// one dwordx2 instr fetches 4 edges x 128B rows; 2 nodes per wave for ILP.

typedef _Float16 half8 __attribute__((ext_vector_type(8)));
typedef float float4v __attribute__((ext_vector_type(4)));

__global__ __launch_bounds__(256) void fallback_kernel(float* __restrict__ out, int n, float v)
{
  int i = blockIdx.x * 256 + threadIdx.x;
  if (i < n) out[i] = v;
}

// detect edges dtype: int64 values < 2^31 -> every odd int32 word is 0
__global__ __launch_bounds__(64) void probe_kernel(const int* __restrict__ edges, int* __restrict__ flag)
{
  if (threadIdx.x == 0) {
    int orv = edges[1] | edges[3] | edges[5] | edges[7] | edges[9] | edges[11] | edges[13] | edges[15];
    flag[0] = (orv == 0) ? 1 : 0;  // 1 => int64 layout (shift word index by 1)
  }
}

__global__ __launch_bounds__(256) void zero_i32_kernel(int* __restrict__ p, int n)
{
  int i = blockIdx.x * 256 + threadIdx.x;
  if (i < n) p[i] = 0;
}

// A: histogram over (dst>>8, blockIdx&7)
__global__ __launch_bounds__(256) void bucket_hist_kernel(
    const int* __restrict__ edges, int E, int N, const int* __restrict__ flag,
    int* __restrict__ bhist8)
{
  int e = blockIdx.x * 256 + threadIdx.x;
  if (e >= E) return;
  int g = blockIdx.x & 7;
  int sh = flag[0];
  int d = edges[(E + e) << sh];
  if ((unsigned)d < (unsigned)N) atomicAdd(&bhist8[((d >> 8) << 3) + g], 1);
}

// B: exclusive scan over m = NBK*8 entries (single block, 24 per thread)
__global__ __launch_bounds__(1024) void scan_buckets8_kernel(
    const int* __restrict__ bhist8, int m,
    int* __restrict__ bstart8, int* __restrict__ bcursor8,
    int* __restrict__ rowptr, int N, int E)
{
  __shared__ int sm[1024];
  const int PER = 24;
  int t = threadIdx.x;
  int base = t * PER;
  int vals[PER];
  int s = 0;
#pragma unroll
  for (int i = 0; i < PER; i++) {
    int idx = base + i;
    int v = (idx < m) ? bhist8[idx] : 0;
    vals[i] = v;
    s += v;
  }
  sm[t] = s;
  __syncthreads();
  for (int off = 1; off < 1024; off <<= 1) {
    int x = 0;
    if (t >= off) x = sm[t - off];
    __syncthreads();
    if (t >= off) sm[t] += x;
    __syncthreads();
  }
  int run = sm[t] - s;
#pragma unroll
  for (int i = 0; i < PER; i++) {
    int idx = base + i;
    if (idx < m) { bstart8[idx] = run; bcursor8[idx] = run; }
    run += vals[i];
  }
  if (t == 0) { bstart8[m] = E; rowptr[N] = E; }
}

// C: partition edges into (bucket, group) slices; packed word = src | (dst&255)<<20
__global__ __launch_bounds__(256) void partition_kernel(
    const int* __restrict__ edges, int E, int N, const int* __restrict__ flag,
    int* __restrict__ bcursor8, int* __restrict__ pair)
{
  int e = blockIdx.x * 256 + threadIdx.x;
  if (e >= E) return;
  int g = blockIdx.x & 7;
  int sh = flag[0];
  int s = edges[e << sh];
  int d = edges[(E + e) << sh];
  if ((unsigned)s >= (unsigned)N || (unsigned)d >= (unsigned)N) return;
  int pos = atomicAdd(&bcursor8[((d >> 8) << 3) + g], 1);
  pair[pos] = s | ((d & 255) << 20);
}

// D: per-bucket CSR build: LDS hist -> LDS scan -> rowptr/dinv -> place edges (LDS cursors)
__global__ __launch_bounds__(256) void build_kernel(
    const int* __restrict__ pair, const int* __restrict__ bstart8,
    int* __restrict__ rowptr, float* __restrict__ dinv, int* __restrict__ col, int N)
{
  __shared__ int hist[256];
  __shared__ int sc[256];
  __shared__ int cur[256];
  int b = blockIdx.x;
  int t = threadIdx.x;
  int pbeg = bstart8[b << 3], pend = bstart8[(b + 1) << 3];
  hist[t] = 0;
  __syncthreads();
  for (int p = pbeg + t; p < pend; p += 256) {
    int v = pair[p];
    atomicAdd(&hist[(v >> 20) & 255], 1);
  }
  __syncthreads();
  int val = hist[t];
  sc[t] = val;
  __syncthreads();
  for (int off = 1; off < 256; off <<= 1) {
    int x = 0;
    if (t >= off) x = sc[t - off];
    __syncthreads();
    if (t >= off) sc[t] += x;
    __syncthreads();
  }
  int excl = sc[t] - val;
  int row = (b << 8) + t;
  int rp = pbeg + excl;
  cur[t] = rp;
  if (row < N) {
    rowptr[row] = rp;
    dinv[row] = rsqrtf((float)(val + 1));  // deg = dst-count + 1 (self loop)
  }
  __syncthreads();
  for (int p = pbeg + t; p < pend; p += 256) {
    int v = pair[p];
    int pos = atomicAdd(&cur[(v >> 20) & 255], 1);
    col[pos] = v & 0xFFFFF;
  }
}

// MFMA mm1: per wave, 16 nodes; D[16][64] = x-tile(fp16) @ W1; G = dinv*D (fp16).
__global__ __launch_bounds__(256) void mfma_mm1_kernel(
    const float* __restrict__ X, const float* __restrict__ W1,
    const float* __restrict__ dinv, __half* __restrict__ G, int n, int ntiles)
{
  int lane = threadIdx.x & 63;
  int n16 = lane & 15;
  int quad = lane >> 4;

  half8 bf[4];
#pragma unroll
  for (int jb = 0; jb < 4; jb++)
#pragma unroll
    for (int i = 0; i < 8; i++)
      bf[jb][i] = (_Float16)W1[(quad * 8 + i) * 64 + jb * 16 + n16];

  _Float16* Gh = (_Float16*)G;
  int wave = (blockIdx.x * 256 + threadIdx.x) >> 6;
  int nw = (gridDim.x * 256) >> 6;
  for (int tile = wave; tile < ntiles; tile += nw) {
    int ut = __builtin_amdgcn_readfirstlane(tile);
    int base = ut * 16;
    int node = base + n16;
    if (node >= n) node = n - 1;
    const float* xr = X + (size_t)node * 32 + quad * 8;
    half8 a;
#pragma unroll
    for (int i = 0; i < 8; i++) a[i] = (_Float16)xr[i];

    float4v acc[4];
#pragma unroll
    for (int jb = 0; jb < 4; jb++) {
      float4v z = {0.f, 0.f, 0.f, 0.f};
      acc[jb] = __builtin_amdgcn_mfma_f32_16x16x32_f16(a, bf[jb], z, 0, 0, 0);
    }
#pragma unroll
    for (int r = 0; r < 4; r++) {
      int node2 = base + quad * 4 + r;
      if (node2 < n) {
        float dv = dinv[node2];
#pragma unroll
        for (int jb = 0; jb < 4; jb++)
          Gh[(size_t)node2 * 64 + jb * 16 + n16] = (_Float16)(dv * acc[jb][r]);
      }
    }
  }
}

__device__ inline void unpack_add(uint2 v, float* a)
{
  __half2 lo = *reinterpret_cast<__half2*>(&v.x);
  __half2 hi = *reinterpret_cast<__half2*>(&v.y);
  float2 l = __half22float2(lo);
  float2 h = __half22float2(hi);
  a[0] += l.x; a[1] += l.y; a[2] += h.x; a[3] += h.y;
}

// Aggregation, edge-parallel: lane = (eg = lane>>4 in [0,4), fq = lane&15).
// One dwordx2 load covers 4 edges' 8B feature-quads (512B/instr). 2 nodes per wave.
// RELU: out = dinv*relu(dinv*acc + bias)  else  out = dinv*acc
template <bool RELU>
__global__ __launch_bounds__(256) void agg_kernel(
    const __half* __restrict__ Gsrc, const int* __restrict__ rowptr,
    const int* __restrict__ col, const float* __restrict__ dinv,
    const float* __restrict__ bias, __half* __restrict__ Udst, int n)
{
  int lane = threadIdx.x & 63;
  int eg = lane >> 4, fq = lane & 15;
  int w = (blockIdx.x * 256 + threadIdx.x) >> 6;
  int node0 = w * 2, node1 = w * 2 + 1;
  if (node0 >= n) return;
  bool has1 = (node1 < n);
  const uint2* G2 = (const uint2*)Gsrc;
  uint2* U2 = (uint2*)Udst;

  int beg0 = rowptr[node0], end0 = rowptr[node0 + 1];
  int beg1 = has1 ? rowptr[node1] : 0;
  int end1 = has1 ? rowptr[node1 + 1] : 0;

  float a0[4] = {0.f, 0.f, 0.f, 0.f};
  float a1[4] = {0.f, 0.f, 0.f, 0.f};

  // self rows (added once via eg-predication)
  uint2 s0 = G2[(size_t)node0 * 16 + fq];
  uint2 s1 = G2[(size_t)(has1 ? node1 : node0) * 16 + fq];

  // main batch: up to 16 edges per node, exec-mask predicated, 8 loads in flight
  {
    uint2 v0[4], v1[4];
    bool p0[4], p1[4];
#pragma unroll
    for (int b = 0; b < 4; b++) {
      int i0 = beg0 + b * 4 + eg;
      int i1 = beg1 + b * 4 + eg;
      p0[b] = (i0 < end0);
      p1[b] = has1 && (i1 < end1);
      v0[b].x = 0; v0[b].y = 0; v1[b].x = 0; v1[b].y = 0;
      if (p0[b]) v0[b] = G2[(size_t)col[i0] * 16 + fq];
      if (p1[b]) v1[b] = G2[(size_t)col[i1] * 16 + fq];
    }
#pragma unroll
    for (int b = 0; b < 4; b++) {
      unpack_add(v0[b], a0);
      unpack_add(v1[b], a1);
    }
  }
  // rare tails (P(deg>16) ~ 1e-4)
  for (int e = beg0 + 16; e < end0; e += 16) {
#pragma unroll
    for (int b = 0; b < 4; b++) {
      int i = e + b * 4 + eg;
      if (i < end0) { uint2 v = G2[(size_t)col[i] * 16 + fq]; unpack_add(v, a0); }
    }
  }
  for (int e = beg1 + 16; e < end1; e += 16) {
#pragma unroll
    for (int b = 0; b < 4; b++) {
      int i = e + b * 4 + eg;
      if (i < end1) { uint2 v = G2[(size_t)col[i] * 16 + fq]; unpack_add(v, a1); }
    }
  }
  // fold self rows in (one edge-group each)
  if (eg == 0) unpack_add(s0, a0);
  if (eg == 1 && has1) unpack_add(s1, a1);

  // reduce across the 4 edge-groups
#pragma unroll
  for (int j = 0; j < 4; j++) {
    a0[j] += __shfl_xor(a0[j], 16);
    a0[j] += __shfl_xor(a0[j], 32);
    a1[j] += __shfl_xor(a1[j], 16);
    a1[j] += __shfl_xor(a1[j], 32);
  }

  float dv0 = dinv[node0];
  float dv1 = has1 ? dinv[node1] : 0.f;
  float r0[4], r1[4];
  if (RELU) {
    float4 bv = *(const float4*)(bias + 4 * fq);
    float bb[4] = {bv.x, bv.y, bv.z, bv.w};
#pragma unroll
    for (int j = 0; j < 4; j++) {
      float h0 = dv0 * a0[j] + bb[j]; h0 = h0 > 0.f ? h0 : 0.f; r0[j] = dv0 * h0;
      float h1 = dv1 * a1[j] + bb[j]; h1 = h1 > 0.f ? h1 : 0.f; r1[j] = dv1 * h1;
    }
  } else {
#pragma unroll
    for (int j = 0; j < 4; j++) { r0[j] = dv0 * a0[j]; r1[j] = dv1 * a1[j]; }
  }
  uint2 o0, o1;
  __half2 h0lo = __floats2half2_rn(r0[0], r0[1]);
  __half2 h0hi = __floats2half2_rn(r0[2], r0[3]);
  __half2 h1lo = __floats2half2_rn(r1[0], r1[1]);
  __half2 h1hi = __floats2half2_rn(r1[2], r1[3]);
  o0.x = *reinterpret_cast<uint*>(&h0lo); o0.y = *reinterpret_cast<uint*>(&h0hi);
  o1.x = *reinterpret_cast<uint*>(&h1lo); o1.y = *reinterpret_cast<uint*>(&h1hi);
  if (eg == 0) U2[(size_t)node0 * 16 + fq] = o0;
  if (eg == 1 && has1) U2[(size_t)node1 * 16 + fq] = o1;
}

__global__ __launch_bounds__(256) void out_init_kernel(
    float* __restrict__ out, const float* __restrict__ bfc, int n)
{
  int i = blockIdx.x * 256 + threadIdx.x;
  if (i < n) out[i] = bfc[0];
}

// MFMA fused layer2-matmul + relu + FC (validated R4)
__global__ __launch_bounds__(256) void mfma_final_kernel(
    const __half* __restrict__ A2, const float* __restrict__ W2,
    const float* __restrict__ b2, const float* __restrict__ Wfc,
    float* __restrict__ out, int ntiles)
{
  int lane = threadIdx.x & 63;
  int n16 = lane & 15;
  int quad = lane >> 4;

  half8 bf[4][2];
#pragma unroll
  for (int jb = 0; jb < 4; jb++)
#pragma unroll
    for (int kf = 0; kf < 2; kf++)
#pragma unroll
      for (int i = 0; i < 8; i++)
        bf[jb][kf][i] = (_Float16)W2[(kf * 32 + quad * 8 + i) * 64 + jb * 16 + n16];
  float b2j[4];
#pragma unroll
  for (int jb = 0; jb < 4; jb++) b2j[jb] = b2[jb * 16 + n16];

  const _Float16* A2h = (const _Float16*)A2;
  int wave = (blockIdx.x * 256 + threadIdx.x) >> 6;
  int nw = (gridDim.x * 256) >> 6;
  for (int tile = wave; tile < ntiles; tile += nw) {
    int ut = __builtin_amdgcn_readfirstlane(tile);
    int base = ut * 16;
    const _Float16* arow = A2h + (size_t)(base + n16) * 64 + quad * 8;
    half8 a0 = *(const half8*)(arow);
    half8 a1 = *(const half8*)(arow + 32);

    int g_r[4], t_r[4];
#pragma unroll
    for (int r = 0; r < 4; r++) {
      int node = base + quad * 4 + r;
      g_r[r] = node / 14;
      t_r[r] = node - g_r[r] * 14;
    }
    float pr[4] = {0.f, 0.f, 0.f, 0.f};
#pragma unroll
    for (int jb = 0; jb < 4; jb++) {
      float4v acc = {0.f, 0.f, 0.f, 0.f};
      acc = __builtin_amdgcn_mfma_f32_16x16x32_f16(a0, bf[jb][0], acc, 0, 0, 0);
      acc = __builtin_amdgcn_mfma_f32_16x16x32_f16(a1, bf[jb][1], acc, 0, 0, 0);
      int j = jb * 16 + n16;
#pragma unroll
      for (int r = 0; r < 4; r++) {
        float h = acc[r] + b2j[jb];
        h = h > 0.f ? h : 0.f;
        pr[r] += h * Wfc[t_r[r] * 64 + j];
      }
    }
#pragma unroll
    for (int r = 0; r < 4; r++) {
#pragma unroll
      for (int off = 1; off < 16; off <<= 1) pr[r] += __shfl_xor(pr[r], off);
    }
    if (n16 == 0) {
#pragma unroll
      for (int r = 0; r < 4; r++) atomicAdd(&out[g_r[r]], pr[r]);
    }
  }
}

extern "C" void kernel_launch(void* const* d_in, const int* in_sizes, int n_in,
                              void* d_out, int out_size, void* d_ws, size_t ws_size,
                              hipStream_t stream)
{
  const float* x = (const float*)d_in[0];
  const int* edges = (const int*)d_in[1];
  const float* W1 = (const float*)d_in[2];
  const float* b1 = (const float*)d_in[3];
  const float* W2 = (const float*)d_in[4];
  const float* b2 = (const float*)d_in[5];
  const float* Wfc = (const float*)d_in[6];
  const float* bfc = (const float*)d_in[7];
  float* out = (float*)d_out;
  (void)n_in;

  const int N = in_sizes[0] / 32;  // 700000
  const int E = in_sizes[1] / 2;   // 4000000
  const int B = out_size;          // 50000
  const int NBK = (N + 255) >> 8;  // 2735 buckets (dst>>8)
  const int NBK8 = NBK * 8;        // 21880 (bucket, xcd-group) slices

  char* ws = (char*)d_ws;
  size_t off = 0;
  auto alloc = [&](size_t bytes) -> void* {
    void* p = ws + off;
    off += (bytes + 255) & ~(size_t)255;
    return p;
  };
  int* flag = (int*)alloc(256);
  int* bhist8 = (int*)alloc((size_t)NBK8 * 4);
  int* bstart8 = (int*)alloc(((size_t)NBK8 + 1) * 4);
  int* bcursor8 = (int*)alloc((size_t)NBK8 * 4);
  int* col = (int*)alloc((size_t)E * 4);
  int* rowptr = (int*)alloc(((size_t)N + 1) * 4);
  float* dinv = (float*)alloc((size_t)N * 4);
  __half* F1 = (__half*)alloc(((size_t)N + 16) * 64 * 2);  // g1, later a2; head aliased as pairbuf
  __half* F2 = (__half*)alloc(((size_t)N + 16) * 64 * 2);  // u1
  int* pair = (int*)F1;  // pairbuf (E*4 = 16MB) dead before mm1 writes F1

  if (off > ws_size) {
    float v = -(float)(double)(ws_size >> 20);
    fallback_kernel<<<(B + 255) / 256, 256, 0, stream>>>(out, B, v);
    return;
  }

  probe_kernel<<<1, 64, 0, stream>>>(edges, flag);
  zero_i32_kernel<<<(NBK8 + 255) / 256, 256, 0, stream>>>(bhist8, NBK8);
  bucket_hist_kernel<<<(E + 255) / 256, 256, 0, stream>>>(edges, E, N, flag, bhist8);
  scan_buckets8_kernel<<<1, 1024, 0, stream>>>(bhist8, NBK8, bstart8, bcursor8, rowptr, N, E);
  partition_kernel<<<(E + 255) / 256, 256, 0, stream>>>(edges, E, N, flag, bcursor8, pair);
  build_kernel<<<NBK, 256, 0, stream>>>(pair, bstart8, rowptr, dinv, col, N);

  int ntiles = (N + 15) / 16;  // 43750
  int aggBlocks = (N + 7) / 8;  // 2 nodes per wave, 4 waves per block
  mfma_mm1_kernel<<<4096, 256, 0, stream>>>(x, W1, dinv, F1, N, ntiles);
  agg_kernel<true><<<aggBlocks, 256, 0, stream>>>(F1, rowptr, col, dinv, b1, F2, N);
  agg_kernel<false><<<aggBlocks, 256, 0, stream>>>(F2, rowptr, col, dinv, nullptr, F1, N);
  out_init_kernel<<<(B + 255) / 256, 256, 0, stream>>>(out, bfc, B);
  mfma_final_kernel<<<2048, 256, 0, stream>>>(F1, W2, b2, Wfc, out, ntiles);
}

// Round 10
// 727.509 us; speedup vs baseline: 2.3455x; 1.3624x over previous
//
#include <hip/hip_runtime.h>
#include <hip/hip_fp16.h>

// GCN: h1 = relu(gcn(x,W1,b1)); h2 = relu(gcn(h1,W2,b2)); out = h2.reshape(B,896)@Wfc + bfc
// Factored: g1 = dinv*(x@W1); h1 = relu(dinv*agg(g1)+b1); u1 = dinv*h1;
//           a2 = dinv*agg(u1);  h2 = relu(a2@W2+b2)  [agg commutes with @W2]
// CSR via deterministic counting sort over buckets b=dst>>11 (NBK=342):
//   hist2 (per-8192-edge chunk LDS hist) -> colscan (per-bucket chunk prefix, in place)
//   -> scan_totals (bucket starts) -> pass3 (contiguous run placement, LDS cursors)
//   -> build (per-bucket 2048-node LDS CSR). No global atomics; writes contiguous
//   by construction (R5/R9 showed scattered 4B stores flush at ~1.7 writes/line).
// mm1 and layer2+FC on MFMA. Aggs edge-parallel (4 edges x 8B quads per dwordx2).

typedef _Float16 half8 __attribute__((ext_vector_type(8)));
typedef float float4v __attribute__((ext_vector_type(4)));

#define CHUNK 8192
#define BSH 11
#define BNODES 2048

__global__ __launch_bounds__(256) void fallback_kernel(float* __restrict__ out, int n, float v)
{
  int i = blockIdx.x * 256 + threadIdx.x;
  if (i < n) out[i] = v;
}

// detect edges dtype: int64 values < 2^31 -> every odd int32 word is 0
__global__ __launch_bounds__(64) void probe_kernel(const int* __restrict__ edges, int* __restrict__ flag)
{
  if (threadIdx.x == 0) {
    int orv = edges[1] | edges[3] | edges[5] | edges[7] | edges[9] | edges[11] | edges[13] | edges[15];
    flag[0] = (orv == 0) ? 1 : 0;  // 1 => int64 layout (shift word index by 1)
  }
}

// (1) per-chunk bucket histogram -> cnt[chunk][b]  (coalesced row write)
__global__ __launch_bounds__(256) void hist2_kernel(
    const int* __restrict__ edges, int E, int N, const int* __restrict__ flag,
    int* __restrict__ cnt, int NBK)
{
  __shared__ int lh[512];
  int t = threadIdx.x;
  int blk = blockIdx.x;
  for (int b = t; b < NBK; b += 256) lh[b] = 0;
  __syncthreads();
  int sh = flag[0];
  int base = blk * CHUNK;
#pragma unroll
  for (int k = 0; k < CHUNK / 256; k++) {
    int e = base + k * 256 + t;
    if (e < E) {
      int d = edges[(E + e) << sh];
      if ((unsigned)d < (unsigned)N) atomicAdd(&lh[d >> BSH], 1);
    }
  }
  __syncthreads();
  for (int b = t; b < NBK; b += 256) cnt[(size_t)blk * NBK + b] = lh[b];
}

// (2) per-bucket exclusive prefix over chunks, in place; totals[b] = column sum
__global__ __launch_bounds__(64) void colscan_kernel(
    int* __restrict__ cnt, int NCH, int NBK, int* __restrict__ totals)
{
  int b = blockIdx.x;
  int lane = threadIdx.x;
  int carry = 0;
  int rounds = (NCH + 63) >> 6;
  for (int r = 0; r < rounds; r++) {
    int blk = r * 64 + lane;
    int v = (blk < NCH) ? cnt[(size_t)blk * NBK + b] : 0;
    int incl = v;
#pragma unroll
    for (int off = 1; off < 64; off <<= 1) {
      int x = __shfl_up(incl, off);
      if (lane >= off) incl += x;
    }
    int excl = incl - v + carry;
    if (blk < NCH) cnt[(size_t)blk * NBK + b] = excl;
    carry += __shfl(incl, 63);
  }
  if (lane == 0) totals[b] = carry;
}

// (3) exclusive scan of bucket totals -> bstart[NBK+1]; rowptr[N] = total
__global__ __launch_bounds__(512) void scan_totals_kernel(
    const int* __restrict__ totals, int NBK,
    int* __restrict__ bstart, int* __restrict__ rowptr, int N)
{
  __shared__ int sm[512];
  int t = threadIdx.x;
  int v = (t < NBK) ? totals[t] : 0;
  sm[t] = v;
  __syncthreads();
  for (int off = 1; off < 512; off <<= 1) {
    int x = 0;
    if (t >= off) x = sm[t - off];
    __syncthreads();
    if (t >= off) sm[t] += x;
    __syncthreads();
  }
  if (t < NBK) bstart[t] = sm[t] - v;
  if (t == 0) { bstart[NBK] = sm[511]; rowptr[N] = sm[511]; }
}

// (4) placement: each chunk writes contiguous runs per bucket; packed = src | (dst&2047)<<20
__global__ __launch_bounds__(256) void pass3_kernel(
    const int* __restrict__ edges, int E, int N, const int* __restrict__ flag,
    const int* __restrict__ cnt, const int* __restrict__ bstart,
    int* __restrict__ pair, int NBK)
{
  __shared__ int lcur[512];
  int t = threadIdx.x;
  int blk = blockIdx.x;
  for (int b = t; b < NBK; b += 256)
    lcur[b] = bstart[b] + cnt[(size_t)blk * NBK + b];
  __syncthreads();
  int sh = flag[0];
  int base = blk * CHUNK;
#pragma unroll
  for (int k = 0; k < CHUNK / 256; k++) {
    int e = base + k * 256 + t;
    if (e < E) {
      int s = edges[e << sh];
      int d = edges[(E + e) << sh];
      if ((unsigned)s < (unsigned)N && (unsigned)d < (unsigned)N) {
        int pos = atomicAdd(&lcur[d >> BSH], 1);
        pair[pos] = s | ((d & (BNODES - 1)) << 20);
      }
    }
  }
}

// (5) per-bucket CSR build: LDS hist(2048) -> scan -> rowptr/dinv -> place via LDS cursors
__global__ __launch_bounds__(256) void build_kernel(
    const int* __restrict__ pair, const int* __restrict__ bstart,
    int* __restrict__ rowptr, float* __restrict__ dinv, int* __restrict__ col, int N)
{
  __shared__ int hist[BNODES];
  __shared__ int cur[BNODES];
  __shared__ int sc[256];
  int b = blockIdx.x;
  int t = threadIdx.x;
  int pbeg = bstart[b], pend = bstart[b + 1];
#pragma unroll
  for (int i = 0; i < BNODES / 256; i++) hist[i * 256 + t] = 0;
  __syncthreads();
  for (int p = pbeg + t; p < pend; p += 256)
    atomicAdd(&hist[(pair[p] >> 20) & (BNODES - 1)], 1);
  __syncthreads();
  // scan 2048 with 256 threads: 8 serial per thread + block scan
  int hv[8];
  int tsum = 0;
#pragma unroll
  for (int i = 0; i < 8; i++) { hv[i] = hist[t * 8 + i]; tsum += hv[i]; }
  sc[t] = tsum;
  __syncthreads();
  for (int off = 1; off < 256; off <<= 1) {
    int x = 0;
    if (t >= off) x = sc[t - off];
    __syncthreads();
    if (t >= off) sc[t] += x;
    __syncthreads();
  }
  int run = sc[t] - tsum;  // exclusive prefix of this thread's first node
#pragma unroll
  for (int i = 0; i < 8; i++) {
    int idx = t * 8 + i;
    int rp = pbeg + run;
    cur[idx] = rp;
    int row = (b << BSH) + idx;
    if (row < N) {
      rowptr[row] = rp;
      dinv[row] = rsqrtf((float)(hv[i] + 1));  // deg = dst-count + 1 (self loop)
    }
    run += hv[i];
  }
  __syncthreads();
  for (int p = pbeg + t; p < pend; p += 256) {
    int v = pair[p];
    int pos = atomicAdd(&cur[(v >> 20) & (BNODES - 1)], 1);
    col[pos] = v & 0xFFFFF;
  }
}

// MFMA mm1: per wave, 16 nodes; D[16][64] = x-tile(fp16) @ W1; G = dinv*D (fp16).
__global__ __launch_bounds__(256) void mfma_mm1_kernel(
    const float* __restrict__ X, const float* __restrict__ W1,
    const float* __restrict__ dinv, __half* __restrict__ G, int n, int ntiles)
{
  int lane = threadIdx.x & 63;
  int n16 = lane & 15;
  int quad = lane >> 4;

  half8 bf[4];
#pragma unroll
  for (int jb = 0; jb < 4; jb++)
#pragma unroll
    for (int i = 0; i < 8; i++)
      bf[jb][i] = (_Float16)W1[(quad * 8 + i) * 64 + jb * 16 + n16];

  _Float16* Gh = (_Float16*)G;
  int wave = (blockIdx.x * 256 + threadIdx.x) >> 6;
  int nw = (gridDim.x * 256) >> 6;
  for (int tile = wave; tile < ntiles; tile += nw) {
    int ut = __builtin_amdgcn_readfirstlane(tile);
    int base = ut * 16;
    int node = base + n16;
    if (node >= n) node = n - 1;
    const float* xr = X + (size_t)node * 32 + quad * 8;
    half8 a;
#pragma unroll
    for (int i = 0; i < 8; i++) a[i] = (_Float16)xr[i];

    float4v acc[4];
#pragma unroll
    for (int jb = 0; jb < 4; jb++) {
      float4v z = {0.f, 0.f, 0.f, 0.f};
      acc[jb] = __builtin_amdgcn_mfma_f32_16x16x32_f16(a, bf[jb], z, 0, 0, 0);
    }
#pragma unroll
    for (int r = 0; r < 4; r++) {
      int node2 = base + quad * 4 + r;
      if (node2 < n) {
        float dv = dinv[node2];
#pragma unroll
        for (int jb = 0; jb < 4; jb++)
          Gh[(size_t)node2 * 64 + jb * 16 + n16] = (_Float16)(dv * acc[jb][r]);
      }
    }
  }
}

__device__ inline void unpack_add(uint2 v, float* a)
{
  __half2 lo = *reinterpret_cast<__half2*>(&v.x);
  __half2 hi = *reinterpret_cast<__half2*>(&v.y);
  float2 l = __half22float2(lo);
  float2 h = __half22float2(hi);
  a[0] += l.x; a[1] += l.y; a[2] += h.x; a[3] += h.y;
}

// Aggregation, edge-parallel: lane = (eg = lane>>4 in [0,4), fq = lane&15).
// One dwordx2 load covers 4 edges' 8B feature-quads (512B/instr). 2 nodes per wave.
template <bool RELU>
__global__ __launch_bounds__(256) void agg_kernel(
    const __half* __restrict__ Gsrc, const int* __restrict__ rowptr,
    const int* __restrict__ col, const float* __restrict__ dinv,
    const float* __restrict__ bias, __half* __restrict__ Udst, int n)
{
  int lane = threadIdx.x & 63;
  int eg = lane >> 4, fq = lane & 15;
  int w = (blockIdx.x * 256 + threadIdx.x) >> 6;
  int node0 = w * 2, node1 = w * 2 + 1;
  if (node0 >= n) return;
  bool has1 = (node1 < n);
  const uint2* G2 = (const uint2*)Gsrc;
  uint2* U2 = (uint2*)Udst;

  int beg0 = rowptr[node0], end0 = rowptr[node0 + 1];
  int beg1 = has1 ? rowptr[node1] : 0;
  int end1 = has1 ? rowptr[node1 + 1] : 0;

  float a0[4] = {0.f, 0.f, 0.f, 0.f};
  float a1[4] = {0.f, 0.f, 0.f, 0.f};

  uint2 s0 = G2[(size_t)node0 * 16 + fq];
  uint2 s1 = G2[(size_t)(has1 ? node1 : node0) * 16 + fq];

  {
    uint2 v0[4], v1[4];
    bool p0[4], p1[4];
#pragma unroll
    for (int b = 0; b < 4; b++) {
      int i0 = beg0 + b * 4 + eg;
      int i1 = beg1 + b * 4 + eg;
      p0[b] = (i0 < end0);
      p1[b] = has1 && (i1 < end1);
      v0[b].x = 0; v0[b].y = 0; v1[b].x = 0; v1[b].y = 0;
      if (p0[b]) v0[b] = G2[(size_t)col[i0] * 16 + fq];
      if (p1[b]) v1[b] = G2[(size_t)col[i1] * 16 + fq];
    }
#pragma unroll
    for (int b = 0; b < 4; b++) {
      unpack_add(v0[b], a0);
      unpack_add(v1[b], a1);
    }
  }
  for (int e = beg0 + 16; e < end0; e += 16) {
#pragma unroll
    for (int b = 0; b < 4; b++) {
      int i = e + b * 4 + eg;
      if (i < end0) { uint2 v = G2[(size_t)col[i] * 16 + fq]; unpack_add(v, a0); }
    }
  }
  for (int e = beg1 + 16; e < end1; e += 16) {
#pragma unroll
    for (int b = 0; b < 4; b++) {
      int i = e + b * 4 + eg;
      if (i < end1) { uint2 v = G2[(size_t)col[i] * 16 + fq]; unpack_add(v, a1); }
    }
  }
  if (eg == 0) unpack_add(s0, a0);
  if (eg == 1 && has1) unpack_add(s1, a1);

#pragma unroll
  for (int j = 0; j < 4; j++) {
    a0[j] += __shfl_xor(a0[j], 16);
    a0[j] += __shfl_xor(a0[j], 32);
    a1[j] += __shfl_xor(a1[j], 16);
    a1[j] += __shfl_xor(a1[j], 32);
  }

  float dv0 = dinv[node0];
  float dv1 = has1 ? dinv[node1] : 0.f;
  float r0[4], r1[4];
  if (RELU) {
    float4 bv = *(const float4*)(bias + 4 * fq);
    float bb[4] = {bv.x, bv.y, bv.z, bv.w};
#pragma unroll
    for (int j = 0; j < 4; j++) {
      float h0 = dv0 * a0[j] + bb[j]; h0 = h0 > 0.f ? h0 : 0.f; r0[j] = dv0 * h0;
      float h1 = dv1 * a1[j] + bb[j]; h1 = h1 > 0.f ? h1 : 0.f; r1[j] = dv1 * h1;
    }
  } else {
#pragma unroll
    for (int j = 0; j < 4; j++) { r0[j] = dv0 * a0[j]; r1[j] = dv1 * a1[j]; }
  }
  uint2 o0, o1;
  __half2 h0lo = __floats2half2_rn(r0[0], r0[1]);
  __half2 h0hi = __floats2half2_rn(r0[2], r0[3]);
  __half2 h1lo = __floats2half2_rn(r1[0], r1[1]);
  __half2 h1hi = __floats2half2_rn(r1[2], r1[3]);
  o0.x = *reinterpret_cast<uint*>(&h0lo); o0.y = *reinterpret_cast<uint*>(&h0hi);
  o1.x = *reinterpret_cast<uint*>(&h1lo); o1.y = *reinterpret_cast<uint*>(&h1hi);
  if (eg == 0) U2[(size_t)node0 * 16 + fq] = o0;
  if (eg == 1 && has1) U2[(size_t)node1 * 16 + fq] = o1;
}

__global__ __launch_bounds__(256) void out_init_kernel(
    float* __restrict__ out, const float* __restrict__ bfc, int n)
{
  int i = blockIdx.x * 256 + threadIdx.x;
  if (i < n) out[i] = bfc[0];
}

// MFMA fused layer2-matmul + relu + FC (validated R4)
__global__ __launch_bounds__(256) void mfma_final_kernel(
    const __half* __restrict__ A2, const float* __restrict__ W2,
    const float* __restrict__ b2, const float* __restrict__ Wfc,
    float* __restrict__ out, int ntiles)
{
  int lane = threadIdx.x & 63;
  int n16 = lane & 15;
  int quad = lane >> 4;

  half8 bf[4][2];
#pragma unroll
  for (int jb = 0; jb < 4; jb++)
#pragma unroll
    for (int kf = 0; kf < 2; kf++)
#pragma unroll
      for (int i = 0; i < 8; i++)
        bf[jb][kf][i] = (_Float16)W2[(kf * 32 + quad * 8 + i) * 64 + jb * 16 + n16];
  float b2j[4];
#pragma unroll
  for (int jb = 0; jb < 4; jb++) b2j[jb] = b2[jb * 16 + n16];

  const _Float16* A2h = (const _Float16*)A2;
  int wave = (blockIdx.x * 256 + threadIdx.x) >> 6;
  int nw = (gridDim.x * 256) >> 6;
  for (int tile = wave; tile < ntiles; tile += nw) {
    int ut = __builtin_amdgcn_readfirstlane(tile);
    int base = ut * 16;
    const _Float16* arow = A2h + (size_t)(base + n16) * 64 + quad * 8;
    half8 a0 = *(const half8*)(arow);
    half8 a1 = *(const half8*)(arow + 32);

    int g_r[4], t_r[4];
#pragma unroll
    for (int r = 0; r < 4; r++) {
      int node = base + quad * 4 + r;
      g_r[r] = node / 14;
      t_r[r] = node - g_r[r] * 14;
    }
    float pr[4] = {0.f, 0.f, 0.f, 0.f};
#pragma unroll
    for (int jb = 0; jb < 4; jb++) {
      float4v acc = {0.f, 0.f, 0.f, 0.f};
      acc = __builtin_amdgcn_mfma_f32_16x16x32_f16(a0, bf[jb][0], acc, 0, 0, 0);
      acc = __builtin_amdgcn_mfma_f32_16x16x32_f16(a1, bf[jb][1], acc, 0, 0, 0);
      int j = jb * 16 + n16;
#pragma unroll
      for (int r = 0; r < 4; r++) {
        float h = acc[r] + b2j[jb];
        h = h > 0.f ? h : 0.f;
        pr[r] += h * Wfc[t_r[r] * 64 + j];
      }
    }
#pragma unroll
    for (int r = 0; r < 4; r++) {
#pragma unroll
      for (int off = 1; off < 16; off <<= 1) pr[r] += __shfl_xor(pr[r], off);
    }
    if (n16 == 0) {
#pragma unroll
      for (int r = 0; r < 4; r++) atomicAdd(&out[g_r[r]], pr[r]);
    }
  }
}

extern "C" void kernel_launch(void* const* d_in, const int* in_sizes, int n_in,
                              void* d_out, int out_size, void* d_ws, size_t ws_size,
                              hipStream_t stream)
{
  const float* x = (const float*)d_in[0];
  const int* edges = (const int*)d_in[1];
  const float* W1 = (const float*)d_in[2];
  const float* b1 = (const float*)d_in[3];
  const float* W2 = (const float*)d_in[4];
  const float* b2 = (const float*)d_in[5];
  const float* Wfc = (const float*)d_in[6];
  const float* bfc = (const float*)d_in[7];
  float* out = (float*)d_out;
  (void)n_in;

  const int N = in_sizes[0] / 32;   // 700000
  const int E = in_sizes[1] / 2;    // 4000000
  const int B = out_size;           // 50000
  const int NBK = (N + BNODES - 1) >> BSH;  // 342 buckets (dst>>11)
  const int NCH = (E + CHUNK - 1) / CHUNK;  // 489 chunks

  char* ws = (char*)d_ws;
  size_t off = 0;
  auto alloc = [&](size_t bytes) -> void* {
    void* p = ws + off;
    off += (bytes + 255) & ~(size_t)255;
    return p;
  };
  int* flag = (int*)alloc(256);
  int* cnt = (int*)alloc((size_t)NCH * NBK * 4);  // per-(chunk,bucket) counts -> prefixes
  int* totals = (int*)alloc((size_t)NBK * 4);
  int* bstart = (int*)alloc(((size_t)NBK + 1) * 4);
  int* col = (int*)alloc((size_t)E * 4);
  int* rowptr = (int*)alloc(((size_t)N + 1) * 4);
  float* dinv = (float*)alloc((size_t)N * 4);
  __half* F1 = (__half*)alloc(((size_t)N + 16) * 64 * 2);  // g1, later a2; head aliased as pairbuf
  __half* F2 = (__half*)alloc(((size_t)N + 16) * 64 * 2);  // u1
  int* pair = (int*)F1;  // pairbuf (E*4 = 16MB) dead before mm1 writes F1

  if (off > ws_size) {
    float v = -(float)(double)(ws_size >> 20);
    fallback_kernel<<<(B + 255) / 256, 256, 0, stream>>>(out, B, v);
    return;
  }

  probe_kernel<<<1, 64, 0, stream>>>(edges, flag);
  hist2_kernel<<<NCH, 256, 0, stream>>>(edges, E, N, flag, cnt, NBK);
  colscan_kernel<<<NBK, 64, 0, stream>>>(cnt, NCH, NBK, totals);
  scan_totals_kernel<<<1, 512, 0, stream>>>(totals, NBK, bstart, rowptr, N);
  pass3_kernel<<<NCH, 256, 0, stream>>>(edges, E, N, flag, cnt, bstart, pair, NBK);
  build_kernel<<<NBK, 256, 0, stream>>>(pair, bstart, rowptr, dinv, col, N);

  int ntiles = (N + 15) / 16;   // 43750
  int aggBlocks = (N + 7) / 8;  // 2 nodes per wave, 4 waves per block
  mfma_mm1_kernel<<<4096, 256, 0, stream>>>(x, W1, dinv, F1, N, ntiles);
  agg_kernel<true><<<aggBlocks, 256, 0, stream>>>(F1, rowptr, col, dinv, b1, F2, N);
  agg_kernel<false><<<aggBlocks, 256, 0, stream>>>(F2, rowptr, col, dinv, nullptr, F1, N);
  out_init_kernel<<<(B + 255) / 256, 256, 0, stream>>>(out, bfc, B);
  mfma_final_kernel<<<2048, 256, 0, stream>>>(F1, W2, b2, Wfc, out, ntiles);
}

// Round 11
// 725.205 us; speedup vs baseline: 2.3529x; 1.0032x over previous
//
#include <hip/hip_runtime.h>
#include <hip/hip_fp16.h>

// GCN: h1 = relu(gcn(x,W1,b1)); h2 = relu(gcn(h1,W2,b2)); out = h2.reshape(B,896)@Wfc + bfc
// Factored: g1 = dinv*(x@W1); h1 = relu(dinv*agg(g1)+b1); u1 = dinv*h1;
//           a2 = dinv*agg(u1);  h2 = relu(a2@W2+b2)  [agg commutes with @W2]
// CSR via deterministic counting sort over buckets b=dst>>11 (NBK=342), no global atomics.
// mm1 and layer2+FC on MFMA. Aggs: lane=(eg in[0,8), fo in[0,8)); one dwordx4 covers
// 8 edges x 16B (1KB/instr); accumulation in packed fp16 (v_pk_add_f16), epilogue fp32.

typedef _Float16 half8 __attribute__((ext_vector_type(8)));
typedef float float4v __attribute__((ext_vector_type(4)));

#define CHUNK 8192
#define BSH 11
#define BNODES 2048

__global__ __launch_bounds__(256) void fallback_kernel(float* __restrict__ out, int n, float v)
{
  int i = blockIdx.x * 256 + threadIdx.x;
  if (i < n) out[i] = v;
}

// detect edges dtype: int64 values < 2^31 -> every odd int32 word is 0
__global__ __launch_bounds__(64) void probe_kernel(const int* __restrict__ edges, int* __restrict__ flag)
{
  if (threadIdx.x == 0) {
    int orv = edges[1] | edges[3] | edges[5] | edges[7] | edges[9] | edges[11] | edges[13] | edges[15];
    flag[0] = (orv == 0) ? 1 : 0;  // 1 => int64 layout (shift word index by 1)
  }
}

// (1) per-chunk bucket histogram -> cnt[chunk][b]  (coalesced row write)
__global__ __launch_bounds__(256) void hist2_kernel(
    const int* __restrict__ edges, int E, int N, const int* __restrict__ flag,
    int* __restrict__ cnt, int NBK)
{
  __shared__ int lh[512];
  int t = threadIdx.x;
  int blk = blockIdx.x;
  for (int b = t; b < NBK; b += 256) lh[b] = 0;
  __syncthreads();
  int sh = flag[0];
  int base = blk * CHUNK;
#pragma unroll
  for (int k = 0; k < CHUNK / 256; k++) {
    int e = base + k * 256 + t;
    if (e < E) {
      int d = edges[(E + e) << sh];
      if ((unsigned)d < (unsigned)N) atomicAdd(&lh[d >> BSH], 1);
    }
  }
  __syncthreads();
  for (int b = t; b < NBK; b += 256) cnt[(size_t)blk * NBK + b] = lh[b];
}

// (2) per-bucket exclusive prefix over chunks, in place; totals[b] = column sum
__global__ __launch_bounds__(64) void colscan_kernel(
    int* __restrict__ cnt, int NCH, int NBK, int* __restrict__ totals)
{
  int b = blockIdx.x;
  int lane = threadIdx.x;
  int carry = 0;
  int rounds = (NCH + 63) >> 6;
  for (int r = 0; r < rounds; r++) {
    int blk = r * 64 + lane;
    int v = (blk < NCH) ? cnt[(size_t)blk * NBK + b] : 0;
    int incl = v;
#pragma unroll
    for (int off = 1; off < 64; off <<= 1) {
      int x = __shfl_up(incl, off);
      if (lane >= off) incl += x;
    }
    int excl = incl - v + carry;
    if (blk < NCH) cnt[(size_t)blk * NBK + b] = excl;
    carry += __shfl(incl, 63);
  }
  if (lane == 0) totals[b] = carry;
}

// (3) exclusive scan of bucket totals -> bstart[NBK+1]; rowptr[N] = total
__global__ __launch_bounds__(512) void scan_totals_kernel(
    const int* __restrict__ totals, int NBK,
    int* __restrict__ bstart, int* __restrict__ rowptr, int N)
{
  __shared__ int sm[512];
  int t = threadIdx.x;
  int v = (t < NBK) ? totals[t] : 0;
  sm[t] = v;
  __syncthreads();
  for (int off = 1; off < 512; off <<= 1) {
    int x = 0;
    if (t >= off) x = sm[t - off];
    __syncthreads();
    if (t >= off) sm[t] += x;
    __syncthreads();
  }
  if (t < NBK) bstart[t] = sm[t] - v;
  if (t == 0) { bstart[NBK] = sm[511]; rowptr[N] = sm[511]; }
}

// (4) placement: each chunk writes contiguous runs per bucket; packed = src | (dst&2047)<<20
__global__ __launch_bounds__(256) void pass3_kernel(
    const int* __restrict__ edges, int E, int N, const int* __restrict__ flag,
    const int* __restrict__ cnt, const int* __restrict__ bstart,
    int* __restrict__ pair, int NBK)
{
  __shared__ int lcur[512];
  int t = threadIdx.x;
  int blk = blockIdx.x;
  for (int b = t; b < NBK; b += 256)
    lcur[b] = bstart[b] + cnt[(size_t)blk * NBK + b];
  __syncthreads();
  int sh = flag[0];
  int base = blk * CHUNK;
#pragma unroll
  for (int k = 0; k < CHUNK / 256; k++) {
    int e = base + k * 256 + t;
    if (e < E) {
      int s = edges[e << sh];
      int d = edges[(E + e) << sh];
      if ((unsigned)s < (unsigned)N && (unsigned)d < (unsigned)N) {
        int pos = atomicAdd(&lcur[d >> BSH], 1);
        pair[pos] = s | ((d & (BNODES - 1)) << 20);
      }
    }
  }
}

// (5) per-bucket CSR build: LDS hist(2048) -> scan -> rowptr/dinv -> place via LDS cursors
__global__ __launch_bounds__(256) void build_kernel(
    const int* __restrict__ pair, const int* __restrict__ bstart,
    int* __restrict__ rowptr, float* __restrict__ dinv, int* __restrict__ col, int N)
{
  __shared__ int hist[BNODES];
  __shared__ int cur[BNODES];
  __shared__ int sc[256];
  int b = blockIdx.x;
  int t = threadIdx.x;
  int pbeg = bstart[b], pend = bstart[b + 1];
#pragma unroll
  for (int i = 0; i < BNODES / 256; i++) hist[i * 256 + t] = 0;
  __syncthreads();
  for (int p = pbeg + t; p < pend; p += 256)
    atomicAdd(&hist[(pair[p] >> 20) & (BNODES - 1)], 1);
  __syncthreads();
  int hv[8];
  int tsum = 0;
#pragma unroll
  for (int i = 0; i < 8; i++) { hv[i] = hist[t * 8 + i]; tsum += hv[i]; }
  sc[t] = tsum;
  __syncthreads();
  for (int off = 1; off < 256; off <<= 1) {
    int x = 0;
    if (t >= off) x = sc[t - off];
    __syncthreads();
    if (t >= off) sc[t] += x;
    __syncthreads();
  }
  int run = sc[t] - tsum;
#pragma unroll
  for (int i = 0; i < 8; i++) {
    int idx = t * 8 + i;
    int rp = pbeg + run;
    cur[idx] = rp;
    int row = (b << BSH) + idx;
    if (row < N) {
      rowptr[row] = rp;
      dinv[row] = rsqrtf((float)(hv[i] + 1));  // deg = dst-count + 1 (self loop)
    }
    run += hv[i];
  }
  __syncthreads();
  for (int p = pbeg + t; p < pend; p += 256) {
    int v = pair[p];
    int pos = atomicAdd(&cur[(v >> 20) & (BNODES - 1)], 1);
    col[pos] = v & 0xFFFFF;
  }
}

// MFMA mm1: per wave, 16 nodes; D[16][64] = x-tile(fp16) @ W1; G = dinv*D (fp16).
__global__ __launch_bounds__(256) void mfma_mm1_kernel(
    const float* __restrict__ X, const float* __restrict__ W1,
    const float* __restrict__ dinv, __half* __restrict__ G, int n, int ntiles)
{
  int lane = threadIdx.x & 63;
  int n16 = lane & 15;
  int quad = lane >> 4;

  half8 bf[4];
#pragma unroll
  for (int jb = 0; jb < 4; jb++)
#pragma unroll
    for (int i = 0; i < 8; i++)
      bf[jb][i] = (_Float16)W1[(quad * 8 + i) * 64 + jb * 16 + n16];

  _Float16* Gh = (_Float16*)G;
  int wave = (blockIdx.x * 256 + threadIdx.x) >> 6;
  int nw = (gridDim.x * 256) >> 6;
  for (int tile = wave; tile < ntiles; tile += nw) {
    int ut = __builtin_amdgcn_readfirstlane(tile);
    int base = ut * 16;
    int node = base + n16;
    if (node >= n) node = n - 1;
    const float* xr = X + (size_t)node * 32 + quad * 8;
    half8 a;
#pragma unroll
    for (int i = 0; i < 8; i++) a[i] = (_Float16)xr[i];

    float4v acc[4];
#pragma unroll
    for (int jb = 0; jb < 4; jb++) {
      float4v z = {0.f, 0.f, 0.f, 0.f};
      acc[jb] = __builtin_amdgcn_mfma_f32_16x16x32_f16(a, bf[jb], z, 0, 0, 0);
    }
#pragma unroll
    for (int r = 0; r < 4; r++) {
      int node2 = base + quad * 4 + r;
      if (node2 < n) {
        float dv = dinv[node2];
#pragma unroll
        for (int jb = 0; jb < 4; jb++)
          Gh[(size_t)node2 * 64 + jb * 16 + n16] = (_Float16)(dv * acc[jb][r]);
      }
    }
  }
}

__device__ inline void hacc(uint4 v, __half2* a)
{
  a[0] = __hadd2(a[0], *reinterpret_cast<__half2*>(&v.x));
  a[1] = __hadd2(a[1], *reinterpret_cast<__half2*>(&v.y));
  a[2] = __hadd2(a[2], *reinterpret_cast<__half2*>(&v.z));
  a[3] = __hadd2(a[3], *reinterpret_cast<__half2*>(&v.w));
}

// Aggregation: lane = (eg = lane>>3 in [0,8), fo = lane&7). One dwordx4 covers
// 8 edges' 16B feature-chunks (1KB/instr). fp16 packed accumulation; 2 nodes/wave.
template <bool RELU>
__global__ __launch_bounds__(256) void agg_kernel(
    const __half* __restrict__ Gsrc, const int* __restrict__ rowptr,
    const int* __restrict__ col, const float* __restrict__ dinv,
    const float* __restrict__ bias, __half* __restrict__ Udst, int n)
{
  int lane = threadIdx.x & 63;
  int eg = lane >> 3, fo = lane & 7;
  int w = (blockIdx.x * 256 + threadIdx.x) >> 6;
  int node0 = w * 2, node1 = w * 2 + 1;
  if (node0 >= n) return;
  bool has1 = (node1 < n);
  const uint4* G4 = (const uint4*)Gsrc;
  uint4* U4 = (uint4*)Udst;

  int beg0 = rowptr[node0], end0 = rowptr[node0 + 1];
  int beg1 = has1 ? rowptr[node1] : 0;
  int end1 = has1 ? rowptr[node1 + 1] : 0;

  __half2 z2 = __floats2half2_rn(0.f, 0.f);
  __half2 a0[4] = {z2, z2, z2, z2};
  __half2 a1[4] = {z2, z2, z2, z2};

  // self rows
  uint4 s0 = G4[(size_t)node0 * 8 + fo];
  uint4 s1 = G4[(size_t)(has1 ? node1 : node0) * 8 + fo];

  // main: 2 batches of 8 edges per node, exec-mask predicated
  {
    uint4 v00 = {0,0,0,0}, v01 = {0,0,0,0}, v10 = {0,0,0,0}, v11 = {0,0,0,0};
    int i00 = beg0 + eg, i01 = beg0 + 8 + eg;
    int i10 = beg1 + eg, i11 = beg1 + 8 + eg;
    if (i00 < end0) v00 = G4[(size_t)col[i00] * 8 + fo];
    if (has1 && i10 < end1) v10 = G4[(size_t)col[i10] * 8 + fo];
    if (i01 < end0) v01 = G4[(size_t)col[i01] * 8 + fo];
    if (has1 && i11 < end1) v11 = G4[(size_t)col[i11] * 8 + fo];
    hacc(v00, a0); hacc(v01, a0);
    hacc(v10, a1); hacc(v11, a1);
  }
  // rare tails (deg > 16)
  for (int e = beg0 + 16; e < end0; e += 8) {
    int i = e + eg;
    if (i < end0) { uint4 v = G4[(size_t)col[i] * 8 + fo]; hacc(v, a0); }
  }
  for (int e = beg1 + 16; e < end1; e += 8) {
    int i = e + eg;
    if (i < end1) { uint4 v = G4[(size_t)col[i] * 8 + fo]; hacc(v, a1); }
  }
  // fold self rows (one edge-group each)
  if (eg == 0) hacc(s0, a0);
  if (eg == 1 && has1) hacc(s1, a1);

  // reduce across the 8 edge-groups (packed halves)
#pragma unroll
  for (int j = 0; j < 4; j++) {
#pragma unroll
    for (int off = 8; off < 64; off <<= 1) {
      int u0 = __shfl_xor(*reinterpret_cast<int*>(&a0[j]), off);
      a0[j] = __hadd2(a0[j], *reinterpret_cast<__half2*>(&u0));
      int u1 = __shfl_xor(*reinterpret_cast<int*>(&a1[j]), off);
      a1[j] = __hadd2(a1[j], *reinterpret_cast<__half2*>(&u1));
    }
  }

  float dv0 = dinv[node0];
  float dv1 = has1 ? dinv[node1] : 0.f;
  float f0[8], f1[8];
#pragma unroll
  for (int j = 0; j < 4; j++) {
    float2 t0 = __half22float2(a0[j]);
    float2 t1 = __half22float2(a1[j]);
    f0[2 * j] = t0.x; f0[2 * j + 1] = t0.y;
    f1[2 * j] = t1.x; f1[2 * j + 1] = t1.y;
  }
  float r0[8], r1[8];
  if (RELU) {
    const float* bp = bias + fo * 8;
    float4 bva = *(const float4*)bp;
    float4 bvb = *(const float4*)(bp + 4);
    float bb[8] = {bva.x, bva.y, bva.z, bva.w, bvb.x, bvb.y, bvb.z, bvb.w};
#pragma unroll
    for (int j = 0; j < 8; j++) {
      float h0 = dv0 * f0[j] + bb[j]; h0 = h0 > 0.f ? h0 : 0.f; r0[j] = dv0 * h0;
      float h1 = dv1 * f1[j] + bb[j]; h1 = h1 > 0.f ? h1 : 0.f; r1[j] = dv1 * h1;
    }
  } else {
#pragma unroll
    for (int j = 0; j < 8; j++) { r0[j] = dv0 * f0[j]; r1[j] = dv1 * f1[j]; }
  }
  uint4 o0, o1;
  {
    __half2 p0 = __floats2half2_rn(r0[0], r0[1]);
    __half2 p1 = __floats2half2_rn(r0[2], r0[3]);
    __half2 p2 = __floats2half2_rn(r0[4], r0[5]);
    __half2 p3 = __floats2half2_rn(r0[6], r0[7]);
    o0.x = *reinterpret_cast<uint*>(&p0); o0.y = *reinterpret_cast<uint*>(&p1);
    o0.z = *reinterpret_cast<uint*>(&p2); o0.w = *reinterpret_cast<uint*>(&p3);
    __half2 q0 = __floats2half2_rn(r1[0], r1[1]);
    __half2 q1 = __floats2half2_rn(r1[2], r1[3]);
    __half2 q2 = __floats2half2_rn(r1[4], r1[5]);
    __half2 q3 = __floats2half2_rn(r1[6], r1[7]);
    o1.x = *reinterpret_cast<uint*>(&q0); o1.y = *reinterpret_cast<uint*>(&q1);
    o1.z = *reinterpret_cast<uint*>(&q2); o1.w = *reinterpret_cast<uint*>(&q3);
  }
  if (eg == 0) U4[(size_t)node0 * 8 + fo] = o0;
  if (eg == 1 && has1) U4[(size_t)node1 * 8 + fo] = o1;
}

__global__ __launch_bounds__(256) void out_init_kernel(
    float* __restrict__ out, const float* __restrict__ bfc, int n)
{
  int i = blockIdx.x * 256 + threadIdx.x;
  if (i < n) out[i] = bfc[0];
}

// MFMA fused layer2-matmul + relu + FC (validated R4)
__global__ __launch_bounds__(256) void mfma_final_kernel(
    const __half* __restrict__ A2, const float* __restrict__ W2,
    const float* __restrict__ b2, const float* __restrict__ Wfc,
    float* __restrict__ out, int ntiles)
{
  int lane = threadIdx.x & 63;
  int n16 = lane & 15;
  int quad = lane >> 4;

  half8 bf[4][2];
#pragma unroll
  for (int jb = 0; jb < 4; jb++)
#pragma unroll
    for (int kf = 0; kf < 2; kf++)
#pragma unroll
      for (int i = 0; i < 8; i++)
        bf[jb][kf][i] = (_Float16)W2[(kf * 32 + quad * 8 + i) * 64 + jb * 16 + n16];
  float b2j[4];
#pragma unroll
  for (int jb = 0; jb < 4; jb++) b2j[jb] = b2[jb * 16 + n16];

  const _Float16* A2h = (const _Float16*)A2;
  int wave = (blockIdx.x * 256 + threadIdx.x) >> 6;
  int nw = (gridDim.x * 256) >> 6;
  for (int tile = wave; tile < ntiles; tile += nw) {
    int ut = __builtin_amdgcn_readfirstlane(tile);
    int base = ut * 16;
    const _Float16* arow = A2h + (size_t)(base + n16) * 64 + quad * 8;
    half8 a0 = *(const half8*)(arow);
    half8 a1 = *(const half8*)(arow + 32);

    int g_r[4], t_r[4];
#pragma unroll
    for (int r = 0; r < 4; r++) {
      int node = base + quad * 4 + r;
      g_r[r] = node / 14;
      t_r[r] = node - g_r[r] * 14;
    }
    float pr[4] = {0.f, 0.f, 0.f, 0.f};
#pragma unroll
    for (int jb = 0; jb < 4; jb++) {
      float4v acc = {0.f, 0.f, 0.f, 0.f};
      acc = __builtin_amdgcn_mfma_f32_16x16x32_f16(a0, bf[jb][0], acc, 0, 0, 0);
      acc = __builtin_amdgcn_mfma_f32_16x16x32_f16(a1, bf[jb][1], acc, 0, 0, 0);
      int j = jb * 16 + n16;
#pragma unroll
      for (int r = 0; r < 4; r++) {
        float h = acc[r] + b2j[jb];
        h = h > 0.f ? h : 0.f;
        pr[r] += h * Wfc[t_r[r] * 64 + j];
      }
    }
#pragma unroll
    for (int r = 0; r < 4; r++) {
#pragma unroll
      for (int off = 1; off < 16; off <<= 1) pr[r] += __shfl_xor(pr[r], off);
    }
    if (n16 == 0) {
#pragma unroll
      for (int r = 0; r < 4; r++) atomicAdd(&out[g_r[r]], pr[r]);
    }
  }
}

extern "C" void kernel_launch(void* const* d_in, const int* in_sizes, int n_in,
                              void* d_out, int out_size, void* d_ws, size_t ws_size,
                              hipStream_t stream)
{
  const float* x = (const float*)d_in[0];
  const int* edges = (const int*)d_in[1];
  const float* W1 = (const float*)d_in[2];
  const float* b1 = (const float*)d_in[3];
  const float* W2 = (const float*)d_in[4];
  const float* b2 = (const float*)d_in[5];
  const float* Wfc = (const float*)d_in[6];
  const float* bfc = (const float*)d_in[7];
  float* out = (float*)d_out;
  (void)n_in;

  const int N = in_sizes[0] / 32;   // 700000
  const int E = in_sizes[1] / 2;    // 4000000
  const int B = out_size;           // 50000
  const int NBK = (N + BNODES - 1) >> BSH;  // 342 buckets (dst>>11)
  const int NCH = (E + CHUNK - 1) / CHUNK;  // 489 chunks

  char* ws = (char*)d_ws;
  size_t off = 0;
  auto alloc = [&](size_t bytes) -> void* {
    void* p = ws + off;
    off += (bytes + 255) & ~(size_t)255;
    return p;
  };
  int* flag = (int*)alloc(256);
  int* cnt = (int*)alloc((size_t)NCH * NBK * 4);
  int* totals = (int*)alloc((size_t)NBK * 4);
  int* bstart = (int*)alloc(((size_t)NBK + 1) * 4);
  int* col = (int*)alloc((size_t)E * 4);
  int* rowptr = (int*)alloc(((size_t)N + 1) * 4);
  float* dinv = (float*)alloc((size_t)N * 4);
  __half* F1 = (__half*)alloc(((size_t)N + 16) * 64 * 2);  // g1, later a2; head aliased as pairbuf
  __half* F2 = (__half*)alloc(((size_t)N + 16) * 64 * 2);  // u1
  int* pair = (int*)F1;  // pairbuf (E*4 = 16MB) dead before mm1 writes F1

  if (off > ws_size) {
    float v = -(float)(double)(ws_size >> 20);
    fallback_kernel<<<(B + 255) / 256, 256, 0, stream>>>(out, B, v);
    return;
  }

  probe_kernel<<<1, 64, 0, stream>>>(edges, flag);
  hist2_kernel<<<NCH, 256, 0, stream>>>(edges, E, N, flag, cnt, NBK);
  colscan_kernel<<<NBK, 64, 0, stream>>>(cnt, NCH, NBK, totals);
  scan_totals_kernel<<<1, 512, 0, stream>>>(totals, NBK, bstart, rowptr, N);
  pass3_kernel<<<NCH, 256, 0, stream>>>(edges, E, N, flag, cnt, bstart, pair, NBK);
  build_kernel<<<NBK, 256, 0, stream>>>(pair, bstart, rowptr, dinv, col, N);

  int ntiles = (N + 15) / 16;   // 43750
  int aggBlocks = (N + 7) / 8;  // 2 nodes per wave, 4 waves per block
  mfma_mm1_kernel<<<4096, 256, 0, stream>>>(x, W1, dinv, F1, N, ntiles);
  agg_kernel<true><<<aggBlocks, 256, 0, stream>>>(F1, rowptr, col, dinv, b1, F2, N);
  agg_kernel<false><<<aggBlocks, 256, 0, stream>>>(F2, rowptr, col, dinv, nullptr, F1, N);
  out_init_kernel<<<(B + 255) / 256, 256, 0, stream>>>(out, bfc, B);
  mfma_final_kernel<<<2048, 256, 0, stream>>>(F1, W2, b2, Wfc, out, ntiles);
}

// Round 13
// 662.073 us; speedup vs baseline: 2.5773x; 1.0954x over previous
//
#include <hip/hip_runtime.h>
#include <hip/hip_fp16.h>

// GCN: h1 = relu(gcn(x,W1,b1)); h2 = relu(gcn(h1,W2,b2)); out = h2.reshape(B,896)@Wfc + bfc
// Factored: g1 = dinv*(x@W1); h1 = relu(dinv*agg(g1)+b1); u1 = dinv*h1;
//           a2 = dinv*agg(u1);  h2 = relu(a2@W2+b2)  [agg commutes with @W2]
// CSR via deterministic counting sort (b=dst>>11, NBK=342), no global atomics.
// Self-loop stored IN the CSR row; dummy zero row at index N lets agg clamp the
// column index (1 cndmask) instead of predicating loaded values (R11: predication
// machinery, not adds, consumed the VALU). Packed-fp16 agg accumulate + epilogue
// (relu via scalar __hmax — ROCm 7.2 lacks a __half2 __hmax2 overload).
// mm1 and layer2+FC on MFMA.

typedef _Float16 half8 __attribute__((ext_vector_type(8)));
typedef float float4v __attribute__((ext_vector_type(4)));

#define CHUNK 8192
#define BSH 11
#define BNODES 2048

__global__ __launch_bounds__(256) void fallback_kernel(float* __restrict__ out, int n, float v)
{
  int i = blockIdx.x * 256 + threadIdx.x;
  if (i < n) out[i] = v;
}

// detect edges dtype: int64 values < 2^31 -> every odd int32 word is 0
__global__ __launch_bounds__(64) void probe_kernel(const int* __restrict__ edges, int* __restrict__ flag)
{
  if (threadIdx.x == 0) {
    int orv = edges[1] | edges[3] | edges[5] | edges[7] | edges[9] | edges[11] | edges[13] | edges[15];
    flag[0] = (orv == 0) ? 1 : 0;  // 1 => int64 layout (shift word index by 1)
  }
}

// zero the dummy rows (index N) of both feature buffers (ws is poisoned every call)
__global__ __launch_bounds__(64) void zero_dummy_kernel(
    __half* __restrict__ F1, __half* __restrict__ F2, int N)
{
  int t = threadIdx.x;
  if (t < 16) ((uint2*)(F1 + (size_t)N * 64))[t] = make_uint2(0, 0);
  else if (t < 32) ((uint2*)(F2 + (size_t)N * 64))[t - 16] = make_uint2(0, 0);
}

// (1) per-chunk bucket histogram -> cnt[chunk][b]  (coalesced row write)
__global__ __launch_bounds__(256) void hist2_kernel(
    const int* __restrict__ edges, int E, int N, const int* __restrict__ flag,
    int* __restrict__ cnt, int NBK)
{
  __shared__ int lh[512];
  int t = threadIdx.x;
  int blk = blockIdx.x;
  for (int b = t; b < NBK; b += 256) lh[b] = 0;
  __syncthreads();
  int sh = flag[0];
  int base = blk * CHUNK;
#pragma unroll
  for (int k = 0; k < CHUNK / 256; k++) {
    int e = base + k * 256 + t;
    if (e < E) {
      int d = edges[(E + e) << sh];
      if ((unsigned)d < (unsigned)N) atomicAdd(&lh[d >> BSH], 1);
    }
  }
  __syncthreads();
  for (int b = t; b < NBK; b += 256) cnt[(size_t)blk * NBK + b] = lh[b];
}

// (2) per-bucket exclusive prefix over chunks, in place; totals[b] = column sum
__global__ __launch_bounds__(64) void colscan_kernel(
    int* __restrict__ cnt, int NCH, int NBK, int* __restrict__ totals)
{
  int b = blockIdx.x;
  int lane = threadIdx.x;
  int carry = 0;
  int rounds = (NCH + 63) >> 6;
  for (int r = 0; r < rounds; r++) {
    int blk = r * 64 + lane;
    int v = (blk < NCH) ? cnt[(size_t)blk * NBK + b] : 0;
    int incl = v;
#pragma unroll
    for (int off = 1; off < 64; off <<= 1) {
      int x = __shfl_up(incl, off);
      if (lane >= off) incl += x;
    }
    int excl = incl - v + carry;
    if (blk < NCH) cnt[(size_t)blk * NBK + b] = excl;
    carry += __shfl(incl, 63);
  }
  if (lane == 0) totals[b] = carry;
}

// (3) exclusive scan of bucket totals -> bstart[NBK+1]; rowptr[N] = Ev + N (self entries)
__global__ __launch_bounds__(512) void scan_totals_kernel(
    const int* __restrict__ totals, int NBK,
    int* __restrict__ bstart, int* __restrict__ rowptr, int N)
{
  __shared__ int sm[512];
  int t = threadIdx.x;
  int v = (t < NBK) ? totals[t] : 0;
  sm[t] = v;
  __syncthreads();
  for (int off = 1; off < 512; off <<= 1) {
    int x = 0;
    if (t >= off) x = sm[t - off];
    __syncthreads();
    if (t >= off) sm[t] += x;
    __syncthreads();
  }
  if (t < NBK) bstart[t] = sm[t] - v;
  if (t == 0) { bstart[NBK] = sm[511]; rowptr[N] = sm[511] + N; }
}

// (4) placement: each chunk writes contiguous runs per bucket; packed = src | (dst&2047)<<20
__global__ __launch_bounds__(256) void pass3_kernel(
    const int* __restrict__ edges, int E, int N, const int* __restrict__ flag,
    const int* __restrict__ cnt, const int* __restrict__ bstart,
    int* __restrict__ pair, int NBK)
{
  __shared__ int lcur[512];
  int t = threadIdx.x;
  int blk = blockIdx.x;
  for (int b = t; b < NBK; b += 256)
    lcur[b] = bstart[b] + cnt[(size_t)blk * NBK + b];
  __syncthreads();
  int sh = flag[0];
  int base = blk * CHUNK;
#pragma unroll
  for (int k = 0; k < CHUNK / 256; k++) {
    int e = base + k * 256 + t;
    if (e < E) {
      int s = edges[e << sh];
      int d = edges[(E + e) << sh];
      if ((unsigned)s < (unsigned)N && (unsigned)d < (unsigned)N) {
        int pos = atomicAdd(&lcur[d >> BSH], 1);
        pair[pos] = s | ((d & (BNODES - 1)) << 20);
      }
    }
  }
}

// (5) per-bucket CSR build with self entry first in each row.
// col-space position = pair-space position + (#rows before) since each row adds 1 self.
__global__ __launch_bounds__(256) void build_kernel(
    const int* __restrict__ pair, const int* __restrict__ bstart,
    int* __restrict__ rowptr, float* __restrict__ dinv, int* __restrict__ col, int N)
{
  __shared__ int hist[BNODES];
  __shared__ int cur[BNODES];
  __shared__ int sc[256];
  int b = blockIdx.x;
  int t = threadIdx.x;
  int pbeg = bstart[b], pend = bstart[b + 1];
  int colbase = pbeg + (b << BSH);  // prior buckets contribute b*2048 self entries
#pragma unroll
  for (int i = 0; i < BNODES / 256; i++) {
    int idx = i * 256 + t;
    int row = (b << BSH) + idx;
    hist[idx] = (row < N) ? 1 : 0;  // self entry
  }
  __syncthreads();
  for (int p = pbeg + t; p < pend; p += 256)
    atomicAdd(&hist[(pair[p] >> 20) & (BNODES - 1)], 1);
  __syncthreads();
  int hv[8];
  int tsum = 0;
#pragma unroll
  for (int i = 0; i < 8; i++) { hv[i] = hist[t * 8 + i]; tsum += hv[i]; }
  sc[t] = tsum;
  __syncthreads();
  for (int off = 1; off < 256; off <<= 1) {
    int x = 0;
    if (t >= off) x = sc[t - off];
    __syncthreads();
    if (t >= off) sc[t] += x;
    __syncthreads();
  }
  int run = sc[t] - tsum;
#pragma unroll
  for (int i = 0; i < 8; i++) {
    int idx = t * 8 + i;
    int rp = colbase + run;
    int row = (b << BSH) + idx;
    if (row < N) {
      rowptr[row] = rp;
      dinv[row] = rsqrtf((float)hv[i]);  // hv = deg + 1 (self included)
      col[rp] = row;                      // self entry at slot 0
      cur[idx] = rp + 1;
    } else {
      cur[idx] = rp;
    }
    run += hv[i];
  }
  __syncthreads();
  for (int p = pbeg + t; p < pend; p += 256) {
    int v = pair[p];
    int pos = atomicAdd(&cur[(v >> 20) & (BNODES - 1)], 1);
    col[pos] = v & 0xFFFFF;
  }
}

// MFMA mm1: per wave, 16 nodes; D[16][64] = x-tile(fp16) @ W1; G = dinv*D (fp16).
__global__ __launch_bounds__(256) void mfma_mm1_kernel(
    const float* __restrict__ X, const float* __restrict__ W1,
    const float* __restrict__ dinv, __half* __restrict__ G, int n, int ntiles)
{
  int lane = threadIdx.x & 63;
  int n16 = lane & 15;
  int quad = lane >> 4;

  half8 bf[4];
#pragma unroll
  for (int jb = 0; jb < 4; jb++)
#pragma unroll
    for (int i = 0; i < 8; i++)
      bf[jb][i] = (_Float16)W1[(quad * 8 + i) * 64 + jb * 16 + n16];

  _Float16* Gh = (_Float16*)G;
  int wave = (blockIdx.x * 256 + threadIdx.x) >> 6;
  int nw = (gridDim.x * 256) >> 6;
  for (int tile = wave; tile < ntiles; tile += nw) {
    int ut = __builtin_amdgcn_readfirstlane(tile);
    int base = ut * 16;
    int node = base + n16;
    if (node >= n) node = n - 1;
    const float* xr = X + (size_t)node * 32 + quad * 8;
    half8 a;
#pragma unroll
    for (int i = 0; i < 8; i++) a[i] = (_Float16)xr[i];

    float4v acc[4];
#pragma unroll
    for (int jb = 0; jb < 4; jb++) {
      float4v z = {0.f, 0.f, 0.f, 0.f};
      acc[jb] = __builtin_amdgcn_mfma_f32_16x16x32_f16(a, bf[jb], z, 0, 0, 0);
    }
#pragma unroll
    for (int r = 0; r < 4; r++) {
      int node2 = base + quad * 4 + r;
      if (node2 < n) {
        float dv = dinv[node2];
#pragma unroll
        for (int jb = 0; jb < 4; jb++)
          Gh[(size_t)node2 * 64 + jb * 16 + n16] = (_Float16)(dv * acc[jb][r]);
      }
    }
  }
}

__device__ inline void hacc(uint4 v, __half2* a)
{
  a[0] = __hadd2(a[0], *reinterpret_cast<__half2*>(&v.x));
  a[1] = __hadd2(a[1], *reinterpret_cast<__half2*>(&v.y));
  a[2] = __hadd2(a[2], *reinterpret_cast<__half2*>(&v.z));
  a[3] = __hadd2(a[3], *reinterpret_cast<__half2*>(&v.w));
}

__device__ inline __half2 hrelu2(__half2 v)
{
  __half z = __float2half_rn(0.f);
  __half2 r;
  r.x = __hmax(v.x, z);
  r.y = __hmax(v.y, z);
  return r;
}

// Aggregation: lane = (eg = lane>>3 in [0,8), fo = lane&7). One dwordx4 covers
// 8 row entries x 16B (1KB/instr). Rows include self; out-of-range slots clamp
// the column index to the dummy zero row (index ndummy) — loads unconditional.
// Packed fp16 accumulate + epilogue. 2 nodes/wave (rows contiguous: beg1 == end0).
template <bool RELU>
__global__ __launch_bounds__(256) void agg_kernel(
    const __half* __restrict__ Gsrc, const int* __restrict__ rowptr,
    const int* __restrict__ col, const float* __restrict__ dinv,
    const float* __restrict__ bias, __half* __restrict__ Udst, int n, int ndummy)
{
  int lane = threadIdx.x & 63;
  int eg = lane >> 3, fo = lane & 7;
  int w = (int)((blockIdx.x * 256 + threadIdx.x) >> 6);
  w = __builtin_amdgcn_readfirstlane(w);
  int node0 = w * 2, node1 = node0 + 1;
  if (node0 >= n) return;
  bool has1 = (node1 < n);
  const uint4* G4 = (const uint4*)Gsrc;
  uint4* U4 = (uint4*)Udst;

  int beg0 = rowptr[node0];
  int end0 = rowptr[node0 + 1];
  int end1 = has1 ? rowptr[node0 + 2] : end0;  // beg1 == end0 (rows contiguous)

  __half2 z2 = __float2half2_rn(0.f);
  __half2 a0[4] = {z2, z2, z2, z2};
  __half2 a1[4] = {z2, z2, z2, z2};

  // first batch for both nodes, unconditional (every row has >= 1 entry)
  {
    int i0 = beg0 + eg, i1 = end0 + eg;
    int c0 = col[i0], c1 = col[i1];
    c0 = (i0 < end0) ? c0 : ndummy;
    c1 = (i1 < end1) ? c1 : ndummy;
    uint4 v0 = G4[((size_t)c0 << 3) + fo];
    uint4 v1 = G4[((size_t)c1 << 3) + fo];
    hacc(v0, a0);
    hacc(v1, a1);
  }
  // rare tails (row length > 8)
  for (int i = beg0 + 8; i < end0; i += 8) {
    int ii = i + eg;
    int c = col[ii];
    c = (ii < end0) ? c : ndummy;
    uint4 v = G4[((size_t)c << 3) + fo];
    hacc(v, a0);
  }
  for (int i = end0 + 8; i < end1; i += 8) {
    int ii = i + eg;
    int c = col[ii];
    c = (ii < end1) ? c : ndummy;
    uint4 v = G4[((size_t)c << 3) + fo];
    hacc(v, a1);
  }

  // reduce across the 8 edge-groups (lanes differ in bits 3..5)
#pragma unroll
  for (int j = 0; j < 4; j++) {
#pragma unroll
    for (int off = 8; off < 64; off <<= 1) {
      int u0 = __shfl_xor(*reinterpret_cast<int*>(&a0[j]), off);
      a0[j] = __hadd2(a0[j], *reinterpret_cast<__half2*>(&u0));
      int u1 = __shfl_xor(*reinterpret_cast<int*>(&a1[j]), off);
      a1[j] = __hadd2(a1[j], *reinterpret_cast<__half2*>(&u1));
    }
  }

  __half2 d0 = __half2half2(__float2half_rn(dinv[node0]));
  __half2 d1 = __half2half2(__float2half_rn(has1 ? dinv[node1] : 0.f));
  __half2 r0[4], r1[4];
  if (RELU) {
    const float* bp = bias + fo * 8;
    float4 ba = *(const float4*)bp;
    float4 bb = *(const float4*)(bp + 4);
    __half2 bh[4] = {__floats2half2_rn(ba.x, ba.y), __floats2half2_rn(ba.z, ba.w),
                     __floats2half2_rn(bb.x, bb.y), __floats2half2_rn(bb.z, bb.w)};
#pragma unroll
    for (int j = 0; j < 4; j++) {
      __half2 h0 = hrelu2(__hadd2(__hmul2(a0[j], d0), bh[j]));
      r0[j] = __hmul2(h0, d0);
      __half2 h1 = hrelu2(__hadd2(__hmul2(a1[j], d1), bh[j]));
      r1[j] = __hmul2(h1, d1);
    }
  } else {
#pragma unroll
    for (int j = 0; j < 4; j++) {
      r0[j] = __hmul2(a0[j], d0);
      r1[j] = __hmul2(a1[j], d1);
    }
  }
  uint4 o0, o1;
  o0.x = *reinterpret_cast<uint*>(&r0[0]); o0.y = *reinterpret_cast<uint*>(&r0[1]);
  o0.z = *reinterpret_cast<uint*>(&r0[2]); o0.w = *reinterpret_cast<uint*>(&r0[3]);
  o1.x = *reinterpret_cast<uint*>(&r1[0]); o1.y = *reinterpret_cast<uint*>(&r1[1]);
  o1.z = *reinterpret_cast<uint*>(&r1[2]); o1.w = *reinterpret_cast<uint*>(&r1[3]);
  if (eg == 0) U4[((size_t)node0 << 3) + fo] = o0;
  if (eg == 1 && has1) U4[((size_t)node1 << 3) + fo] = o1;
}

__global__ __launch_bounds__(256) void out_init_kernel(
    float* __restrict__ out, const float* __restrict__ bfc, int n)
{
  int i = blockIdx.x * 256 + threadIdx.x;
  if (i < n) out[i] = bfc[0];
}

// MFMA fused layer2-matmul + relu + FC (validated R4)
__global__ __launch_bounds__(256) void mfma_final_kernel(
    const __half* __restrict__ A2, const float* __restrict__ W2,
    const float* __restrict__ b2, const float* __restrict__ Wfc,
    float* __restrict__ out, int ntiles)
{
  int lane = threadIdx.x & 63;
  int n16 = lane & 15;
  int quad = lane >> 4;

  half8 bf[4][2];
#pragma unroll
  for (int jb = 0; jb < 4; jb++)
#pragma unroll
    for (int kf = 0; kf < 2; kf++)
#pragma unroll
      for (int i = 0; i < 8; i++)
        bf[jb][kf][i] = (_Float16)W2[(kf * 32 + quad * 8 + i) * 64 + jb * 16 + n16];
  float b2j[4];
#pragma unroll
  for (int jb = 0; jb < 4; jb++) b2j[jb] = b2[jb * 16 + n16];

  const _Float16* A2h = (const _Float16*)A2;
  int wave = (blockIdx.x * 256 + threadIdx.x) >> 6;
  int nw = (gridDim.x * 256) >> 6;
  for (int tile = wave; tile < ntiles; tile += nw) {
    int ut = __builtin_amdgcn_readfirstlane(tile);
    int base = ut * 16;
    const _Float16* arow = A2h + (size_t)(base + n16) * 64 + quad * 8;
    half8 a0 = *(const half8*)(arow);
    half8 a1 = *(const half8*)(arow + 32);

    int g_r[4], t_r[4];
#pragma unroll
    for (int r = 0; r < 4; r++) {
      int node = base + quad * 4 + r;
      g_r[r] = node / 14;
      t_r[r] = node - g_r[r] * 14;
    }
    float pr[4] = {0.f, 0.f, 0.f, 0.f};
#pragma unroll
    for (int jb = 0; jb < 4; jb++) {
      float4v acc = {0.f, 0.f, 0.f, 0.f};
      acc = __builtin_amdgcn_mfma_f32_16x16x32_f16(a0, bf[jb][0], acc, 0, 0, 0);
      acc = __builtin_amdgcn_mfma_f32_16x16x32_f16(a1, bf[jb][1], acc, 0, 0, 0);
      int j = jb * 16 + n16;
#pragma unroll
      for (int r = 0; r < 4; r++) {
        float h = acc[r] + b2j[jb];
        h = h > 0.f ? h : 0.f;
        pr[r] += h * Wfc[t_r[r] * 64 + j];
      }
    }
#pragma unroll
    for (int r = 0; r < 4; r++) {
#pragma unroll
      for (int off = 1; off < 16; off <<= 1) pr[r] += __shfl_xor(pr[r], off);
    }
    if (n16 == 0) {
#pragma unroll
      for (int r = 0; r < 4; r++) atomicAdd(&out[g_r[r]], pr[r]);
    }
  }
}

extern "C" void kernel_launch(void* const* d_in, const int* in_sizes, int n_in,
                              void* d_out, int out_size, void* d_ws, size_t ws_size,
                              hipStream_t stream)
{
  const float* x = (const float*)d_in[0];
  const int* edges = (const int*)d_in[1];
  const float* W1 = (const float*)d_in[2];
  const float* b1 = (const float*)d_in[3];
  const float* W2 = (const float*)d_in[4];
  const float* b2 = (const float*)d_in[5];
  const float* Wfc = (const float*)d_in[6];
  const float* bfc = (const float*)d_in[7];
  float* out = (float*)d_out;
  (void)n_in;

  const int N = in_sizes[0] / 32;   // 700000
  const int E = in_sizes[1] / 2;    // 4000000
  const int B = out_size;           // 50000
  const int NBK = (N + BNODES - 1) >> BSH;  // 342 buckets (dst>>11)
  const int NCH = (E + CHUNK - 1) / CHUNK;  // 489 chunks

  char* ws = (char*)d_ws;
  size_t off = 0;
  auto alloc = [&](size_t bytes) -> void* {
    void* p = ws + off;
    off += (bytes + 255) & ~(size_t)255;
    return p;
  };
  int* flag = (int*)alloc(256);
  int* cnt = (int*)alloc((size_t)NCH * NBK * 4);
  int* totals = (int*)alloc((size_t)NBK * 4);
  int* bstart = (int*)alloc(((size_t)NBK + 1) * 4);
  int* col = (int*)alloc(((size_t)E + N + 64) * 4);  // self entries + clamp slack
  int* rowptr = (int*)alloc(((size_t)N + 1) * 4);
  float* dinv = (float*)alloc((size_t)N * 4);
  __half* F1 = (__half*)alloc(((size_t)N + 16) * 64 * 2);  // g1, later a2; head aliased as pairbuf
  __half* F2 = (__half*)alloc(((size_t)N + 16) * 64 * 2);  // u1
  int* pair = (int*)F1;  // pairbuf (E*4 = 16MB) dead before mm1 writes F1

  if (off > ws_size) {
    float v = -(float)(double)(ws_size >> 20);
    fallback_kernel<<<(B + 255) / 256, 256, 0, stream>>>(out, B, v);
    return;
  }

  probe_kernel<<<1, 64, 0, stream>>>(edges, flag);
  zero_dummy_kernel<<<1, 64, 0, stream>>>(F1, F2, N);
  hist2_kernel<<<NCH, 256, 0, stream>>>(edges, E, N, flag, cnt, NBK);
  colscan_kernel<<<NBK, 64, 0, stream>>>(cnt, NCH, NBK, totals);
  scan_totals_kernel<<<1, 512, 0, stream>>>(totals, NBK, bstart, rowptr, N);
  pass3_kernel<<<NCH, 256, 0, stream>>>(edges, E, N, flag, cnt, bstart, pair, NBK);
  build_kernel<<<NBK, 256, 0, stream>>>(pair, bstart, rowptr, dinv, col, N);

  int ntiles = (N + 15) / 16;   // 43750
  int aggBlocks = (N + 7) / 8;  // 2 nodes per wave, 4 waves per block
  mfma_mm1_kernel<<<4096, 256, 0, stream>>>(x, W1, dinv, F1, N, ntiles);
  agg_kernel<true><<<aggBlocks, 256, 0, stream>>>(F1, rowptr, col, dinv, b1, F2, N, N);
  agg_kernel<false><<<aggBlocks, 256, 0, stream>>>(F2, rowptr, col, dinv, nullptr, F1, N, N);
  out_init_kernel<<<(B + 255) / 256, 256, 0, stream>>>(out, bfc, B);
  mfma_final_kernel<<<2048, 256, 0, stream>>>(F1, W2, b2, Wfc, out, ntiles);
}

// Round 14
// 622.432 us; speedup vs baseline: 2.7414x; 1.0637x over previous
//
#include <hip/hip_runtime.h>
#include <hip/hip_fp16.h>

// GCN: h1 = relu(gcn(x,W1,b1)); h2 = relu(gcn(h1,W2,b2)); out = h2.reshape(B,896)@Wfc + bfc
// Factored: g1 = dinv*(x@W1); h1 = relu(dinv*agg(g1)+b1); u1 = dinv*h1;
//           h2 = relu((dinv*agg(u1))@W2+b2)  [agg commutes with @W2]
// CSR via deterministic counting sort (b=dst>>11), self-loop stored in-row, dummy
// zero row at N for clamped gathers. agg1 edge-parallel packed-fp16 (R13, 149us).
// NEW: agg2 FUSED into the MFMA final — u1 rows gathered directly into MFMA
// A-fragments (lane(m,quad) owns 16B of row m), pk_add accumulate, scale by dinv,
// then 8 MFMAs + relu + Wfc dot. Kills agg2's kernel, 87.5MB write, 90MB re-read,
// its lane-reduce and epilogue entirely.

typedef _Float16 half8 __attribute__((ext_vector_type(8)));
typedef float float4v __attribute__((ext_vector_type(4)));

#define CHUNK 8192
#define BSH 11
#define BNODES 2048

__global__ __launch_bounds__(256) void fallback_kernel(float* __restrict__ out, int n, float v)
{
  int i = blockIdx.x * 256 + threadIdx.x;
  if (i < n) out[i] = v;
}

// detect edges dtype: int64 values < 2^31 -> every odd int32 word is 0
__global__ __launch_bounds__(64) void probe_kernel(const int* __restrict__ edges, int* __restrict__ flag)
{
  if (threadIdx.x == 0) {
    int orv = edges[1] | edges[3] | edges[5] | edges[7] | edges[9] | edges[11] | edges[13] | edges[15];
    flag[0] = (orv == 0) ? 1 : 0;  // 1 => int64 layout (shift word index by 1)
  }
}

// zero the dummy rows (index N) of both feature buffers (ws is poisoned every call)
__global__ __launch_bounds__(64) void zero_dummy_kernel(
    __half* __restrict__ F1, __half* __restrict__ F2, int N)
{
  int t = threadIdx.x;
  if (t < 16) ((uint2*)(F1 + (size_t)N * 64))[t] = make_uint2(0, 0);
  else if (t < 32) ((uint2*)(F2 + (size_t)N * 64))[t - 16] = make_uint2(0, 0);
}

// (1) per-chunk bucket histogram -> cnt[chunk][b]
__global__ __launch_bounds__(256) void hist2_kernel(
    const int* __restrict__ edges, int E, int N, const int* __restrict__ flag,
    int* __restrict__ cnt, int NBK)
{
  __shared__ int lh[512];
  int t = threadIdx.x;
  int blk = blockIdx.x;
  for (int b = t; b < NBK; b += 256) lh[b] = 0;
  __syncthreads();
  int sh = flag[0];
  int base = blk * CHUNK;
#pragma unroll
  for (int k = 0; k < CHUNK / 256; k++) {
    int e = base + k * 256 + t;
    if (e < E) {
      int d = edges[(E + e) << sh];
      if ((unsigned)d < (unsigned)N) atomicAdd(&lh[d >> BSH], 1);
    }
  }
  __syncthreads();
  for (int b = t; b < NBK; b += 256) cnt[(size_t)blk * NBK + b] = lh[b];
}

// (2) per-bucket exclusive prefix over chunks, in place; totals[b] = column sum
__global__ __launch_bounds__(64) void colscan_kernel(
    int* __restrict__ cnt, int NCH, int NBK, int* __restrict__ totals)
{
  int b = blockIdx.x;
  int lane = threadIdx.x;
  int carry = 0;
  int rounds = (NCH + 63) >> 6;
  for (int r = 0; r < rounds; r++) {
    int blk = r * 64 + lane;
    int v = (blk < NCH) ? cnt[(size_t)blk * NBK + b] : 0;
    int incl = v;
#pragma unroll
    for (int off = 1; off < 64; off <<= 1) {
      int x = __shfl_up(incl, off);
      if (lane >= off) incl += x;
    }
    int excl = incl - v + carry;
    if (blk < NCH) cnt[(size_t)blk * NBK + b] = excl;
    carry += __shfl(incl, 63);
  }
  if (lane == 0) totals[b] = carry;
}

// (3) exclusive scan of bucket totals -> bstart[NBK+1]; rowptr[N] = Ev + N
__global__ __launch_bounds__(512) void scan_totals_kernel(
    const int* __restrict__ totals, int NBK,
    int* __restrict__ bstart, int* __restrict__ rowptr, int N)
{
  __shared__ int sm[512];
  int t = threadIdx.x;
  int v = (t < NBK) ? totals[t] : 0;
  sm[t] = v;
  __syncthreads();
  for (int off = 1; off < 512; off <<= 1) {
    int x = 0;
    if (t >= off) x = sm[t - off];
    __syncthreads();
    if (t >= off) sm[t] += x;
    __syncthreads();
  }
  if (t < NBK) bstart[t] = sm[t] - v;
  if (t == 0) { bstart[NBK] = sm[511]; rowptr[N] = sm[511] + N; }
}

// (4) placement: contiguous runs per (chunk,bucket); packed = src | (dst&2047)<<20
__global__ __launch_bounds__(256) void pass3_kernel(
    const int* __restrict__ edges, int E, int N, const int* __restrict__ flag,
    const int* __restrict__ cnt, const int* __restrict__ bstart,
    int* __restrict__ pair, int NBK)
{
  __shared__ int lcur[512];
  int t = threadIdx.x;
  int blk = blockIdx.x;
  for (int b = t; b < NBK; b += 256)
    lcur[b] = bstart[b] + cnt[(size_t)blk * NBK + b];
  __syncthreads();
  int sh = flag[0];
  int base = blk * CHUNK;
#pragma unroll
  for (int k = 0; k < CHUNK / 256; k++) {
    int e = base + k * 256 + t;
    if (e < E) {
      int s = edges[e << sh];
      int d = edges[(E + e) << sh];
      if ((unsigned)s < (unsigned)N && (unsigned)d < (unsigned)N) {
        int pos = atomicAdd(&lcur[d >> BSH], 1);
        pair[pos] = s | ((d & (BNODES - 1)) << 20);
      }
    }
  }
}

// (5) per-bucket CSR build with self entry first in each row.
__global__ __launch_bounds__(256) void build_kernel(
    const int* __restrict__ pair, const int* __restrict__ bstart,
    int* __restrict__ rowptr, float* __restrict__ dinv, int* __restrict__ col, int N)
{
  __shared__ int hist[BNODES];
  __shared__ int cur[BNODES];
  __shared__ int sc[256];
  int b = blockIdx.x;
  int t = threadIdx.x;
  int pbeg = bstart[b], pend = bstart[b + 1];
  int colbase = pbeg + (b << BSH);
#pragma unroll
  for (int i = 0; i < BNODES / 256; i++) {
    int idx = i * 256 + t;
    int row = (b << BSH) + idx;
    hist[idx] = (row < N) ? 1 : 0;  // self entry
  }
  __syncthreads();
  for (int p = pbeg + t; p < pend; p += 256)
    atomicAdd(&hist[(pair[p] >> 20) & (BNODES - 1)], 1);
  __syncthreads();
  int hv[8];
  int tsum = 0;
#pragma unroll
  for (int i = 0; i < 8; i++) { hv[i] = hist[t * 8 + i]; tsum += hv[i]; }
  sc[t] = tsum;
  __syncthreads();
  for (int off = 1; off < 256; off <<= 1) {
    int x = 0;
    if (t >= off) x = sc[t - off];
    __syncthreads();
    if (t >= off) sc[t] += x;
    __syncthreads();
  }
  int run = sc[t] - tsum;
#pragma unroll
  for (int i = 0; i < 8; i++) {
    int idx = t * 8 + i;
    int rp = colbase + run;
    int row = (b << BSH) + idx;
    if (row < N) {
      rowptr[row] = rp;
      dinv[row] = rsqrtf((float)hv[i]);  // hv = deg + 1 (self included)
      col[rp] = row;                      // self entry at slot 0
      cur[idx] = rp + 1;
    } else {
      cur[idx] = rp;
    }
    run += hv[i];
  }
  __syncthreads();
  for (int p = pbeg + t; p < pend; p += 256) {
    int v = pair[p];
    int pos = atomicAdd(&cur[(v >> 20) & (BNODES - 1)], 1);
    col[pos] = v & 0xFFFFF;
  }
}

// MFMA mm1: per wave, 16 nodes; D[16][64] = x-tile(fp16) @ W1; G = dinv*D (fp16).
__global__ __launch_bounds__(256) void mfma_mm1_kernel(
    const float* __restrict__ X, const float* __restrict__ W1,
    const float* __restrict__ dinv, __half* __restrict__ G, int n, int ntiles)
{
  int lane = threadIdx.x & 63;
  int n16 = lane & 15;
  int quad = lane >> 4;

  half8 bf[4];
#pragma unroll
  for (int jb = 0; jb < 4; jb++)
#pragma unroll
    for (int i = 0; i < 8; i++)
      bf[jb][i] = (_Float16)W1[(quad * 8 + i) * 64 + jb * 16 + n16];

  _Float16* Gh = (_Float16*)G;
  int wave = (blockIdx.x * 256 + threadIdx.x) >> 6;
  int nw = (gridDim.x * 256) >> 6;
  for (int tile = wave; tile < ntiles; tile += nw) {
    int ut = __builtin_amdgcn_readfirstlane(tile);
    int base = ut * 16;
    int node = base + n16;
    if (node >= n) node = n - 1;
    const float* xr = X + (size_t)node * 32 + quad * 8;
    half8 a;
#pragma unroll
    for (int i = 0; i < 8; i++) a[i] = (_Float16)xr[i];

    float4v acc[4];
#pragma unroll
    for (int jb = 0; jb < 4; jb++) {
      float4v z = {0.f, 0.f, 0.f, 0.f};
      acc[jb] = __builtin_amdgcn_mfma_f32_16x16x32_f16(a, bf[jb], z, 0, 0, 0);
    }
#pragma unroll
    for (int r = 0; r < 4; r++) {
      int node2 = base + quad * 4 + r;
      if (node2 < n) {
        float dv = dinv[node2];
#pragma unroll
        for (int jb = 0; jb < 4; jb++)
          Gh[(size_t)node2 * 64 + jb * 16 + n16] = (_Float16)(dv * acc[jb][r]);
      }
    }
  }
}

__device__ inline void hacc(uint4 v, __half2* a)
{
  a[0] = __hadd2(a[0], *reinterpret_cast<__half2*>(&v.x));
  a[1] = __hadd2(a[1], *reinterpret_cast<__half2*>(&v.y));
  a[2] = __hadd2(a[2], *reinterpret_cast<__half2*>(&v.z));
  a[3] = __hadd2(a[3], *reinterpret_cast<__half2*>(&v.w));
}

__device__ inline __half2 hrelu2(__half2 v)
{
  __half z = __float2half_rn(0.f);
  __half2 r;
  r.x = __hmax(v.x, z);
  r.y = __hmax(v.y, z);
  return r;
}

// agg1: lane = (eg = lane>>3, fo = lane&7); one dwordx4 covers 8 row entries x 16B.
// Rows include self; clamp col to dummy row. Packed fp16. 2 nodes/wave.
// u1 = dinv * relu(dinv*sum + b1)
__global__ __launch_bounds__(256) void agg_kernel(
    const __half* __restrict__ Gsrc, const int* __restrict__ rowptr,
    const int* __restrict__ col, const float* __restrict__ dinv,
    const float* __restrict__ bias, __half* __restrict__ Udst, int n, int ndummy)
{
  int lane = threadIdx.x & 63;
  int eg = lane >> 3, fo = lane & 7;
  int w = (int)((blockIdx.x * 256 + threadIdx.x) >> 6);
  w = __builtin_amdgcn_readfirstlane(w);
  int node0 = w * 2, node1 = node0 + 1;
  if (node0 >= n) return;
  bool has1 = (node1 < n);
  const uint4* G4 = (const uint4*)Gsrc;
  uint4* U4 = (uint4*)Udst;

  int beg0 = rowptr[node0];
  int end0 = rowptr[node0 + 1];
  int end1 = has1 ? rowptr[node0 + 2] : end0;

  __half2 z2 = __float2half2_rn(0.f);
  __half2 a0[4] = {z2, z2, z2, z2};
  __half2 a1[4] = {z2, z2, z2, z2};

  {
    int i0 = beg0 + eg, i1 = end0 + eg;
    int c0 = col[i0], c1 = col[i1];
    c0 = (i0 < end0) ? c0 : ndummy;
    c1 = (i1 < end1) ? c1 : ndummy;
    uint4 v0 = G4[((size_t)c0 << 3) + fo];
    uint4 v1 = G4[((size_t)c1 << 3) + fo];
    hacc(v0, a0);
    hacc(v1, a1);
  }
  for (int i = beg0 + 8; i < end0; i += 8) {
    int ii = i + eg;
    int c = col[ii];
    c = (ii < end0) ? c : ndummy;
    uint4 v = G4[((size_t)c << 3) + fo];
    hacc(v, a0);
  }
  for (int i = end0 + 8; i < end1; i += 8) {
    int ii = i + eg;
    int c = col[ii];
    c = (ii < end1) ? c : ndummy;
    uint4 v = G4[((size_t)c << 3) + fo];
    hacc(v, a1);
  }

#pragma unroll
  for (int j = 0; j < 4; j++) {
#pragma unroll
    for (int off = 8; off < 64; off <<= 1) {
      int u0 = __shfl_xor(*reinterpret_cast<int*>(&a0[j]), off);
      a0[j] = __hadd2(a0[j], *reinterpret_cast<__half2*>(&u0));
      int u1 = __shfl_xor(*reinterpret_cast<int*>(&a1[j]), off);
      a1[j] = __hadd2(a1[j], *reinterpret_cast<__half2*>(&u1));
    }
  }

  __half2 d0 = __half2half2(__float2half_rn(dinv[node0]));
  __half2 d1 = __half2half2(__float2half_rn(has1 ? dinv[node1] : 0.f));
  __half2 r0[4], r1[4];
  {
    const float* bp = bias + fo * 8;
    float4 ba = *(const float4*)bp;
    float4 bb = *(const float4*)(bp + 4);
    __half2 bh[4] = {__floats2half2_rn(ba.x, ba.y), __floats2half2_rn(ba.z, ba.w),
                     __floats2half2_rn(bb.x, bb.y), __floats2half2_rn(bb.z, bb.w)};
#pragma unroll
    for (int j = 0; j < 4; j++) {
      __half2 h0 = hrelu2(__hadd2(__hmul2(a0[j], d0), bh[j]));
      r0[j] = __hmul2(h0, d0);
      __half2 h1 = hrelu2(__hadd2(__hmul2(a1[j], d1), bh[j]));
      r1[j] = __hmul2(h1, d1);
    }
  }
  uint4 o0, o1;
  o0.x = *reinterpret_cast<uint*>(&r0[0]); o0.y = *reinterpret_cast<uint*>(&r0[1]);
  o0.z = *reinterpret_cast<uint*>(&r0[2]); o0.w = *reinterpret_cast<uint*>(&r0[3]);
  o1.x = *reinterpret_cast<uint*>(&r1[0]); o1.y = *reinterpret_cast<uint*>(&r1[1]);
  o1.z = *reinterpret_cast<uint*>(&r1[2]); o1.w = *reinterpret_cast<uint*>(&r1[3]);
  if (eg == 0) U4[((size_t)node0 << 3) + fo] = o0;
  if (eg == 1 && has1) U4[((size_t)node1 << 3) + fo] = o1;
}

__global__ __launch_bounds__(256) void out_init_kernel(
    float* __restrict__ out, const float* __restrict__ bfc, int n)
{
  int i = blockIdx.x * 256 + threadIdx.x;
  if (i < n) out[i] = bfc[0];
}

// FUSED agg2 + layer2-matmul + relu + FC.
// Per 16-node tile: gather u1 rows of each node's CSR entries directly into MFMA
// A-fragments (lane(m=lane&15, quad=lane>>4) owns bytes [quad*16,quad*16+16) and
// [64+quad*16, ...) of row m), pk_add fp16 accumulate, scale by dinv[m] -> A = a2.
// Then D = A@W2 (8 MFMAs), h2 = relu(D+b2), out[g] += h2 . Wfc.
__global__ __launch_bounds__(256) void mfma_final_fused_kernel(
    const __half* __restrict__ U, const int* __restrict__ rowptr,
    const int* __restrict__ col, const float* __restrict__ dinv,
    const float* __restrict__ W2, const float* __restrict__ b2,
    const float* __restrict__ Wfc, float* __restrict__ out,
    int ntiles, int ndummy)
{
  int lane = threadIdx.x & 63;
  int n16 = lane & 15;
  int quad = lane >> 4;

  half8 bf[4][2];
#pragma unroll
  for (int jb = 0; jb < 4; jb++)
#pragma unroll
    for (int kf = 0; kf < 2; kf++)
#pragma unroll
      for (int i = 0; i < 8; i++)
        bf[jb][kf][i] = (_Float16)W2[(kf * 32 + quad * 8 + i) * 64 + jb * 16 + n16];
  float b2j[4];
#pragma unroll
  for (int jb = 0; jb < 4; jb++) b2j[jb] = b2[jb * 16 + n16];

  const uint4* U4 = (const uint4*)U;
  int wave = (blockIdx.x * 256 + threadIdx.x) >> 6;
  int nw = (gridDim.x * 256) >> 6;
  for (int tile = wave; tile < ntiles; tile += nw) {
    int ut = __builtin_amdgcn_readfirstlane(tile);
    int base = ut * 16;
    int node = base + n16;  // ntiles*16 == N exactly
    int rbeg = rowptr[node];
    int rlen = rowptr[node + 1] - rbeg;

    __half2 z2 = __float2half2_rn(0.f);
    __half2 acc0[4] = {z2, z2, z2, z2};
    __half2 acc1[4] = {z2, z2, z2, z2};

    for (int j = 0; __any(j < rlen); j++) {
      int c = col[rbeg + j];          // slack-padded; safe overread within col
      c = (j < rlen) ? c : ndummy;    // dummy zero row
      size_t rbase = (size_t)c << 3;  // row = 8 uint4
      uint4 v0 = U4[rbase + quad];
      uint4 v1 = U4[rbase + 4 + quad];
      hacc(v0, acc0);
      hacc(v1, acc1);
    }
    // scale by dinv[node] -> a2 in A-fragment layout
    __half2 dv = __half2half2(__float2half_rn(dinv[node]));
#pragma unroll
    for (int j = 0; j < 4; j++) {
      acc0[j] = __hmul2(acc0[j], dv);
      acc1[j] = __hmul2(acc1[j], dv);
    }
    half8 a0 = *reinterpret_cast<half8*>(acc0);
    half8 a1 = *reinterpret_cast<half8*>(acc1);

    int g_r[4], t_r[4];
#pragma unroll
    for (int r = 0; r < 4; r++) {
      int nd = base + quad * 4 + r;
      g_r[r] = nd / 14;
      t_r[r] = nd - g_r[r] * 14;
    }
    float pr[4] = {0.f, 0.f, 0.f, 0.f};
#pragma unroll
    for (int jb = 0; jb < 4; jb++) {
      float4v acc = {0.f, 0.f, 0.f, 0.f};
      acc = __builtin_amdgcn_mfma_f32_16x16x32_f16(a0, bf[jb][0], acc, 0, 0, 0);
      acc = __builtin_amdgcn_mfma_f32_16x16x32_f16(a1, bf[jb][1], acc, 0, 0, 0);
      int j = jb * 16 + n16;
#pragma unroll
      for (int r = 0; r < 4; r++) {
        float h = acc[r] + b2j[jb];
        h = h > 0.f ? h : 0.f;
        pr[r] += h * Wfc[t_r[r] * 64 + j];
      }
    }
#pragma unroll
    for (int r = 0; r < 4; r++) {
#pragma unroll
      for (int off = 1; off < 16; off <<= 1) pr[r] += __shfl_xor(pr[r], off);
    }
    if (n16 == 0) {
#pragma unroll
      for (int r = 0; r < 4; r++) atomicAdd(&out[g_r[r]], pr[r]);
    }
  }
}

extern "C" void kernel_launch(void* const* d_in, const int* in_sizes, int n_in,
                              void* d_out, int out_size, void* d_ws, size_t ws_size,
                              hipStream_t stream)
{
  const float* x = (const float*)d_in[0];
  const int* edges = (const int*)d_in[1];
  const float* W1 = (const float*)d_in[2];
  const float* b1 = (const float*)d_in[3];
  const float* W2 = (const float*)d_in[4];
  const float* b2 = (const float*)d_in[5];
  const float* Wfc = (const float*)d_in[6];
  const float* bfc = (const float*)d_in[7];
  float* out = (float*)d_out;
  (void)n_in;

  const int N = in_sizes[0] / 32;   // 700000
  const int E = in_sizes[1] / 2;    // 4000000
  const int B = out_size;           // 50000
  const int NBK = (N + BNODES - 1) >> BSH;  // 342 buckets (dst>>11)
  const int NCH = (E + CHUNK - 1) / CHUNK;  // 489 chunks

  char* ws = (char*)d_ws;
  size_t off = 0;
  auto alloc = [&](size_t bytes) -> void* {
    void* p = ws + off;
    off += (bytes + 255) & ~(size_t)255;
    return p;
  };
  int* flag = (int*)alloc(256);
  int* cnt = (int*)alloc((size_t)NCH * NBK * 4);
  int* totals = (int*)alloc((size_t)NBK * 4);
  int* bstart = (int*)alloc(((size_t)NBK + 1) * 4);
  int* col = (int*)alloc(((size_t)E + N + 256) * 4);  // self entries + overread slack
  int* rowptr = (int*)alloc(((size_t)N + 1) * 4);
  float* dinv = (float*)alloc((size_t)N * 4);
  __half* F1 = (__half*)alloc(((size_t)N + 16) * 64 * 2);  // g1; head aliased as pairbuf
  __half* F2 = (__half*)alloc(((size_t)N + 16) * 64 * 2);  // u1
  int* pair = (int*)F1;  // pairbuf (E*4 = 16MB) dead before mm1 writes F1

  if (off > ws_size) {
    float v = -(float)(double)(ws_size >> 20);
    fallback_kernel<<<(B + 255) / 256, 256, 0, stream>>>(out, B, v);
    return;
  }

  probe_kernel<<<1, 64, 0, stream>>>(edges, flag);
  zero_dummy_kernel<<<1, 64, 0, stream>>>(F1, F2, N);
  hist2_kernel<<<NCH, 256, 0, stream>>>(edges, E, N, flag, cnt, NBK);
  colscan_kernel<<<NBK, 64, 0, stream>>>(cnt, NCH, NBK, totals);
  scan_totals_kernel<<<1, 512, 0, stream>>>(totals, NBK, bstart, rowptr, N);
  pass3_kernel<<<NCH, 256, 0, stream>>>(edges, E, N, flag, cnt, bstart, pair, NBK);
  build_kernel<<<NBK, 256, 0, stream>>>(pair, bstart, rowptr, dinv, col, N);

  int ntiles = (N + 15) / 16;   // 43750 (N divisible by 16)
  int aggBlocks = (N + 7) / 8;  // 2 nodes per wave, 4 waves per block
  mfma_mm1_kernel<<<4096, 256, 0, stream>>>(x, W1, dinv, F1, N, ntiles);
  agg_kernel<<<aggBlocks, 256, 0, stream>>>(F1, rowptr, col, dinv, b1, F2, N, N);
  out_init_kernel<<<(B + 255) / 256, 256, 0, stream>>>(out, bfc, B);
  mfma_final_fused_kernel<<<4096, 256, 0, stream>>>(F2, rowptr, col, dinv, W2, b2, Wfc,
                                                    out, ntiles, N);
}

// Round 15
// 572.345 us; speedup vs baseline: 2.9814x; 1.0875x over previous
//
#include <hip/hip_runtime.h>
#include <hip/hip_fp16.h>

// GCN: h1 = relu(gcn(x,W1,b1)); h2 = relu(gcn(h1,W2,b2)); out = h2.reshape(B,896)@Wfc + bfc
// Factored: g1 = dinv*(x@W1); u1 = dinv*relu(dinv*agg(g1)+b1);
//           h2 = relu((dinv*agg(u1))@W2+b2)  [agg commutes with @W2]
// CSR via deterministic counting sort (b=dst>>11), self-loop in-row, dummy zero row at N.
// BOTH gather stages use the fragment layout: lane(m=lane&15, quad=lane>>4) owns 16B
// chunks of row m; clamped col -> unconditional dwordx4 gathers, pk_add fp16, 2 edges/iter
// unroll. agg1 stores coalesced rows (no cross-lane reduce); final consumes fragments
// in-register via 8 MFMAs + relu + Wfc dot.

typedef _Float16 half8 __attribute__((ext_vector_type(8)));
typedef float float4v __attribute__((ext_vector_type(4)));

#define CHUNK 8192
#define BSH 11
#define BNODES 2048

__global__ __launch_bounds__(256) void fallback_kernel(float* __restrict__ out, int n, float v)
{
  int i = blockIdx.x * 256 + threadIdx.x;
  if (i < n) out[i] = v;
}

// detect edges dtype: int64 values < 2^31 -> every odd int32 word is 0
__global__ __launch_bounds__(64) void probe_kernel(const int* __restrict__ edges, int* __restrict__ flag)
{
  if (threadIdx.x == 0) {
    int orv = edges[1] | edges[3] | edges[5] | edges[7] | edges[9] | edges[11] | edges[13] | edges[15];
    flag[0] = (orv == 0) ? 1 : 0;  // 1 => int64 layout (shift word index by 1)
  }
}

// zero the dummy rows (index N) of both feature buffers (ws is poisoned every call)
__global__ __launch_bounds__(64) void zero_dummy_kernel(
    __half* __restrict__ F1, __half* __restrict__ F2, int N)
{
  int t = threadIdx.x;
  if (t < 16) ((uint2*)(F1 + (size_t)N * 64))[t] = make_uint2(0, 0);
  else if (t < 32) ((uint2*)(F2 + (size_t)N * 64))[t - 16] = make_uint2(0, 0);
}

// (1) per-chunk bucket histogram -> cnt[chunk][b]
__global__ __launch_bounds__(256) void hist2_kernel(
    const int* __restrict__ edges, int E, int N, const int* __restrict__ flag,
    int* __restrict__ cnt, int NBK)
{
  __shared__ int lh[512];
  int t = threadIdx.x;
  int blk = blockIdx.x;
  for (int b = t; b < NBK; b += 256) lh[b] = 0;
  __syncthreads();
  int sh = flag[0];
  int base = blk * CHUNK;
#pragma unroll
  for (int k = 0; k < CHUNK / 256; k++) {
    int e = base + k * 256 + t;
    if (e < E) {
      int d = edges[(E + e) << sh];
      if ((unsigned)d < (unsigned)N) atomicAdd(&lh[d >> BSH], 1);
    }
  }
  __syncthreads();
  for (int b = t; b < NBK; b += 256) cnt[(size_t)blk * NBK + b] = lh[b];
}

// (2) per-bucket exclusive prefix over chunks, in place; totals[b] = column sum
__global__ __launch_bounds__(64) void colscan_kernel(
    int* __restrict__ cnt, int NCH, int NBK, int* __restrict__ totals)
{
  int b = blockIdx.x;
  int lane = threadIdx.x;
  int carry = 0;
  int rounds = (NCH + 63) >> 6;
  for (int r = 0; r < rounds; r++) {
    int blk = r * 64 + lane;
    int v = (blk < NCH) ? cnt[(size_t)blk * NBK + b] : 0;
    int incl = v;
#pragma unroll
    for (int off = 1; off < 64; off <<= 1) {
      int x = __shfl_up(incl, off);
      if (lane >= off) incl += x;
    }
    int excl = incl - v + carry;
    if (blk < NCH) cnt[(size_t)blk * NBK + b] = excl;
    carry += __shfl(incl, 63);
  }
  if (lane == 0) totals[b] = carry;
}

// (3) exclusive scan of bucket totals -> bstart[NBK+1]; rowptr[N] = Ev + N
__global__ __launch_bounds__(512) void scan_totals_kernel(
    const int* __restrict__ totals, int NBK,
    int* __restrict__ bstart, int* __restrict__ rowptr, int N)
{
  __shared__ int sm[512];
  int t = threadIdx.x;
  int v = (t < NBK) ? totals[t] : 0;
  sm[t] = v;
  __syncthreads();
  for (int off = 1; off < 512; off <<= 1) {
    int x = 0;
    if (t >= off) x = sm[t - off];
    __syncthreads();
    if (t >= off) sm[t] += x;
    __syncthreads();
  }
  if (t < NBK) bstart[t] = sm[t] - v;
  if (t == 0) { bstart[NBK] = sm[511]; rowptr[N] = sm[511] + N; }
}

// (4) placement: contiguous runs per (chunk,bucket); packed = src | (dst&2047)<<20
__global__ __launch_bounds__(256) void pass3_kernel(
    const int* __restrict__ edges, int E, int N, const int* __restrict__ flag,
    const int* __restrict__ cnt, const int* __restrict__ bstart,
    int* __restrict__ pair, int NBK)
{
  __shared__ int lcur[512];
  int t = threadIdx.x;
  int blk = blockIdx.x;
  for (int b = t; b < NBK; b += 256)
    lcur[b] = bstart[b] + cnt[(size_t)blk * NBK + b];
  __syncthreads();
  int sh = flag[0];
  int base = blk * CHUNK;
#pragma unroll
  for (int k = 0; k < CHUNK / 256; k++) {
    int e = base + k * 256 + t;
    if (e < E) {
      int s = edges[e << sh];
      int d = edges[(E + e) << sh];
      if ((unsigned)s < (unsigned)N && (unsigned)d < (unsigned)N) {
        int pos = atomicAdd(&lcur[d >> BSH], 1);
        pair[pos] = s | ((d & (BNODES - 1)) << 20);
      }
    }
  }
}

// (5) per-bucket CSR build with self entry first in each row.
__global__ __launch_bounds__(256) void build_kernel(
    const int* __restrict__ pair, const int* __restrict__ bstart,
    int* __restrict__ rowptr, float* __restrict__ dinv, int* __restrict__ col, int N)
{
  __shared__ int hist[BNODES];
  __shared__ int cur[BNODES];
  __shared__ int sc[256];
  int b = blockIdx.x;
  int t = threadIdx.x;
  int pbeg = bstart[b], pend = bstart[b + 1];
  int colbase = pbeg + (b << BSH);
#pragma unroll
  for (int i = 0; i < BNODES / 256; i++) {
    int idx = i * 256 + t;
    int row = (b << BSH) + idx;
    hist[idx] = (row < N) ? 1 : 0;  // self entry
  }
  __syncthreads();
  for (int p = pbeg + t; p < pend; p += 256)
    atomicAdd(&hist[(pair[p] >> 20) & (BNODES - 1)], 1);
  __syncthreads();
  int hv[8];
  int tsum = 0;
#pragma unroll
  for (int i = 0; i < 8; i++) { hv[i] = hist[t * 8 + i]; tsum += hv[i]; }
  sc[t] = tsum;
  __syncthreads();
  for (int off = 1; off < 256; off <<= 1) {
    int x = 0;
    if (t >= off) x = sc[t - off];
    __syncthreads();
    if (t >= off) sc[t] += x;
    __syncthreads();
  }
  int run = sc[t] - tsum;
#pragma unroll
  for (int i = 0; i < 8; i++) {
    int idx = t * 8 + i;
    int rp = colbase + run;
    int row = (b << BSH) + idx;
    if (row < N) {
      rowptr[row] = rp;
      dinv[row] = rsqrtf((float)hv[i]);  // hv = deg + 1 (self included)
      col[rp] = row;                      // self entry at slot 0
      cur[idx] = rp + 1;
    } else {
      cur[idx] = rp;
    }
    run += hv[i];
  }
  __syncthreads();
  for (int p = pbeg + t; p < pend; p += 256) {
    int v = pair[p];
    int pos = atomicAdd(&cur[(v >> 20) & (BNODES - 1)], 1);
    col[pos] = v & 0xFFFFF;
  }
}

// MFMA mm1: per wave, 16 nodes; D[16][64] = x-tile(fp16) @ W1; G = dinv*D (fp16).
__global__ __launch_bounds__(256) void mfma_mm1_kernel(
    const float* __restrict__ X, const float* __restrict__ W1,
    const float* __restrict__ dinv, __half* __restrict__ G, int n, int ntiles)
{
  int lane = threadIdx.x & 63;
  int n16 = lane & 15;
  int quad = lane >> 4;

  half8 bf[4];
#pragma unroll
  for (int jb = 0; jb < 4; jb++)
#pragma unroll
    for (int i = 0; i < 8; i++)
      bf[jb][i] = (_Float16)W1[(quad * 8 + i) * 64 + jb * 16 + n16];

  _Float16* Gh = (_Float16*)G;
  int wave = (blockIdx.x * 256 + threadIdx.x) >> 6;
  int nw = (gridDim.x * 256) >> 6;
  for (int tile = wave; tile < ntiles; tile += nw) {
    int ut = __builtin_amdgcn_readfirstlane(tile);
    int base = ut * 16;
    int node = base + n16;
    if (node >= n) node = n - 1;
    const float* xr = X + (size_t)node * 32 + quad * 8;
    half8 a;
#pragma unroll
    for (int i = 0; i < 8; i++) a[i] = (_Float16)xr[i];

    float4v acc[4];
#pragma unroll
    for (int jb = 0; jb < 4; jb++) {
      float4v z = {0.f, 0.f, 0.f, 0.f};
      acc[jb] = __builtin_amdgcn_mfma_f32_16x16x32_f16(a, bf[jb], z, 0, 0, 0);
    }
#pragma unroll
    for (int r = 0; r < 4; r++) {
      int node2 = base + quad * 4 + r;
      if (node2 < n) {
        float dv = dinv[node2];
#pragma unroll
        for (int jb = 0; jb < 4; jb++)
          Gh[(size_t)node2 * 64 + jb * 16 + n16] = (_Float16)(dv * acc[jb][r]);
      }
    }
  }
}

__device__ inline void hacc(uint4 v, __half2* a)
{
  a[0] = __hadd2(a[0], *reinterpret_cast<__half2*>(&v.x));
  a[1] = __hadd2(a[1], *reinterpret_cast<__half2*>(&v.y));
  a[2] = __hadd2(a[2], *reinterpret_cast<__half2*>(&v.z));
  a[3] = __hadd2(a[3], *reinterpret_cast<__half2*>(&v.w));
}

__device__ inline __half2 hrelu2(__half2 v)
{
  __half z = __float2half_rn(0.f);
  __half2 r;
  r.x = __hmax(v.x, z);
  r.y = __hmax(v.y, z);
  return r;
}

// agg1 in fragment layout: lane(m=lane&15, quad) owns bytes [quad*16,+16) and
// [64+quad*16,+16) of row m. Gather 2 edges/iter (clamped col -> dummy zero row),
// pk_add fp16; epilogue u1 = dinv*relu(dinv*acc + b1); coalesced row stores.
// No cross-lane reduce, no predicated stores.
__global__ __launch_bounds__(256) void agg1_frag_kernel(
    const __half* __restrict__ G, const int* __restrict__ rowptr,
    const int* __restrict__ col, const float* __restrict__ dinv,
    const float* __restrict__ bias, __half* __restrict__ U, int ntiles, int ndummy)
{
  int lane = threadIdx.x & 63;
  int n16 = lane & 15;
  int quad = lane >> 4;

  // bias slices for this lane's features: acc0 -> [quad*8, +8), acc1 -> [32+quad*8, +8)
  const float* bp0 = bias + quad * 8;
  const float* bp1 = bias + 32 + quad * 8;
  float4 b0a = *(const float4*)bp0, b0b = *(const float4*)(bp0 + 4);
  float4 b1a = *(const float4*)bp1, b1b = *(const float4*)(bp1 + 4);
  __half2 bh0[4] = {__floats2half2_rn(b0a.x, b0a.y), __floats2half2_rn(b0a.z, b0a.w),
                    __floats2half2_rn(b0b.x, b0b.y), __floats2half2_rn(b0b.z, b0b.w)};
  __half2 bh1[4] = {__floats2half2_rn(b1a.x, b1a.y), __floats2half2_rn(b1a.z, b1a.w),
                    __floats2half2_rn(b1b.x, b1b.y), __floats2half2_rn(b1b.z, b1b.w)};

  const uint4* G4 = (const uint4*)G;
  uint4* U4 = (uint4*)U;
  int wave = (blockIdx.x * 256 + threadIdx.x) >> 6;
  int nw = (gridDim.x * 256) >> 6;
  for (int tile = wave; tile < ntiles; tile += nw) {
    int ut = __builtin_amdgcn_readfirstlane(tile);
    int node = ut * 16 + n16;  // N divisible by 16
    int rbeg = rowptr[node];
    int rlen = rowptr[node + 1] - rbeg;

    __half2 z2 = __float2half2_rn(0.f);
    __half2 acc0[4] = {z2, z2, z2, z2};
    __half2 acc1[4] = {z2, z2, z2, z2};

    for (int j = 0; __any(j < rlen); j += 2) {
      int c0 = col[rbeg + j];
      int c1 = col[rbeg + j + 1];  // slack-padded overread ok
      c0 = (j < rlen) ? c0 : ndummy;
      c1 = (j + 1 < rlen) ? c1 : ndummy;
      uint4 v00 = G4[((size_t)c0 << 3) + quad];
      uint4 v01 = G4[((size_t)c0 << 3) + 4 + quad];
      uint4 v10 = G4[((size_t)c1 << 3) + quad];
      uint4 v11 = G4[((size_t)c1 << 3) + 4 + quad];
      hacc(v00, acc0); hacc(v01, acc1);
      hacc(v10, acc0); hacc(v11, acc1);
    }

    __half2 dv = __half2half2(__float2half_rn(dinv[node]));
    uint4 o0, o1;
    __half2 r;
#pragma unroll
    for (int j = 0; j < 4; j++) {
      r = __hmul2(hrelu2(__hadd2(__hmul2(acc0[j], dv), bh0[j])), dv);
      (&o0.x)[j] = *reinterpret_cast<uint*>(&r);
      r = __hmul2(hrelu2(__hadd2(__hmul2(acc1[j], dv), bh1[j])), dv);
      (&o1.x)[j] = *reinterpret_cast<uint*>(&r);
    }
    U4[((size_t)node << 3) + quad] = o0;
    U4[((size_t)node << 3) + 4 + quad] = o1;
  }
}

__global__ __launch_bounds__(256) void out_init_kernel(
    float* __restrict__ out, const float* __restrict__ bfc, int n)
{
  int i = blockIdx.x * 256 + threadIdx.x;
  if (i < n) out[i] = bfc[0];
}

// FUSED agg2 + layer2-matmul + relu + FC, 2 edges/iter unroll.
__global__ __launch_bounds__(256) void mfma_final_fused_kernel(
    const __half* __restrict__ U, const int* __restrict__ rowptr,
    const int* __restrict__ col, const float* __restrict__ dinv,
    const float* __restrict__ W2, const float* __restrict__ b2,
    const float* __restrict__ Wfc, float* __restrict__ out,
    int ntiles, int ndummy)
{
  int lane = threadIdx.x & 63;
  int n16 = lane & 15;
  int quad = lane >> 4;

  half8 bf[4][2];
#pragma unroll
  for (int jb = 0; jb < 4; jb++)
#pragma unroll
    for (int kf = 0; kf < 2; kf++)
#pragma unroll
      for (int i = 0; i < 8; i++)
        bf[jb][kf][i] = (_Float16)W2[(kf * 32 + quad * 8 + i) * 64 + jb * 16 + n16];
  float b2j[4];
#pragma unroll
  for (int jb = 0; jb < 4; jb++) b2j[jb] = b2[jb * 16 + n16];

  const uint4* U4 = (const uint4*)U;
  int wave = (blockIdx.x * 256 + threadIdx.x) >> 6;
  int nw = (gridDim.x * 256) >> 6;
  for (int tile = wave; tile < ntiles; tile += nw) {
    int ut = __builtin_amdgcn_readfirstlane(tile);
    int base = ut * 16;
    int node = base + n16;
    int rbeg = rowptr[node];
    int rlen = rowptr[node + 1] - rbeg;

    __half2 z2 = __float2half2_rn(0.f);
    __half2 acc0[4] = {z2, z2, z2, z2};
    __half2 acc1[4] = {z2, z2, z2, z2};

    for (int j = 0; __any(j < rlen); j += 2) {
      int c0 = col[rbeg + j];
      int c1 = col[rbeg + j + 1];  // slack-padded overread ok
      c0 = (j < rlen) ? c0 : ndummy;
      c1 = (j + 1 < rlen) ? c1 : ndummy;
      uint4 v00 = U4[((size_t)c0 << 3) + quad];
      uint4 v01 = U4[((size_t)c0 << 3) + 4 + quad];
      uint4 v10 = U4[((size_t)c1 << 3) + quad];
      uint4 v11 = U4[((size_t)c1 << 3) + 4 + quad];
      hacc(v00, acc0); hacc(v01, acc1);
      hacc(v10, acc0); hacc(v11, acc1);
    }
    // scale by dinv[node] -> a2 in A-fragment layout
    __half2 dv = __half2half2(__float2half_rn(dinv[node]));
#pragma unroll
    for (int j = 0; j < 4; j++) {
      acc0[j] = __hmul2(acc0[j], dv);
      acc1[j] = __hmul2(acc1[j], dv);
    }
    half8 a0 = *reinterpret_cast<half8*>(acc0);
    half8 a1 = *reinterpret_cast<half8*>(acc1);

    int g_r[4], t_r[4];
#pragma unroll
    for (int r = 0; r < 4; r++) {
      int nd = base + quad * 4 + r;
      g_r[r] = nd / 14;
      t_r[r] = nd - g_r[r] * 14;
    }
    float pr[4] = {0.f, 0.f, 0.f, 0.f};
#pragma unroll
    for (int jb = 0; jb < 4; jb++) {
      float4v acc = {0.f, 0.f, 0.f, 0.f};
      acc = __builtin_amdgcn_mfma_f32_16x16x32_f16(a0, bf[jb][0], acc, 0, 0, 0);
      acc = __builtin_amdgcn_mfma_f32_16x16x32_f16(a1, bf[jb][1], acc, 0, 0, 0);
      int j = jb * 16 + n16;
#pragma unroll
      for (int r = 0; r < 4; r++) {
        float h = acc[r] + b2j[jb];
        h = h > 0.f ? h : 0.f;
        pr[r] += h * Wfc[t_r[r] * 64 + j];
      }
    }
#pragma unroll
    for (int r = 0; r < 4; r++) {
#pragma unroll
      for (int off = 1; off < 16; off <<= 1) pr[r] += __shfl_xor(pr[r], off);
    }
    if (n16 == 0) {
#pragma unroll
      for (int r = 0; r < 4; r++) atomicAdd(&out[g_r[r]], pr[r]);
    }
  }
}

extern "C" void kernel_launch(void* const* d_in, const int* in_sizes, int n_in,
                              void* d_out, int out_size, void* d_ws, size_t ws_size,
                              hipStream_t stream)
{
  const float* x = (const float*)d_in[0];
  const int* edges = (const int*)d_in[1];
  const float* W1 = (const float*)d_in[2];
  const float* b1 = (const float*)d_in[3];
  const float* W2 = (const float*)d_in[4];
  const float* b2 = (const float*)d_in[5];
  const float* Wfc = (const float*)d_in[6];
  const float* bfc = (const float*)d_in[7];
  float* out = (float*)d_out;
  (void)n_in;

  const int N = in_sizes[0] / 32;   // 700000
  const int E = in_sizes[1] / 2;    // 4000000
  const int B = out_size;           // 50000
  const int NBK = (N + BNODES - 1) >> BSH;  // 342 buckets (dst>>11)
  const int NCH = (E + CHUNK - 1) / CHUNK;  // 489 chunks

  char* ws = (char*)d_ws;
  size_t off = 0;
  auto alloc = [&](size_t bytes) -> void* {
    void* p = ws + off;
    off += (bytes + 255) & ~(size_t)255;
    return p;
  };
  int* flag = (int*)alloc(256);
  int* cnt = (int*)alloc((size_t)NCH * NBK * 4);
  int* totals = (int*)alloc((size_t)NBK * 4);
  int* bstart = (int*)alloc(((size_t)NBK + 1) * 4);
  int* col = (int*)alloc(((size_t)E + N + 256) * 4);  // self entries + overread slack
  int* rowptr = (int*)alloc(((size_t)N + 1) * 4);
  float* dinv = (float*)alloc((size_t)N * 4);
  __half* F1 = (__half*)alloc(((size_t)N + 16) * 64 * 2);  // g1; head aliased as pairbuf
  __half* F2 = (__half*)alloc(((size_t)N + 16) * 64 * 2);  // u1
  int* pair = (int*)F1;  // pairbuf (E*4 = 16MB) dead before mm1 writes F1

  if (off > ws_size) {
    float v = -(float)(double)(ws_size >> 20);
    fallback_kernel<<<(B + 255) / 256, 256, 0, stream>>>(out, B, v);
    return;
  }

  probe_kernel<<<1, 64, 0, stream>>>(edges, flag);
  zero_dummy_kernel<<<1, 64, 0, stream>>>(F1, F2, N);
  hist2_kernel<<<NCH, 256, 0, stream>>>(edges, E, N, flag, cnt, NBK);
  colscan_kernel<<<NBK, 64, 0, stream>>>(cnt, NCH, NBK, totals);
  scan_totals_kernel<<<1, 512, 0, stream>>>(totals, NBK, bstart, rowptr, N);
  pass3_kernel<<<NCH, 256, 0, stream>>>(edges, E, N, flag, cnt, bstart, pair, NBK);
  build_kernel<<<NBK, 256, 0, stream>>>(pair, bstart, rowptr, dinv, col, N);

  int ntiles = (N + 15) / 16;  // 43750 (N divisible by 16)
  mfma_mm1_kernel<<<4096, 256, 0, stream>>>(x, W1, dinv, F1, N, ntiles);
  agg1_frag_kernel<<<4096, 256, 0, stream>>>(F1, rowptr, col, dinv, b1, F2, ntiles, N);
  out_init_kernel<<<(B + 255) / 256, 256, 0, stream>>>(out, bfc, B);
  mfma_final_fused_kernel<<<4096, 256, 0, stream>>>(F2, rowptr, col, dinv, W2, b2, Wfc,
                                                    out, ntiles, N);
}